// Round 8
// baseline (1356.977 us; speedup 1.0000x reference)
//
#include <hip/hip_runtime.h>
#include <stdint.h>

#define NN 50000
#define EE 800000
#define FIN 256
#define HD 128
#define DD 32
#define KK 25000
#define SLOPEF 0.4f
#define NEGF (-1e9f)
#define ATT_OFF 34
#define STR_OFF (34 + EE * 4)
#define CW 128             // LDS-cached edges per node (deg ~Poisson(16); recompute fallback)

// counting-sort CSR build (layer 0 only; layer 1 reuses it via slot-filtering)
#define BCH 32             // edge chunks
#define EPC (EE / BCH)     // 25000 edges per chunk
#define NRQ 12500          // node-range quarter for count blocks (4 x 12500 = NN)

// ---------- helpers ----------
__device__ __forceinline__ unsigned fkey(float x) {
    unsigned u = __float_as_uint(x);
    return (u & 0x80000000u) ? ~u : (u | 0x80000000u);   // monotone float->uint
}
__device__ __forceinline__ float unfkey(unsigned k) {
    unsigned u = (k & 0x80000000u) ? (k ^ 0x80000000u) : ~k;
    return __uint_as_float(u);
}
__device__ __forceinline__ float lrelu(float v) { return v > 0.f ? v : SLOPEF * v; }

// ---------- pointer bundle ----------
struct P {
    // inputs
    const float *feature, *strength, *W0, *b0, *al0, *ar0, *Wc0, *bc0;
    const float *W1, *b1, *al1, *ar1, *gW, *gb, *cW, *cb;
    const int *src, *dst;
    // zeroed scratch
    double *Zacc, *racc;
    int *cnt;
    unsigned *gmaxk;
    unsigned *rs;                 // [0]=pivot,[1]=need,[2]=hi bin,[3]=hi remaining
    unsigned *binsHi, *binsLo;    // 65536 u32 bins each
    // other scratch
    unsigned *keys;
    unsigned char *degc_i, *degc_o;   // per-(chunk,node) u8 counts [BCH][NN]
    unsigned *cb0;                // per-(chunk,node) CSR base cursors
    int *dsum;                    // out-degree totals
    int *csr_src, *rank, *off0, *slot, *list, *bsum, *boff;
    float *z0, *el0, *er0, *q4, *m0f, *s0f, *b0wc, *hc, *xk, *z1;
    float *el1, *er1, *m1f, *s1f, *res, *g, *tscale;
    float *out;                   // d_out (float32)
};

// ---------- fp32 tiled GEMM body, DOUBLE-BUFFERED: C[M,128] = A[M,Kd] @ B[Kd,128] ----------
// Reg-staged prefetch: loads for tile k+1 issue before computing tile k; the
// LDS store of k+1 (after compute-k's barrier) is where vmcnt waits land —
// global latency hides under the 16-deep MAC loop. (R7: 67% stall, VALU 33%.)
#define BM 128
#define BN 64
#define BK 16
__device__ void gemm_body(
    const float* __restrict__ A, const float* __restrict__ B, float* __restrict__ C,
    int M, int Kd,
    const float* __restrict__ al, const float* __restrict__ ar,
    float* __restrict__ el, float* __restrict__ er,
    const float* __restrict__ Wc, float* __restrict__ q4,
    int bx, int by) {
    __shared__ float As[2][BK][BM + 4];
    __shared__ float Bs[2][BK][BN];
    int bm = by * BM, bn = bx * BN;
    int tid = threadIdx.x;
    int tr = tid >> 4, tc = tid & 15;
    int lrow = tid >> 1;
    int arow = (bm + lrow < M) ? (bm + lrow) : -1;
    int acol = (tid & 1) << 3;
    int kr = tid >> 4, bcol = (tid & 15) << 2;
    const float* aptr = (arow >= 0) ? (A + (size_t)arow * Kd + acol) : nullptr;
    const float* bptr = B + (size_t)kr * HD + bn + bcol;

    float4 ra0 = {0.f,0.f,0.f,0.f}, ra1 = {0.f,0.f,0.f,0.f}, rb;
    // load tile 0
    if (aptr) { ra0 = *(const float4*)aptr; ra1 = *(const float4*)(aptr + 4); }
    rb = *(const float4*)bptr;
    // store tile 0 -> buf 0
    As[0][acol + 0][lrow] = ra0.x; As[0][acol + 1][lrow] = ra0.y;
    As[0][acol + 2][lrow] = ra0.z; As[0][acol + 3][lrow] = ra0.w;
    As[0][acol + 4][lrow] = ra1.x; As[0][acol + 5][lrow] = ra1.y;
    As[0][acol + 6][lrow] = ra1.z; As[0][acol + 7][lrow] = ra1.w;
    *(float4*)&Bs[0][kr][bcol] = rb;
    // issue loads for tile 1
    if (aptr) { ra0 = *(const float4*)(aptr + BK); ra1 = *(const float4*)(aptr + BK + 4); }
    rb = *(const float4*)(bptr + (size_t)BK * HD);
    __syncthreads();

    float acc[8][4] = {};
    int nit = Kd / BK;
    for (int it = 0; it < nit; it++) {
        int cur = it & 1;
#pragma unroll
        for (int kk = 0; kk < BK; kk++) {
            float a[8], b[4];
#pragma unroll
            for (int i = 0; i < 8; i++) a[i] = As[cur][kk][tr * 8 + i];
#pragma unroll
            for (int j = 0; j < 4; j++) b[j] = Bs[cur][kk][tc * 4 + j];
#pragma unroll
            for (int i = 0; i < 8; i++)
#pragma unroll
                for (int j = 0; j < 4; j++) acc[i][j] = fmaf(a[i], b[j], acc[i][j]);
        }
        if (it + 1 < nit) {
            __syncthreads();                 // prior reads of buf cur^1 done
            int nxt = cur ^ 1;
            As[nxt][acol + 0][lrow] = ra0.x; As[nxt][acol + 1][lrow] = ra0.y;
            As[nxt][acol + 2][lrow] = ra0.z; As[nxt][acol + 3][lrow] = ra0.w;
            As[nxt][acol + 4][lrow] = ra1.x; As[nxt][acol + 5][lrow] = ra1.y;
            As[nxt][acol + 6][lrow] = ra1.z; As[nxt][acol + 7][lrow] = ra1.w;
            *(float4*)&Bs[nxt][kr][bcol] = rb;
            if (it + 2 < nit) {
                int k2 = (it + 2) * BK;
                if (aptr) { ra0 = *(const float4*)(aptr + k2); ra1 = *(const float4*)(aptr + k2 + 4); }
                rb = *(const float4*)(bptr + (size_t)k2 * HD);
            }
            __syncthreads();                 // buf nxt ready
        }
    }
#pragma unroll
    for (int i = 0; i < 8; i++) {
        int gr = bm + tr * 8 + i;
        if (gr < M) {
            float4 v = {acc[i][0], acc[i][1], acc[i][2], acc[i][3]};
            *(float4*)(C + (size_t)gr * HD + bn + tc * 4) = v;
        }
    }
    int head = bx * 2 + (tc >> 3);
    int dbase = (tc & 7) * 4;
    const float* alh = al + head * 32 + dbase;
    const float* arh = ar + head * 32 + dbase;
    float a0 = alh[0], a1 = alh[1], a2 = alh[2], a3 = alh[3];
    float r0 = arh[0], r1 = arh[1], r2 = arh[2], r3 = arh[3];
    float w0 = 0.f, w1 = 0.f, w2 = 0.f, w3 = 0.f;
    if (Wc) {
        const float* wch = Wc + head * 32 + dbase;
        w0 = wch[0]; w1 = wch[1]; w2 = wch[2]; w3 = wch[3];
    }
#pragma unroll
    for (int i = 0; i < 8; i++) {
        int gr = bm + tr * 8 + i;
        float pe = acc[i][0]*a0 + acc[i][1]*a1 + acc[i][2]*a2 + acc[i][3]*a3;
        float pr = acc[i][0]*r0 + acc[i][1]*r1 + acc[i][2]*r2 + acc[i][3]*r3;
        float pq = acc[i][0]*w0 + acc[i][1]*w1 + acc[i][2]*w2 + acc[i][3]*w3;
#pragma unroll
        for (int o = 1; o < 8; o <<= 1) {
            pe += __shfl_xor(pe, o); pr += __shfl_xor(pr, o); pq += __shfl_xor(pq, o);
        }
        if ((tc & 7) == 0 && gr < M) {
            el[gr * 4 + head] = pe; er[gr * 4 + head] = pr;
            if (Wc) q4[gr * 4 + head] = pq;
        }
    }
}

// ---------- layer-0 count: (chunk x node-quarter) u8 LDS histogram ----------
__global__ __launch_bounds__(256) void k_count0(P p) {
    __shared__ unsigned hist[NRQ / 4];        // 12500 u8 counters
    int blk = blockIdx.x;
    int isD = blk < 128;
    int c = blk & 31, rq = (blk >> 5) & 3;
    int nbase = rq * NRQ;
    for (int w = threadIdx.x; w < NRQ / 4; w += 256) hist[w] = 0u;
    __syncthreads();
    int j0 = c * EPC, j1 = j0 + EPC;
    if (isD) {
        for (int e = j0 + (int)threadIdx.x; e < j1; e += 256) {
            int d = p.dst[e] - nbase;
            if ((unsigned)d < (unsigned)NRQ) {
                unsigned sh = (unsigned)(d & 3) * 8u;
                unsigned old = atomicAdd(&hist[d >> 2], 1u << sh);
                p.rank[e] = (int)((old >> sh) & 0xffu);
            }
        }
    } else {
        for (int e = j0 + (int)threadIdx.x; e < j1; e += 256) {
            int s = p.src[e] - nbase;
            if ((unsigned)s < (unsigned)NRQ)
                atomicAdd(&hist[s >> 2], 1u << ((unsigned)(s & 3) * 8u));
        }
    }
    __syncthreads();
    unsigned* o32 = (unsigned*)((isD ? p.degc_i : p.degc_o) + (size_t)c * NN + nbase);
    for (int w = threadIdx.x; w < NRQ / 4; w += 256) o32[w] = hist[w];
}

// ---------- two-level exclusive scan over node totals (stream-ordered) ----------
__global__ __launch_bounds__(256) void k_bsum(const unsigned char* __restrict__ deg,
                                              int* __restrict__ bsum, int n, int nn) {
    int i = blockIdx.x * 256 + threadIdx.x;
    int v = 0;
    if (i < n) {
#pragma unroll
        for (int c = 0; c < BCH; c++) v += deg[(size_t)c * nn + i];
    }
    int lane = threadIdx.x & 63, w = threadIdx.x >> 6;
    __shared__ int ws[4];
#pragma unroll
    for (int o = 1; o < 64; o <<= 1) v += __shfl_xor(v, o);
    if (lane == 0) ws[w] = v;
    __syncthreads();
    if (threadIdx.x == 0) bsum[blockIdx.x] = ws[0] + ws[1] + ws[2] + ws[3];
}
__global__ __launch_bounds__(256) void k_bscan(const int* __restrict__ bsum, int nb,
                                               int* __restrict__ boff,
                                               int* __restrict__ off, int n) {
    __shared__ int ws[4];
    __shared__ int wo[5];
    int t = threadIdx.x;
    int v = (t < nb) ? bsum[t] : 0;
    int lane = t & 63, w = t >> 6;
    int incl = v;
    for (int o = 1; o < 64; o <<= 1) { int u = __shfl_up(incl, o); if (lane >= o) incl += u; }
    if (lane == 63) ws[w] = incl;
    __syncthreads();
    if (t == 0) { int a = 0; for (int i = 0; i < 4; i++) { wo[i] = a; a += ws[i]; } wo[4] = a; }
    __syncthreads();
    if (t < nb) boff[t] = wo[w] + incl - v;
    if (t == 0) off[n] = wo[4];
}
// final scan: off0 + per-chunk bases cb0 + out-degree totals dsum
__global__ __launch_bounds__(256) void k_fscan0(P p) {
    __shared__ int ws[4];
    __shared__ int wo[4];
    int i = blockIdx.x * 256 + threadIdx.x;
    int v = 0;
    if (i < NN) {
#pragma unroll
        for (int c = 0; c < BCH; c++) v += p.degc_i[(size_t)c * NN + i];
    }
    int lane = threadIdx.x & 63, w = threadIdx.x >> 6;
    int incl = v;
    for (int o = 1; o < 64; o <<= 1) { int u = __shfl_up(incl, o); if (lane >= o) incl += u; }
    if (lane == 63) ws[w] = incl;
    __syncthreads();
    if (threadIdx.x == 0) { int a = 0; for (int k = 0; k < 4; k++) { wo[k] = a; a += ws[k]; } }
    __syncthreads();
    if (i < NN) {
        int base = p.boff[blockIdx.x] + wo[w] + incl - v;
        p.off0[i] = base;
        unsigned run = (unsigned)base;
        int s = 0;
#pragma unroll
        for (int c = 0; c < BCH; c++) {
            p.cb0[(size_t)c * NN + i] = run;
            run += p.degc_i[(size_t)c * NN + i];
            s += p.degc_o[(size_t)c * NN + i];
        }
        p.dsum[i] = s;
    }
}

// ---------- CSR scatter0: own kernel (low VGPR -> high occupancy) ----------
#define GB_E 3125
__global__ __launch_bounds__(256) void k_scat0(P p) {
    int e = blockIdx.x * 256 + threadIdx.x;
    if (e >= EE) return;
    int c = e / EPC;
    int d = p.dst[e];
    unsigned pos = p.cb0[(size_t)c * NN + d] + (unsigned)p.rank[e];
    p.csr_src[pos] = p.src[e];
}

// ---------- gemm0 (+ b0wc prep micro-block) ----------
#define G0B 782            // 2 x 391 gemm blocks
__global__ __launch_bounds__(256, 4) void k_gemm0(P p) {
    int blk = blockIdx.x;
    if (blk < G0B) {
        gemm_body(p.feature, p.W0, p.z0, NN, FIN, p.al0, p.ar0, p.el0, p.er0,
                  p.Wc0, p.q4, blk & 1, blk >> 1);
    } else {
        int l = threadIdx.x;
        if (l < 64) {
            float t = p.b0[l] * p.Wc0[l] + p.b0[l + 64] * p.Wc0[l + 64];
#pragma unroll
            for (int o = 1; o < 64; o <<= 1) t += __shfl_xor(t, o);
            if (l == 0) p.b0wc[0] = t;
        }
    }
}

// ---------- layer-0 softmax + SCALAR q-gather (all nodes) ----------
__global__ __launch_bounds__(256) void k_fgatlite(
    const int* __restrict__ off, const int* __restrict__ csrs,
    const float* __restrict__ el, const float* __restrict__ er,
    const float* __restrict__ q4, const int* __restrict__ dsum,
    const float* __restrict__ b0wc,
    float* __restrict__ hc, float* __restrict__ m0f, float* __restrict__ s0f) {
    int wv = threadIdx.x >> 6, lane = threadIdx.x & 63;
    int v = blockIdx.x * 4 + wv;
    int b = off[v], e = off[v + 1], deg = e - b;
    int h = lane >> 4, sub = lane & 15;
    float erh = er[(size_t)v * 4 + h];
    float m = NEGF;
    for (int li = sub; li < deg; li += 16) {
        int s = csrs[b + li];
        m = fmaxf(m, lrelu(el[(size_t)s * 4 + h] + erh));
    }
#pragma unroll
    for (int o = 1; o < 16; o <<= 1) m = fmaxf(m, __shfl_xor(m, o));
    float ssum = 0.f, hq = 0.f;
    for (int li = sub; li < deg; li += 16) {
        int s = csrs[b + li];
        float ex = expf(lrelu(el[(size_t)s * 4 + h] + erh) - m);
        ssum += ex;
        hq = fmaf(ex, q4[(size_t)s * 4 + h], hq);
    }
#pragma unroll
    for (int o = 1; o < 16; o <<= 1) { ssum += __shfl_xor(ssum, o); hq += __shfl_xor(hq, o); }
    if (sub == 0) { m0f[v * 4 + h] = m; s0f[v * 4 + h] = ssum; }
    float t = hq / fmaxf(ssum, 1e-16f);
    t += __shfl_xor(t, 16);
    t += __shfl_xor(t, 32);
    if (lane == 0)
        hc[v] = (t + b0wc[0]) / sqrtf(fmaxf((float)dsum[v], 1.f));
}

// ---------- SAGPool score -> keys ----------
__global__ __launch_bounds__(256) void k_score(P p) {
    int v = blockIdx.x * blockDim.x + threadIdx.x;
    if (v >= NN) return;
    int b = p.off0[v], en = p.off0[v + 1];
    float acc = 0.f;
    for (int i = b; i < en; i++) acc += p.hc[p.csr_src[i]];
    float dg = fmaxf((float)(en - b), 1.f);
    float sc = acc / sqrtf(dg) + p.bc0[0];
    p.keys[v] = fkey(sc);
}

// ---------- hi-16 histogram: per-block u16-packed LDS (two 64KB half-passes) ----------
#define HB 49              // ceil(NN/1024)
__global__ __launch_bounds__(1024) void k_h0(P p) {
    __shared__ unsigned hist[16384];     // 64 KB: 32768 bins u16-packed per half
    int i = blockIdx.x * 1024 + (int)threadIdx.x;
    unsigned key = (i < NN) ? p.keys[i] : 0xFFFFFFFFu;  // sentinel: never counted
    unsigned b16 = key >> 16;
#pragma unroll
    for (int half = 0; half < 2; half++) {
        for (int w = threadIdx.x; w < 16384; w += 1024) hist[w] = 0u;
        __syncthreads();
        if (i < NN && (int)(b16 >> 15) == half) {
            unsigned bb = b16 & 0x7FFFu;
            atomicAdd(&hist[bb >> 1], 1u << (16u * (bb & 1u)));
        }
        __syncthreads();
        for (int w = threadIdx.x; w < 16384; w += 1024) {
            unsigned hv = hist[w];
            unsigned lo = hv & 0xFFFFu, hi = hv >> 16;
            if (lo) atomicAdd(&p.binsHi[half * 32768 + 2 * w], lo);
            if (hi) atomicAdd(&p.binsHi[half * 32768 + 2 * w + 1], hi);
        }
        __syncthreads();
    }
}

// ---------- lo-16 histogram among hi-bin candidates ----------
__global__ __launch_bounds__(1024) void k_h1(P p) {
    __shared__ unsigned hist[16384];
    int i = blockIdx.x * 1024 + (int)threadIdx.x;
    unsigned hib = p.rs[2];
    unsigned key = (i < NN) ? p.keys[i] : 0u;
    int cand = (i < NN) && ((key >> 16) == hib);
    unsigned b16 = key & 0xFFFFu;
#pragma unroll
    for (int half = 0; half < 2; half++) {
        for (int w = threadIdx.x; w < 16384; w += 1024) hist[w] = 0u;
        __syncthreads();
        if (cand && (int)(b16 >> 15) == half) {
            unsigned bb = b16 & 0x7FFFu;
            atomicAdd(&hist[bb >> 1], 1u << (16u * (bb & 1u)));
        }
        __syncthreads();
        for (int w = threadIdx.x; w < 16384; w += 1024) {
            unsigned hv = hist[w];
            unsigned lo = hv & 0xFFFFu, hi = hv >> 16;
            if (lo) atomicAdd(&p.binsLo[half * 32768 + 2 * w], lo);
            if (hi) atomicAdd(&p.binsLo[half * 32768 + 2 * w + 1], hi);
        }
        __syncthreads();
    }
}

// ---------- radix pick: 1 block scans 65536 bins ----------
__global__ __launch_bounds__(1024) void k_rsel2(P p, int level) {
    const unsigned* bins = level ? p.binsLo : p.binsHi;
    int K = level ? (int)p.rs[3] : KK;
    __shared__ unsigned wsm[16];
    __shared__ unsigned wpre[17];
    int t = threadIdx.x;
    unsigned base = (unsigned)t * 64;
    const uint4* b4 = (const uint4*)(bins + base);
    unsigned S = 0;
#pragma unroll
    for (int i = 0; i < 16; i++) {
        uint4 u = b4[i];
        S += u.x + u.y + u.z + u.w;
    }
    int lane = t & 63, w = t >> 6;
    unsigned val = S;
    for (int o = 1; o < 64; o <<= 1) { unsigned u = __shfl_up(val, o); if (lane >= o) val += u; }
    if (lane == 63) wsm[w] = val;
    __syncthreads();
    if (t == 0) { unsigned a = 0; for (int i = 0; i < 16; i++) { wpre[i] = a; a += wsm[i]; } wpre[16] = a; }
    __syncthreads();
    unsigned incl = wpre[w] + val;
    unsigned running = wpre[16] - incl;    // keys in strictly higher bins
    for (int i = 63; i >= 0; i--) {
        unsigned c = bins[base + i];
        unsigned above = running;
        running += c;
        if ((int)above < K && (int)running >= K) {
            if (level == 0) { p.rs[2] = base + (unsigned)i; p.rs[3] = (unsigned)(K - (int)above); }
            else { p.rs[0] = (p.rs[2] << 16) | (base + (unsigned)i); p.rs[1] = (unsigned)(K - (int)above); }
        }
    }
}

// ---------- parallel tie counting ----------
__global__ __launch_bounds__(256) void k_tcnt(P p) {
    __shared__ int ws[4];
    int v = blockIdx.x * 256 + (int)threadIdx.x;
    int flag = (v < NN && p.keys[v] == p.rs[0]) ? 1 : 0;
    unsigned long long m = __ballot(flag);
    int lane = threadIdx.x & 63, w = threadIdx.x >> 6;
    if (lane == 0) ws[w] = __popcll(m);
    __syncthreads();
    if (threadIdx.x == 0) p.bsum[blockIdx.x] = ws[0] + ws[1] + ws[2] + ws[3];
}

// ---------- list build: select + lowest-index tie ranks inline ----------
__global__ __launch_bounds__(256) void k_list(P p) {
    __shared__ int pre0;
    __shared__ int ws[4];
    int blk = blockIdx.x, tid = threadIdx.x;
    unsigned pivot = p.rs[0];
    int need = (int)p.rs[1];
    int v = blk * 256 + tid;
    unsigned k = (v < NN) ? p.keys[v] : 0u;
    int flag = (v < NN && k == pivot) ? 1 : 0;
    unsigned long long mask = __ballot(flag);
    int lane = tid & 63, w = tid >> 6;
    if (lane == 0) ws[w] = __popcll(mask);
    if (tid == 0) {
        int s = 0;
        for (int b2 = 0; b2 < blk; b2++) s += p.bsum[b2];
        pre0 = s;
    }
    __syncthreads();
    int woff = 0;
    for (int i = 0; i < w; i++) woff += ws[i];
    int rank = pre0 + woff + __popcll(mask & ((1ull << lane) - 1ull));
    if (v < NN) {
        int selv = (k > pivot) || (flag && rank < need);
        if (selv) {
            int idx = atomicAdd(p.cnt, 1);
            p.list[idx] = v;
            p.slot[v] = idx;
            p.tscale[idx] = tanhf(unfkey(k));
        } else {
            p.slot[v] = -1;
        }
    }
}

// ---------- full x for SELECTED nodes only ----------
__global__ __launch_bounds__(256) void k_fgatx(
    const int* __restrict__ list, const float* __restrict__ tscale,
    const int* __restrict__ off, const int* __restrict__ csrs,
    const float* __restrict__ el, const float* __restrict__ er,
    const float* __restrict__ m0f, const float* __restrict__ s0f,
    const float* __restrict__ z, const float* __restrict__ b0,
    float* __restrict__ xk) {
    __shared__ int ssrc[4][CW];
    __shared__ float sexp[4][CW][4];
    int wv = threadIdx.x >> 6, lane = threadIdx.x & 63;
    int i = blockIdx.x * 4 + wv;
    int v = list[i];
    int b = off[v], e = off[v + 1], deg = e - b;
    int h = lane >> 4, sub = lane & 15;
    float erh = er[(size_t)v * 4 + h];
    float mh = m0f[v * 4 + h];
    for (int li = sub; li < deg; li += 16) {
        int s = csrs[b + li];
        if (h == 0 && li < CW) ssrc[wv][li] = s;
        if (li < CW) sexp[wv][li][h] = expf(lrelu(el[(size_t)s * 4 + h] + erh) - mh);
    }
    __syncthreads();
    int h0 = lane >> 5, h1 = h0 + 2;
    float s0 = s0f[v * 4 + h0], s1 = s0f[v * 4 + h1];
    float m0 = m0f[v * 4 + h0], m1 = m0f[v * 4 + h1];
    float er0v = er[(size_t)v * 4 + h0], er1v = er[(size_t)v * 4 + h1];
    int c0 = lane, c1 = lane + 64;
    float acc0 = 0.f, acc1 = 0.f;
    for (int li = 0; li < deg; li++) {
        int s; float w0, w1;
        if (li < CW) {
            s = ssrc[wv][li];
            w0 = sexp[wv][li][h0]; w1 = sexp[wv][li][h1];
        } else {
            s = csrs[b + li];
            w0 = expf(lrelu(el[(size_t)s * 4 + h0] + er0v) - m0);
            w1 = expf(lrelu(el[(size_t)s * 4 + h1] + er1v) - m1);
        }
        int su = __builtin_amdgcn_readfirstlane(s);
        const float* zr = z + (size_t)su * HD;
        acc0 = fmaf(w0, zr[c0], acc0);
        acc1 = fmaf(w1, zr[c1], acc1);
    }
    float ts = tscale[i];
    float* xr = xk + (size_t)i * HD;
    xr[c0] = (acc0 / fmaxf(s0, 1e-16f) + b0[c0]) * ts;
    xr[c1] = (acc1 / fmaxf(s1, 1e-16f) + b0[c1]) * ts;
}

// ---------- pure gemm1 ----------
#define G1B 392
__global__ __launch_bounds__(256, 4) void k_gemm1(P p) {
    gemm_body(p.xk, p.W1, p.z1, KK, HD, p.al1, p.ar1, p.el1, p.er1,
              nullptr, nullptr, blockIdx.x & 1, blockIdx.x >> 1);
}

// ---------- layer-1 fused GAT: reuses LAYER-0 CSR, filters by slot ----------
__global__ __launch_bounds__(256) void k_fgat2(P p) {
    __shared__ int ssrc[4][CW];
    __shared__ float sexp[4][CW][4];
    int wv = threadIdx.x >> 6, lane = threadIdx.x & 63;
    int i = blockIdx.x * 4 + wv;          // slot index
    int v = p.list[i];                    // original node id
    int b = p.off0[v], e = p.off0[v + 1], deg = e - b;
    int h = lane >> 4, sub = lane & 15;
    float4 er4 = *(const float4*)(p.er1 + (size_t)i * 4);
    float erh = ((const float*)&er4)[h];
    float m = NEGF;
    for (int li = sub; li < deg; li += 16) {
        int so = p.csr_src[b + li];
        int ss = p.slot[so];
        if (h == 0 && li < CW) ssrc[wv][li] = ss;
        if (ss >= 0) m = fmaxf(m, lrelu(p.el1[(size_t)ss * 4 + h] + erh));
    }
#pragma unroll
    for (int o = 1; o < 16; o <<= 1) m = fmaxf(m, __shfl_xor(m, o));
    float ssum = 0.f;
    for (int li = sub; li < deg; li += 16) {
        int so = p.csr_src[b + li];
        int ss = p.slot[so];
        float x = (ss >= 0) ? expf(lrelu(p.el1[(size_t)ss * 4 + h] + erh) - m) : 0.f;
        if (li < CW) sexp[wv][li][h] = x;
        ssum += x;
    }
#pragma unroll
    for (int o = 1; o < 16; o <<= 1) ssum += __shfl_xor(ssum, o);
    if (sub == 0) { p.m1f[i * 4 + h] = m; p.s1f[i * 4 + h] = ssum; }
    __syncthreads();
    int h0 = lane >> 5, h1 = h0 + 2;
    float m0 = __shfl(m, h0 << 4), m1 = __shfl(m, h1 << 4);
    float s0 = __shfl(ssum, h0 << 4), s1 = __shfl(ssum, h1 << 4);
    int c0 = lane, c1 = lane + 64;
    float acc0 = 0.f, acc1 = 0.f;
    for (int li = 0; li < deg; li++) {
        int s; float w0, w1;
        if (li < CW) {
            s = ssrc[wv][li];
            if (s < 0) continue;
            w0 = sexp[wv][li][h0]; w1 = sexp[wv][li][h1];
        } else {
            int so = p.csr_src[b + li];
            s = p.slot[so];
            if (s < 0) continue;
            w0 = expf(lrelu(p.el1[(size_t)s * 4 + h0] + ((const float*)&er4)[h0]) - m0);
            w1 = expf(lrelu(p.el1[(size_t)s * 4 + h1] + ((const float*)&er4)[h1]) - m1);
        }
        int su = __builtin_amdgcn_readfirstlane(s);
        const float* zr = p.z1 + (size_t)su * HD;
        acc0 = fmaf(w0, zr[c0], acc0);
        acc1 = fmaf(w1, zr[c1], acc1);
    }
    float xc0 = acc0 / fmaxf(s0, 1e-16f) + p.b1[c0];
    float xc1 = acc1 / fmaxf(s1, 1e-16f) + p.b1[c1];
    float t = xc0 + xc1;
    t += __shfl_xor(t, 32);
    float pg = 0.f;
    if (lane < 32) {
        float r = 0.25f * t;
        p.res[(size_t)i * 32 + lane] = r;
        pg = r * p.gW[lane];
    }
#pragma unroll
    for (int o = 1; o < 32; o <<= 1) pg += __shfl_xor(pg, o);
    if (lane == 0) p.g[i] = pg + p.gb[0];
}

// ---------- MERGED: per-edge alpha outputs || gmax ----------
__global__ __launch_bounds__(256) void k_eg(P p) {
    int blk = blockIdx.x;
    if (blk < GB_E) {
        int e = blk * 256 + (int)threadIdx.x;
        if (e >= EE) return;
        int ds = p.slot[p.src[e]], dd = p.slot[p.dst[e]];
        float a[4] = {0.f, 0.f, 0.f, 0.f};
        float st = 0.f;
        if (ds >= 0 && dd >= 0) {
            float4 es = *(const float4*)(p.el1 + ds * 4);
            float4 ed = *(const float4*)(p.er1 + dd * 4);
            float l[4] = {lrelu(es.x + ed.x), lrelu(es.y + ed.y), lrelu(es.z + ed.z), lrelu(es.w + ed.w)};
#pragma unroll
            for (int h = 0; h < 4; h++) {
                float m = p.m1f[dd * 4 + h];
                float ex = expf(l[h] - m);
                a[h] = ex / fmaxf(p.s1f[dd * 4 + h], 1e-16f);
            }
            st = p.strength[e];
        }
        float* o = p.out + ATT_OFF + (size_t)e * 4;
        *(float2*)(o) = make_float2(a[0], a[1]);
        *(float2*)(o + 2) = make_float2(a[2], a[3]);
        p.out[STR_OFF + e] = st;
    } else {
        __shared__ float red[256];
        int t = threadIdx.x;
        float m = -3.4e38f;
        for (int i = (blk - GB_E) * 256 + t; i < KK; i += 98 * 256) m = fmaxf(m, p.g[i]);
        red[t] = m;
        __syncthreads();
        for (int o = 128; o > 0; o >>= 1) { if (t < o) red[t] = fmaxf(red[t], red[t + o]); __syncthreads(); }
        if (t == 0) atomicMax(p.gmaxk, fkey(red[0]));   // memset-0 identity ok
    }
}

#define WSUM_BLOCKS 104
__global__ __launch_bounds__(256) void k_wsum(P p) {
    __shared__ double vred[256];
    __shared__ double zred[8];
    int t = threadIdx.x, il = t >> 5, d = t & 31;
    float gm = unfkey(*p.gmaxk);
    double accv = 0.0, accw = 0.0;
    for (int i = blockIdx.x * 8 + il; i < KK; i += WSUM_BLOCKS * 8) {
        float w = expf(p.g[i] - gm);
        accv += (double)(w * p.res[(size_t)i * 32 + d]);
        if (d == 0) accw += (double)w;
    }
    vred[t] = accv;
    if (d == 0) zred[il] = accw;
    __syncthreads();
    if (il == 0) {
        double s = 0;
#pragma unroll
        for (int k2 = 0; k2 < 8; k2++) s += vred[k2 * 32 + d];
        atomicAdd(&p.racc[d], s);
    }
    if (t == 32) {
        double z2 = 0;
#pragma unroll
        for (int k2 = 0; k2 < 8; k2++) z2 += zred[k2];
        atomicAdd(p.Zacc, z2);
    }
}
__global__ void k_final(P p) {
    __shared__ float rb[32];
    int t = threadIdx.x;
    double Z = *p.Zacc;
    if (t < 32) {
        float r = (float)(p.racc[t] / Z);
        p.out[t] = r;
        rb[t] = r;
    }
    __syncthreads();
    if (t < 2) {
        float s = 0.f;
        for (int d = 0; d < 32; d++) s += rb[d] * p.cW[d * 2 + t];
        p.out[32 + t] = s + p.cb[t];
    }
}

// ---------- host ----------
extern "C" void kernel_launch(void* const* d_in, const int* in_sizes, int n_in,
                              void* d_out, int out_size, void* d_ws, size_t ws_size,
                              hipStream_t stream) {
    (void)in_sizes; (void)n_in; (void)out_size; (void)ws_size;
    P p;
    p.feature  = (const float*)d_in[0];
    p.strength = (const float*)d_in[1];
    p.W0  = (const float*)d_in[2];  p.b0  = (const float*)d_in[3];
    p.al0 = (const float*)d_in[4];  p.ar0 = (const float*)d_in[5];
    p.Wc0 = (const float*)d_in[6];  p.bc0 = (const float*)d_in[7];
    p.W1  = (const float*)d_in[8];  p.b1  = (const float*)d_in[9];
    p.al1 = (const float*)d_in[10]; p.ar1 = (const float*)d_in[11];
    p.gW  = (const float*)d_in[12]; p.gb  = (const float*)d_in[13];
    p.cW  = (const float*)d_in[14]; p.cb  = (const float*)d_in[15];
    p.src = (const int*)d_in[16];   p.dst = (const int*)d_in[17];
    p.out = (float*)d_out;

    char* ws = (char*)d_ws;
    size_t off = 0;
    auto alloc = [&](size_t bytes) -> void* {
        void* r = ws + off;
        off = (off + bytes + 255) & ~(size_t)255;
        return r;
    };
    // ---- zeroed region (must stay first/contiguous) ----
    p.Zacc  = (double*)alloc(8);
    p.racc  = (double*)alloc(32 * 8);
    p.cnt   = (int*)alloc(4);
    p.gmaxk = (unsigned*)alloc(4);
    p.rs    = (unsigned*)alloc(16);
    p.binsHi = (unsigned*)alloc(65536 * 4);
    p.binsLo = (unsigned*)alloc(65536 * 4);
    size_t zbytes = off;
    // ---- big buffers (fully overwritten each run) ----
    p.degc_i = (unsigned char*)alloc((size_t)BCH * NN);
    p.degc_o = (unsigned char*)alloc((size_t)BCH * NN);
    p.cb0 = (unsigned*)alloc((size_t)BCH * NN * 4);
    p.dsum = (int*)alloc((size_t)NN * 4);
    p.z0 = (float*)alloc((size_t)NN * HD * 4);
    p.xk = (float*)alloc((size_t)KK * HD * 4);
    p.z1 = (float*)alloc((size_t)KK * HD * 4);
    p.csr_src = (int*)alloc((size_t)EE * 4);
    p.rank    = (int*)alloc((size_t)EE * 4);
    p.el0 = (float*)alloc((size_t)NN * 4 * 4);
    p.er0 = (float*)alloc((size_t)NN * 4 * 4);
    p.q4  = (float*)alloc((size_t)NN * 4 * 4);
    p.m0f = (float*)alloc((size_t)NN * 4 * 4);
    p.s0f = (float*)alloc((size_t)NN * 4 * 4);
    p.b0wc = (float*)alloc(4);
    p.off0 = (int*)alloc((size_t)(NN + 1) * 4);
    p.bsum = (int*)alloc(256 * 4);
    p.boff = (int*)alloc(256 * 4);
    p.hc    = (float*)alloc((size_t)NN * 4);
    p.keys  = (unsigned*)alloc((size_t)NN * 4);
    p.slot  = (int*)alloc((size_t)NN * 4);
    p.list  = (int*)alloc((size_t)KK * 4);
    p.tscale = (float*)alloc((size_t)KK * 4);
    p.el1 = (float*)alloc((size_t)KK * 4 * 4);
    p.er1 = (float*)alloc((size_t)KK * 4 * 4);
    p.m1f = (float*)alloc((size_t)KK * 4 * 4);
    p.s1f = (float*)alloc((size_t)KK * 4 * 4);
    p.res = (float*)alloc((size_t)KK * DD * 4);
    p.g   = (float*)alloc((size_t)KK * 4);

    const int GB_N = (NN + 255) / 256;        // 196

    hipMemsetAsync(d_ws, 0, zbytes, stream);

    // ---- GAT layer 0: count -> scan -> scatter0 -> gemm0 -> fgatlite ----
    k_count0<<<256, 256, 0, stream>>>(p);
    k_bsum<<<GB_N, 256, 0, stream>>>(p.degc_i, p.bsum, NN, NN);
    k_bscan<<<1, 256, 0, stream>>>(p.bsum, GB_N, p.boff, p.off0, NN);
    k_fscan0<<<GB_N, 256, 0, stream>>>(p);
    k_scat0<<<GB_E, 256, 0, stream>>>(p);
    k_gemm0<<<G0B + 1, 256, 0, stream>>>(p);
    k_fgatlite<<<NN / 4, 256, 0, stream>>>(p.off0, p.csr_src, p.el0, p.er0, p.q4,
                                           p.dsum, p.b0wc, p.hc, p.m0f, p.s0f);

    // ---- SAGPool: stream-ordered select ----
    k_score<<<GB_N, 256, 0, stream>>>(p);
    k_h0<<<HB, 1024, 0, stream>>>(p);
    k_rsel2<<<1, 1024, 0, stream>>>(p, 0);
    k_h1<<<HB, 1024, 0, stream>>>(p);
    k_rsel2<<<1, 1024, 0, stream>>>(p, 1);
    k_tcnt<<<GB_N, 256, 0, stream>>>(p);
    k_list<<<GB_N, 256, 0, stream>>>(p);

    // ---- GAT layer 1: fgatx -> gemm1 -> fgat2 (layer-0 CSR reused) ----
    k_fgatx<<<KK / 4, 256, 0, stream>>>(p.list, p.tscale, p.off0, p.csr_src,
                                        p.el0, p.er0, p.m0f, p.s0f, p.z0, p.b0, p.xk);
    k_gemm1<<<G1B, 256, 0, stream>>>(p);
    k_fgat2<<<KK / 4, 256, 0, stream>>>(p);

    // ---- edge outputs || gmax, then readout ----
    k_eg<<<GB_E + 98, 256, 0, stream>>>(p);
    k_wsum<<<WSUM_BLOCKS, 256, 0, stream>>>(p);
    k_final<<<1, 64, 0, stream>>>(p);
}

// Round 9
// 584.582 us; speedup vs baseline: 2.3213x; 2.3213x over previous
//
#include <hip/hip_runtime.h>
#include <stdint.h>

#define NN 50000
#define EE 800000
#define FIN 256
#define HD 128
#define DD 32
#define KK 25000
#define SLOPEF 0.4f
#define NEGF (-1e9f)
#define ATT_OFF 34
#define STR_OFF (34 + EE * 4)
#define CW 128             // LDS-cached edges per node (deg ~Poisson(16); recompute fallback)

// counting-sort CSR build (layer 0 only; layer 1 reuses it via slot-filtering)
#define BCH 32             // edge chunks
#define EPC (EE / BCH)     // 25000 edges per chunk
#define NRQ 12500          // node-range quarter for count blocks (4 x 12500 = NN)

// ---------- helpers ----------
__device__ __forceinline__ unsigned fkey(float x) {
    unsigned u = __float_as_uint(x);
    return (u & 0x80000000u) ? ~u : (u | 0x80000000u);   // monotone float->uint
}
__device__ __forceinline__ float unfkey(unsigned k) {
    unsigned u = (k & 0x80000000u) ? (k ^ 0x80000000u) : ~k;
    return __uint_as_float(u);
}
__device__ __forceinline__ float lrelu(float v) { return v > 0.f ? v : SLOPEF * v; }

// ---------- pointer bundle ----------
struct P {
    // inputs
    const float *feature, *strength, *W0, *b0, *al0, *ar0, *Wc0, *bc0;
    const float *W1, *b1, *al1, *ar1, *gW, *gb, *cW, *cb;
    const int *src, *dst;
    // zeroed scratch
    double *Zacc, *racc;
    int *cnt;
    unsigned *gmaxk;
    unsigned *rs;                 // [0]=pivot,[1]=need,[2]=hi bin,[3]=hi remaining
    unsigned *binsHi, *binsLo;    // 65536 u32 bins each
    // other scratch
    unsigned *keys;
    unsigned char *degc_i, *degc_o;   // per-(chunk,node) u8 counts [BCH][NN]
    unsigned *cb0;                // per-(chunk,node) CSR base cursors
    int *dsum;                    // out-degree totals
    int *csr_src, *rank, *off0, *slot, *list, *bsum, *boff;
    float *z0, *el0, *er0, *q4, *m0f, *s0f, *b0wc, *hc, *xk, *z1;
    float *el1, *er1, *m1f, *s1f, *res, *g, *tscale;
    float *out;                   // d_out (float32)
};

// ---------- fp32 tiled GEMM body, DOUBLE-BUFFERED: C[M,128] = A[M,Kd] @ B[Kd,128] ----------
// Reg-staged prefetch (R8 lesson: NO launch_bounds occupancy pin — the 64-VGPR
// squeeze spilled 2.6 GB of scratch; unconstrained the body fits ~140 VGPR).
#define BM 128
#define BN 64
#define BK 16
__device__ void gemm_body(
    const float* __restrict__ A, const float* __restrict__ B, float* __restrict__ C,
    int M, int Kd,
    const float* __restrict__ al, const float* __restrict__ ar,
    float* __restrict__ el, float* __restrict__ er,
    const float* __restrict__ Wc, float* __restrict__ q4,
    int bx, int by) {
    __shared__ float As[2][BK][BM + 4];
    __shared__ float Bs[2][BK][BN];
    int bm = by * BM, bn = bx * BN;
    int tid = threadIdx.x;
    int tr = tid >> 4, tc = tid & 15;
    int lrow = tid >> 1;
    int arow = (bm + lrow < M) ? (bm + lrow) : -1;
    int acol = (tid & 1) << 3;
    int kr = tid >> 4, bcol = (tid & 15) << 2;
    const float* aptr = (arow >= 0) ? (A + (size_t)arow * Kd + acol) : nullptr;
    const float* bptr = B + (size_t)kr * HD + bn + bcol;

    float4 ra0 = {0.f,0.f,0.f,0.f}, ra1 = {0.f,0.f,0.f,0.f}, rb;
    // load tile 0
    if (aptr) { ra0 = *(const float4*)aptr; ra1 = *(const float4*)(aptr + 4); }
    rb = *(const float4*)bptr;
    // store tile 0 -> buf 0
    As[0][acol + 0][lrow] = ra0.x; As[0][acol + 1][lrow] = ra0.y;
    As[0][acol + 2][lrow] = ra0.z; As[0][acol + 3][lrow] = ra0.w;
    As[0][acol + 4][lrow] = ra1.x; As[0][acol + 5][lrow] = ra1.y;
    As[0][acol + 6][lrow] = ra1.z; As[0][acol + 7][lrow] = ra1.w;
    *(float4*)&Bs[0][kr][bcol] = rb;
    // issue loads for tile 1
    if (aptr) { ra0 = *(const float4*)(aptr + BK); ra1 = *(const float4*)(aptr + BK + 4); }
    rb = *(const float4*)(bptr + (size_t)BK * HD);
    __syncthreads();

    float acc[8][4] = {};
    int nit = Kd / BK;
    for (int it = 0; it < nit; it++) {
        int cur = it & 1;
#pragma unroll
        for (int kk = 0; kk < BK; kk++) {
            float a[8], b[4];
#pragma unroll
            for (int i = 0; i < 8; i++) a[i] = As[cur][kk][tr * 8 + i];
#pragma unroll
            for (int j = 0; j < 4; j++) b[j] = Bs[cur][kk][tc * 4 + j];
#pragma unroll
            for (int i = 0; i < 8; i++)
#pragma unroll
                for (int j = 0; j < 4; j++) acc[i][j] = fmaf(a[i], b[j], acc[i][j]);
        }
        if (it + 1 < nit) {
            __syncthreads();                 // prior reads of buf cur^1 done
            int nxt = cur ^ 1;
            As[nxt][acol + 0][lrow] = ra0.x; As[nxt][acol + 1][lrow] = ra0.y;
            As[nxt][acol + 2][lrow] = ra0.z; As[nxt][acol + 3][lrow] = ra0.w;
            As[nxt][acol + 4][lrow] = ra1.x; As[nxt][acol + 5][lrow] = ra1.y;
            As[nxt][acol + 6][lrow] = ra1.z; As[nxt][acol + 7][lrow] = ra1.w;
            *(float4*)&Bs[nxt][kr][bcol] = rb;
            if (it + 2 < nit) {
                int k2 = (it + 2) * BK;
                if (aptr) { ra0 = *(const float4*)(aptr + k2); ra1 = *(const float4*)(aptr + k2 + 4); }
                rb = *(const float4*)(bptr + (size_t)k2 * HD);
            }
            __syncthreads();                 // buf nxt ready
        }
    }
#pragma unroll
    for (int i = 0; i < 8; i++) {
        int gr = bm + tr * 8 + i;
        if (gr < M) {
            float4 v = {acc[i][0], acc[i][1], acc[i][2], acc[i][3]};
            *(float4*)(C + (size_t)gr * HD + bn + tc * 4) = v;
        }
    }
    int head = bx * 2 + (tc >> 3);
    int dbase = (tc & 7) * 4;
    const float* alh = al + head * 32 + dbase;
    const float* arh = ar + head * 32 + dbase;
    float a0 = alh[0], a1 = alh[1], a2 = alh[2], a3 = alh[3];
    float r0 = arh[0], r1 = arh[1], r2 = arh[2], r3 = arh[3];
    float w0 = 0.f, w1 = 0.f, w2 = 0.f, w3 = 0.f;
    if (Wc) {
        const float* wch = Wc + head * 32 + dbase;
        w0 = wch[0]; w1 = wch[1]; w2 = wch[2]; w3 = wch[3];
    }
#pragma unroll
    for (int i = 0; i < 8; i++) {
        int gr = bm + tr * 8 + i;
        float pe = acc[i][0]*a0 + acc[i][1]*a1 + acc[i][2]*a2 + acc[i][3]*a3;
        float pr = acc[i][0]*r0 + acc[i][1]*r1 + acc[i][2]*r2 + acc[i][3]*r3;
        float pq = acc[i][0]*w0 + acc[i][1]*w1 + acc[i][2]*w2 + acc[i][3]*w3;
#pragma unroll
        for (int o = 1; o < 8; o <<= 1) {
            pe += __shfl_xor(pe, o); pr += __shfl_xor(pr, o); pq += __shfl_xor(pq, o);
        }
        if ((tc & 7) == 0 && gr < M) {
            el[gr * 4 + head] = pe; er[gr * 4 + head] = pr;
            if (Wc) q4[gr * 4 + head] = pq;
        }
    }
}

// ---------- layer-0 count: (chunk x node-quarter) u8 LDS histogram ----------
__global__ __launch_bounds__(256) void k_count0(P p) {
    __shared__ unsigned hist[NRQ / 4];        // 12500 u8 counters
    int blk = blockIdx.x;
    int isD = blk < 128;
    int c = blk & 31, rq = (blk >> 5) & 3;
    int nbase = rq * NRQ;
    for (int w = threadIdx.x; w < NRQ / 4; w += 256) hist[w] = 0u;
    __syncthreads();
    int j0 = c * EPC, j1 = j0 + EPC;
    if (isD) {
        for (int e = j0 + (int)threadIdx.x; e < j1; e += 256) {
            int d = p.dst[e] - nbase;
            if ((unsigned)d < (unsigned)NRQ) {
                unsigned sh = (unsigned)(d & 3) * 8u;
                unsigned old = atomicAdd(&hist[d >> 2], 1u << sh);
                p.rank[e] = (int)((old >> sh) & 0xffu);
            }
        }
    } else {
        for (int e = j0 + (int)threadIdx.x; e < j1; e += 256) {
            int s = p.src[e] - nbase;
            if ((unsigned)s < (unsigned)NRQ)
                atomicAdd(&hist[s >> 2], 1u << ((unsigned)(s & 3) * 8u));
        }
    }
    __syncthreads();
    unsigned* o32 = (unsigned*)((isD ? p.degc_i : p.degc_o) + (size_t)c * NN + nbase);
    for (int w = threadIdx.x; w < NRQ / 4; w += 256) o32[w] = hist[w];
}

// ---------- two-level exclusive scan over node totals (stream-ordered) ----------
__global__ __launch_bounds__(256) void k_bsum(const unsigned char* __restrict__ deg,
                                              int* __restrict__ bsum, int n, int nn) {
    int i = blockIdx.x * 256 + threadIdx.x;
    int v = 0;
    if (i < n) {
#pragma unroll
        for (int c = 0; c < BCH; c++) v += deg[(size_t)c * nn + i];
    }
    int lane = threadIdx.x & 63, w = threadIdx.x >> 6;
    __shared__ int ws[4];
#pragma unroll
    for (int o = 1; o < 64; o <<= 1) v += __shfl_xor(v, o);
    if (lane == 0) ws[w] = v;
    __syncthreads();
    if (threadIdx.x == 0) bsum[blockIdx.x] = ws[0] + ws[1] + ws[2] + ws[3];
}
__global__ __launch_bounds__(256) void k_bscan(const int* __restrict__ bsum, int nb,
                                               int* __restrict__ boff,
                                               int* __restrict__ off, int n) {
    __shared__ int ws[4];
    __shared__ int wo[5];
    int t = threadIdx.x;
    int v = (t < nb) ? bsum[t] : 0;
    int lane = t & 63, w = t >> 6;
    int incl = v;
    for (int o = 1; o < 64; o <<= 1) { int u = __shfl_up(incl, o); if (lane >= o) incl += u; }
    if (lane == 63) ws[w] = incl;
    __syncthreads();
    if (t == 0) { int a = 0; for (int i = 0; i < 4; i++) { wo[i] = a; a += ws[i]; } wo[4] = a; }
    __syncthreads();
    if (t < nb) boff[t] = wo[w] + incl - v;
    if (t == 0) off[n] = wo[4];
}
// final scan: off0 + per-chunk bases cb0 + out-degree totals dsum
__global__ __launch_bounds__(256) void k_fscan0(P p) {
    __shared__ int ws[4];
    __shared__ int wo[4];
    int i = blockIdx.x * 256 + threadIdx.x;
    int v = 0;
    if (i < NN) {
#pragma unroll
        for (int c = 0; c < BCH; c++) v += p.degc_i[(size_t)c * NN + i];
    }
    int lane = threadIdx.x & 63, w = threadIdx.x >> 6;
    int incl = v;
    for (int o = 1; o < 64; o <<= 1) { int u = __shfl_up(incl, o); if (lane >= o) incl += u; }
    if (lane == 63) ws[w] = incl;
    __syncthreads();
    if (threadIdx.x == 0) { int a = 0; for (int k = 0; k < 4; k++) { wo[k] = a; a += ws[k]; } }
    __syncthreads();
    if (i < NN) {
        int base = p.boff[blockIdx.x] + wo[w] + incl - v;
        p.off0[i] = base;
        unsigned run = (unsigned)base;
        int s = 0;
#pragma unroll
        for (int c = 0; c < BCH; c++) {
            p.cb0[(size_t)c * NN + i] = run;
            run += p.degc_i[(size_t)c * NN + i];
            s += p.degc_o[(size_t)c * NN + i];
        }
        p.dsum[i] = s;
    }
}

// ---------- CSR scatter0: own kernel (low VGPR -> high occupancy) ----------
#define GB_E 3125
__global__ __launch_bounds__(256) void k_scat0(P p) {
    int e = blockIdx.x * 256 + threadIdx.x;
    if (e >= EE) return;
    int c = e / EPC;
    int d = p.dst[e];
    unsigned pos = p.cb0[(size_t)c * NN + d] + (unsigned)p.rank[e];
    p.csr_src[pos] = p.src[e];
}

// ---------- gemm0 (+ b0wc prep micro-block) ----------
#define G0B 782            // 2 x 391 gemm blocks
__global__ __launch_bounds__(256) void k_gemm0(P p) {
    int blk = blockIdx.x;
    if (blk < G0B) {
        gemm_body(p.feature, p.W0, p.z0, NN, FIN, p.al0, p.ar0, p.el0, p.er0,
                  p.Wc0, p.q4, blk & 1, blk >> 1);
    } else {
        int l = threadIdx.x;
        if (l < 64) {
            float t = p.b0[l] * p.Wc0[l] + p.b0[l + 64] * p.Wc0[l + 64];
#pragma unroll
            for (int o = 1; o < 64; o <<= 1) t += __shfl_xor(t, o);
            if (l == 0) p.b0wc[0] = t;
        }
    }
}

// ---------- layer-0 softmax + SCALAR q-gather (all nodes) ----------
__global__ __launch_bounds__(256) void k_fgatlite(
    const int* __restrict__ off, const int* __restrict__ csrs,
    const float* __restrict__ el, const float* __restrict__ er,
    const float* __restrict__ q4, const int* __restrict__ dsum,
    const float* __restrict__ b0wc,
    float* __restrict__ hc, float* __restrict__ m0f, float* __restrict__ s0f) {
    int wv = threadIdx.x >> 6, lane = threadIdx.x & 63;
    int v = blockIdx.x * 4 + wv;
    int b = off[v], e = off[v + 1], deg = e - b;
    int h = lane >> 4, sub = lane & 15;
    float erh = er[(size_t)v * 4 + h];
    float m = NEGF;
    for (int li = sub; li < deg; li += 16) {
        int s = csrs[b + li];
        m = fmaxf(m, lrelu(el[(size_t)s * 4 + h] + erh));
    }
#pragma unroll
    for (int o = 1; o < 16; o <<= 1) m = fmaxf(m, __shfl_xor(m, o));
    float ssum = 0.f, hq = 0.f;
    for (int li = sub; li < deg; li += 16) {
        int s = csrs[b + li];
        float ex = expf(lrelu(el[(size_t)s * 4 + h] + erh) - m);
        ssum += ex;
        hq = fmaf(ex, q4[(size_t)s * 4 + h], hq);
    }
#pragma unroll
    for (int o = 1; o < 16; o <<= 1) { ssum += __shfl_xor(ssum, o); hq += __shfl_xor(hq, o); }
    if (sub == 0) { m0f[v * 4 + h] = m; s0f[v * 4 + h] = ssum; }
    float t = hq / fmaxf(ssum, 1e-16f);
    t += __shfl_xor(t, 16);
    t += __shfl_xor(t, 32);
    if (lane == 0)
        hc[v] = (t + b0wc[0]) / sqrtf(fmaxf((float)dsum[v], 1.f));
}

// ---------- SAGPool score -> keys ----------
__global__ __launch_bounds__(256) void k_score(P p) {
    int v = blockIdx.x * blockDim.x + threadIdx.x;
    if (v >= NN) return;
    int b = p.off0[v], en = p.off0[v + 1];
    float acc = 0.f;
    for (int i = b; i < en; i++) acc += p.hc[p.csr_src[i]];
    float dg = fmaxf((float)(en - b), 1.f);
    float sc = acc / sqrtf(dg) + p.bc0[0];
    p.keys[v] = fkey(sc);
}

// ---------- hi-16 histogram: per-block u16-packed LDS (two 64KB half-passes) ----------
#define HB 49              // ceil(NN/1024)
__global__ __launch_bounds__(1024) void k_h0(P p) {
    __shared__ unsigned hist[16384];     // 64 KB: 32768 bins u16-packed per half
    int i = blockIdx.x * 1024 + (int)threadIdx.x;
    unsigned key = (i < NN) ? p.keys[i] : 0xFFFFFFFFu;  // sentinel: never counted
    unsigned b16 = key >> 16;
#pragma unroll
    for (int half = 0; half < 2; half++) {
        for (int w = threadIdx.x; w < 16384; w += 1024) hist[w] = 0u;
        __syncthreads();
        if (i < NN && (int)(b16 >> 15) == half) {
            unsigned bb = b16 & 0x7FFFu;
            atomicAdd(&hist[bb >> 1], 1u << (16u * (bb & 1u)));
        }
        __syncthreads();
        for (int w = threadIdx.x; w < 16384; w += 1024) {
            unsigned hv = hist[w];
            unsigned lo = hv & 0xFFFFu, hi = hv >> 16;
            if (lo) atomicAdd(&p.binsHi[half * 32768 + 2 * w], lo);
            if (hi) atomicAdd(&p.binsHi[half * 32768 + 2 * w + 1], hi);
        }
        __syncthreads();
    }
}

// ---------- lo-16 histogram among hi-bin candidates ----------
__global__ __launch_bounds__(1024) void k_h1(P p) {
    __shared__ unsigned hist[16384];
    int i = blockIdx.x * 1024 + (int)threadIdx.x;
    unsigned hib = p.rs[2];
    unsigned key = (i < NN) ? p.keys[i] : 0u;
    int cand = (i < NN) && ((key >> 16) == hib);
    unsigned b16 = key & 0xFFFFu;
#pragma unroll
    for (int half = 0; half < 2; half++) {
        for (int w = threadIdx.x; w < 16384; w += 1024) hist[w] = 0u;
        __syncthreads();
        if (cand && (int)(b16 >> 15) == half) {
            unsigned bb = b16 & 0x7FFFu;
            atomicAdd(&hist[bb >> 1], 1u << (16u * (bb & 1u)));
        }
        __syncthreads();
        for (int w = threadIdx.x; w < 16384; w += 1024) {
            unsigned hv = hist[w];
            unsigned lo = hv & 0xFFFFu, hi = hv >> 16;
            if (lo) atomicAdd(&p.binsLo[half * 32768 + 2 * w], lo);
            if (hi) atomicAdd(&p.binsLo[half * 32768 + 2 * w + 1], hi);
        }
        __syncthreads();
    }
}

// ---------- radix pick: 1 block scans 65536 bins ----------
__global__ __launch_bounds__(1024) void k_rsel2(P p, int level) {
    const unsigned* bins = level ? p.binsLo : p.binsHi;
    int K = level ? (int)p.rs[3] : KK;
    __shared__ unsigned wsm[16];
    __shared__ unsigned wpre[17];
    int t = threadIdx.x;
    unsigned base = (unsigned)t * 64;
    const uint4* b4 = (const uint4*)(bins + base);
    unsigned S = 0;
#pragma unroll
    for (int i = 0; i < 16; i++) {
        uint4 u = b4[i];
        S += u.x + u.y + u.z + u.w;
    }
    int lane = t & 63, w = t >> 6;
    unsigned val = S;
    for (int o = 1; o < 64; o <<= 1) { unsigned u = __shfl_up(val, o); if (lane >= o) val += u; }
    if (lane == 63) wsm[w] = val;
    __syncthreads();
    if (t == 0) { unsigned a = 0; for (int i = 0; i < 16; i++) { wpre[i] = a; a += wsm[i]; } wpre[16] = a; }
    __syncthreads();
    unsigned incl = wpre[w] + val;
    unsigned running = wpre[16] - incl;    // keys in strictly higher bins
    for (int i = 63; i >= 0; i--) {
        unsigned c = bins[base + i];
        unsigned above = running;
        running += c;
        if ((int)above < K && (int)running >= K) {
            if (level == 0) { p.rs[2] = base + (unsigned)i; p.rs[3] = (unsigned)(K - (int)above); }
            else { p.rs[0] = (p.rs[2] << 16) | (base + (unsigned)i); p.rs[1] = (unsigned)(K - (int)above); }
        }
    }
}

// ---------- parallel tie counting ----------
__global__ __launch_bounds__(256) void k_tcnt(P p) {
    __shared__ int ws[4];
    int v = blockIdx.x * 256 + (int)threadIdx.x;
    int flag = (v < NN && p.keys[v] == p.rs[0]) ? 1 : 0;
    unsigned long long m = __ballot(flag);
    int lane = threadIdx.x & 63, w = threadIdx.x >> 6;
    if (lane == 0) ws[w] = __popcll(m);
    __syncthreads();
    if (threadIdx.x == 0) p.bsum[blockIdx.x] = ws[0] + ws[1] + ws[2] + ws[3];
}

// ---------- list build: select + lowest-index tie ranks inline ----------
__global__ __launch_bounds__(256) void k_list(P p) {
    __shared__ int pre0;
    __shared__ int ws[4];
    int blk = blockIdx.x, tid = threadIdx.x;
    unsigned pivot = p.rs[0];
    int need = (int)p.rs[1];
    int v = blk * 256 + tid;
    unsigned k = (v < NN) ? p.keys[v] : 0u;
    int flag = (v < NN && k == pivot) ? 1 : 0;
    unsigned long long mask = __ballot(flag);
    int lane = tid & 63, w = tid >> 6;
    if (lane == 0) ws[w] = __popcll(mask);
    if (tid == 0) {
        int s = 0;
        for (int b2 = 0; b2 < blk; b2++) s += p.bsum[b2];
        pre0 = s;
    }
    __syncthreads();
    int woff = 0;
    for (int i = 0; i < w; i++) woff += ws[i];
    int rank = pre0 + woff + __popcll(mask & ((1ull << lane) - 1ull));
    if (v < NN) {
        int selv = (k > pivot) || (flag && rank < need);
        if (selv) {
            int idx = atomicAdd(p.cnt, 1);
            p.list[idx] = v;
            p.slot[v] = idx;
            p.tscale[idx] = tanhf(unfkey(k));
        } else {
            p.slot[v] = -1;
        }
    }
}

// ---------- full x for SELECTED nodes only ----------
__global__ __launch_bounds__(256) void k_fgatx(
    const int* __restrict__ list, const float* __restrict__ tscale,
    const int* __restrict__ off, const int* __restrict__ csrs,
    const float* __restrict__ el, const float* __restrict__ er,
    const float* __restrict__ m0f, const float* __restrict__ s0f,
    const float* __restrict__ z, const float* __restrict__ b0,
    float* __restrict__ xk) {
    __shared__ int ssrc[4][CW];
    __shared__ float sexp[4][CW][4];
    int wv = threadIdx.x >> 6, lane = threadIdx.x & 63;
    int i = blockIdx.x * 4 + wv;
    int v = list[i];
    int b = off[v], e = off[v + 1], deg = e - b;
    int h = lane >> 4, sub = lane & 15;
    float erh = er[(size_t)v * 4 + h];
    float mh = m0f[v * 4 + h];
    for (int li = sub; li < deg; li += 16) {
        int s = csrs[b + li];
        if (h == 0 && li < CW) ssrc[wv][li] = s;
        if (li < CW) sexp[wv][li][h] = expf(lrelu(el[(size_t)s * 4 + h] + erh) - mh);
    }
    __syncthreads();
    int h0 = lane >> 5, h1 = h0 + 2;
    float s0 = s0f[v * 4 + h0], s1 = s0f[v * 4 + h1];
    float m0 = m0f[v * 4 + h0], m1 = m0f[v * 4 + h1];
    float er0v = er[(size_t)v * 4 + h0], er1v = er[(size_t)v * 4 + h1];
    int c0 = lane, c1 = lane + 64;
    float acc0 = 0.f, acc1 = 0.f;
    for (int li = 0; li < deg; li++) {
        int s; float w0, w1;
        if (li < CW) {
            s = ssrc[wv][li];
            w0 = sexp[wv][li][h0]; w1 = sexp[wv][li][h1];
        } else {
            s = csrs[b + li];
            w0 = expf(lrelu(el[(size_t)s * 4 + h0] + er0v) - m0);
            w1 = expf(lrelu(el[(size_t)s * 4 + h1] + er1v) - m1);
        }
        int su = __builtin_amdgcn_readfirstlane(s);
        const float* zr = z + (size_t)su * HD;
        acc0 = fmaf(w0, zr[c0], acc0);
        acc1 = fmaf(w1, zr[c1], acc1);
    }
    float ts = tscale[i];
    float* xr = xk + (size_t)i * HD;
    xr[c0] = (acc0 / fmaxf(s0, 1e-16f) + b0[c0]) * ts;
    xr[c1] = (acc1 / fmaxf(s1, 1e-16f) + b0[c1]) * ts;
}

// ---------- pure gemm1 ----------
#define G1B 392
__global__ __launch_bounds__(256) void k_gemm1(P p) {
    gemm_body(p.xk, p.W1, p.z1, KK, HD, p.al1, p.ar1, p.el1, p.er1,
              nullptr, nullptr, blockIdx.x & 1, blockIdx.x >> 1);
}

// ---------- layer-1 fused GAT: reuses LAYER-0 CSR, filters by slot ----------
__global__ __launch_bounds__(256) void k_fgat2(P p) {
    __shared__ int ssrc[4][CW];
    __shared__ float sexp[4][CW][4];
    int wv = threadIdx.x >> 6, lane = threadIdx.x & 63;
    int i = blockIdx.x * 4 + wv;          // slot index
    int v = p.list[i];                    // original node id
    int b = p.off0[v], e = p.off0[v + 1], deg = e - b;
    int h = lane >> 4, sub = lane & 15;
    float4 er4 = *(const float4*)(p.er1 + (size_t)i * 4);
    float erh = ((const float*)&er4)[h];
    float m = NEGF;
    for (int li = sub; li < deg; li += 16) {
        int so = p.csr_src[b + li];
        int ss = p.slot[so];
        if (h == 0 && li < CW) ssrc[wv][li] = ss;
        if (ss >= 0) m = fmaxf(m, lrelu(p.el1[(size_t)ss * 4 + h] + erh));
    }
#pragma unroll
    for (int o = 1; o < 16; o <<= 1) m = fmaxf(m, __shfl_xor(m, o));
    float ssum = 0.f;
    for (int li = sub; li < deg; li += 16) {
        int so = p.csr_src[b + li];
        int ss = p.slot[so];
        float x = (ss >= 0) ? expf(lrelu(p.el1[(size_t)ss * 4 + h] + erh) - m) : 0.f;
        if (li < CW) sexp[wv][li][h] = x;
        ssum += x;
    }
#pragma unroll
    for (int o = 1; o < 16; o <<= 1) ssum += __shfl_xor(ssum, o);
    if (sub == 0) { p.m1f[i * 4 + h] = m; p.s1f[i * 4 + h] = ssum; }
    __syncthreads();
    int h0 = lane >> 5, h1 = h0 + 2;
    float m0 = __shfl(m, h0 << 4), m1 = __shfl(m, h1 << 4);
    float s0 = __shfl(ssum, h0 << 4), s1 = __shfl(ssum, h1 << 4);
    int c0 = lane, c1 = lane + 64;
    float acc0 = 0.f, acc1 = 0.f;
    for (int li = 0; li < deg; li++) {
        int s; float w0, w1;
        if (li < CW) {
            s = ssrc[wv][li];
            if (s < 0) continue;
            w0 = sexp[wv][li][h0]; w1 = sexp[wv][li][h1];
        } else {
            int so = p.csr_src[b + li];
            s = p.slot[so];
            if (s < 0) continue;
            w0 = expf(lrelu(p.el1[(size_t)s * 4 + h0] + ((const float*)&er4)[h0]) - m0);
            w1 = expf(lrelu(p.el1[(size_t)s * 4 + h1] + ((const float*)&er4)[h1]) - m1);
        }
        int su = __builtin_amdgcn_readfirstlane(s);
        const float* zr = p.z1 + (size_t)su * HD;
        acc0 = fmaf(w0, zr[c0], acc0);
        acc1 = fmaf(w1, zr[c1], acc1);
    }
    float xc0 = acc0 / fmaxf(s0, 1e-16f) + p.b1[c0];
    float xc1 = acc1 / fmaxf(s1, 1e-16f) + p.b1[c1];
    float t = xc0 + xc1;
    t += __shfl_xor(t, 32);
    float pg = 0.f;
    if (lane < 32) {
        float r = 0.25f * t;
        p.res[(size_t)i * 32 + lane] = r;
        pg = r * p.gW[lane];
    }
#pragma unroll
    for (int o = 1; o < 32; o <<= 1) pg += __shfl_xor(pg, o);
    if (lane == 0) p.g[i] = pg + p.gb[0];
}

// ---------- MERGED: per-edge alpha outputs || gmax ----------
__global__ __launch_bounds__(256) void k_eg(P p) {
    int blk = blockIdx.x;
    if (blk < GB_E) {
        int e = blk * 256 + (int)threadIdx.x;
        if (e >= EE) return;
        int ds = p.slot[p.src[e]], dd = p.slot[p.dst[e]];
        float a[4] = {0.f, 0.f, 0.f, 0.f};
        float st = 0.f;
        if (ds >= 0 && dd >= 0) {
            float4 es = *(const float4*)(p.el1 + ds * 4);
            float4 ed = *(const float4*)(p.er1 + dd * 4);
            float l[4] = {lrelu(es.x + ed.x), lrelu(es.y + ed.y), lrelu(es.z + ed.z), lrelu(es.w + ed.w)};
#pragma unroll
            for (int h = 0; h < 4; h++) {
                float m = p.m1f[dd * 4 + h];
                float ex = expf(l[h] - m);
                a[h] = ex / fmaxf(p.s1f[dd * 4 + h], 1e-16f);
            }
            st = p.strength[e];
        }
        float* o = p.out + ATT_OFF + (size_t)e * 4;
        *(float2*)(o) = make_float2(a[0], a[1]);
        *(float2*)(o + 2) = make_float2(a[2], a[3]);
        p.out[STR_OFF + e] = st;
    } else {
        __shared__ float red[256];
        int t = threadIdx.x;
        float m = -3.4e38f;
        for (int i = (blk - GB_E) * 256 + t; i < KK; i += 98 * 256) m = fmaxf(m, p.g[i]);
        red[t] = m;
        __syncthreads();
        for (int o = 128; o > 0; o >>= 1) { if (t < o) red[t] = fmaxf(red[t], red[t + o]); __syncthreads(); }
        if (t == 0) atomicMax(p.gmaxk, fkey(red[0]));   // memset-0 identity ok
    }
}

#define WSUM_BLOCKS 104
__global__ __launch_bounds__(256) void k_wsum(P p) {
    __shared__ double vred[256];
    __shared__ double zred[8];
    int t = threadIdx.x, il = t >> 5, d = t & 31;
    float gm = unfkey(*p.gmaxk);
    double accv = 0.0, accw = 0.0;
    for (int i = blockIdx.x * 8 + il; i < KK; i += WSUM_BLOCKS * 8) {
        float w = expf(p.g[i] - gm);
        accv += (double)(w * p.res[(size_t)i * 32 + d]);
        if (d == 0) accw += (double)w;
    }
    vred[t] = accv;
    if (d == 0) zred[il] = accw;
    __syncthreads();
    if (il == 0) {
        double s = 0;
#pragma unroll
        for (int k2 = 0; k2 < 8; k2++) s += vred[k2 * 32 + d];
        atomicAdd(&p.racc[d], s);
    }
    if (t == 32) {
        double z2 = 0;
#pragma unroll
        for (int k2 = 0; k2 < 8; k2++) z2 += zred[k2];
        atomicAdd(p.Zacc, z2);
    }
}
__global__ void k_final(P p) {
    __shared__ float rb[32];
    int t = threadIdx.x;
    double Z = *p.Zacc;
    if (t < 32) {
        float r = (float)(p.racc[t] / Z);
        p.out[t] = r;
        rb[t] = r;
    }
    __syncthreads();
    if (t < 2) {
        float s = 0.f;
        for (int d = 0; d < 32; d++) s += rb[d] * p.cW[d * 2 + t];
        p.out[32 + t] = s + p.cb[t];
    }
}

// ---------- host ----------
extern "C" void kernel_launch(void* const* d_in, const int* in_sizes, int n_in,
                              void* d_out, int out_size, void* d_ws, size_t ws_size,
                              hipStream_t stream) {
    (void)in_sizes; (void)n_in; (void)out_size; (void)ws_size;
    P p;
    p.feature  = (const float*)d_in[0];
    p.strength = (const float*)d_in[1];
    p.W0  = (const float*)d_in[2];  p.b0  = (const float*)d_in[3];
    p.al0 = (const float*)d_in[4];  p.ar0 = (const float*)d_in[5];
    p.Wc0 = (const float*)d_in[6];  p.bc0 = (const float*)d_in[7];
    p.W1  = (const float*)d_in[8];  p.b1  = (const float*)d_in[9];
    p.al1 = (const float*)d_in[10]; p.ar1 = (const float*)d_in[11];
    p.gW  = (const float*)d_in[12]; p.gb  = (const float*)d_in[13];
    p.cW  = (const float*)d_in[14]; p.cb  = (const float*)d_in[15];
    p.src = (const int*)d_in[16];   p.dst = (const int*)d_in[17];
    p.out = (float*)d_out;

    char* ws = (char*)d_ws;
    size_t off = 0;
    auto alloc = [&](size_t bytes) -> void* {
        void* r = ws + off;
        off = (off + bytes + 255) & ~(size_t)255;
        return r;
    };
    // ---- zeroed region (must stay first/contiguous) ----
    p.Zacc  = (double*)alloc(8);
    p.racc  = (double*)alloc(32 * 8);
    p.cnt   = (int*)alloc(4);
    p.gmaxk = (unsigned*)alloc(4);
    p.rs    = (unsigned*)alloc(16);
    p.binsHi = (unsigned*)alloc(65536 * 4);
    p.binsLo = (unsigned*)alloc(65536 * 4);
    size_t zbytes = off;
    // ---- big buffers (fully overwritten each run) ----
    p.degc_i = (unsigned char*)alloc((size_t)BCH * NN);
    p.degc_o = (unsigned char*)alloc((size_t)BCH * NN);
    p.cb0 = (unsigned*)alloc((size_t)BCH * NN * 4);
    p.dsum = (int*)alloc((size_t)NN * 4);
    p.z0 = (float*)alloc((size_t)NN * HD * 4);
    p.xk = (float*)alloc((size_t)KK * HD * 4);
    p.z1 = (float*)alloc((size_t)KK * HD * 4);
    p.csr_src = (int*)alloc((size_t)EE * 4);
    p.rank    = (int*)alloc((size_t)EE * 4);
    p.el0 = (float*)alloc((size_t)NN * 4 * 4);
    p.er0 = (float*)alloc((size_t)NN * 4 * 4);
    p.q4  = (float*)alloc((size_t)NN * 4 * 4);
    p.m0f = (float*)alloc((size_t)NN * 4 * 4);
    p.s0f = (float*)alloc((size_t)NN * 4 * 4);
    p.b0wc = (float*)alloc(4);
    p.off0 = (int*)alloc((size_t)(NN + 1) * 4);
    p.bsum = (int*)alloc(256 * 4);
    p.boff = (int*)alloc(256 * 4);
    p.hc    = (float*)alloc((size_t)NN * 4);
    p.keys  = (unsigned*)alloc((size_t)NN * 4);
    p.slot  = (int*)alloc((size_t)NN * 4);
    p.list  = (int*)alloc((size_t)KK * 4);
    p.tscale = (float*)alloc((size_t)KK * 4);
    p.el1 = (float*)alloc((size_t)KK * 4 * 4);
    p.er1 = (float*)alloc((size_t)KK * 4 * 4);
    p.m1f = (float*)alloc((size_t)KK * 4 * 4);
    p.s1f = (float*)alloc((size_t)KK * 4 * 4);
    p.res = (float*)alloc((size_t)KK * DD * 4);
    p.g   = (float*)alloc((size_t)KK * 4);

    const int GB_N = (NN + 255) / 256;        // 196

    hipMemsetAsync(d_ws, 0, zbytes, stream);

    // ---- GAT layer 0: count -> scan -> scatter0 -> gemm0 -> fgatlite ----
    k_count0<<<256, 256, 0, stream>>>(p);
    k_bsum<<<GB_N, 256, 0, stream>>>(p.degc_i, p.bsum, NN, NN);
    k_bscan<<<1, 256, 0, stream>>>(p.bsum, GB_N, p.boff, p.off0, NN);
    k_fscan0<<<GB_N, 256, 0, stream>>>(p);
    k_scat0<<<GB_E, 256, 0, stream>>>(p);
    k_gemm0<<<G0B + 1, 256, 0, stream>>>(p);
    k_fgatlite<<<NN / 4, 256, 0, stream>>>(p.off0, p.csr_src, p.el0, p.er0, p.q4,
                                           p.dsum, p.b0wc, p.hc, p.m0f, p.s0f);

    // ---- SAGPool: stream-ordered select ----
    k_score<<<GB_N, 256, 0, stream>>>(p);
    k_h0<<<HB, 1024, 0, stream>>>(p);
    k_rsel2<<<1, 1024, 0, stream>>>(p, 0);
    k_h1<<<HB, 1024, 0, stream>>>(p);
    k_rsel2<<<1, 1024, 0, stream>>>(p, 1);
    k_tcnt<<<GB_N, 256, 0, stream>>>(p);
    k_list<<<GB_N, 256, 0, stream>>>(p);

    // ---- GAT layer 1: fgatx -> gemm1 -> fgat2 (layer-0 CSR reused) ----
    k_fgatx<<<KK / 4, 256, 0, stream>>>(p.list, p.tscale, p.off0, p.csr_src,
                                        p.el0, p.er0, p.m0f, p.s0f, p.z0, p.b0, p.xk);
    k_gemm1<<<G1B, 256, 0, stream>>>(p);
    k_fgat2<<<KK / 4, 256, 0, stream>>>(p);

    // ---- edge outputs || gmax, then readout ----
    k_eg<<<GB_E + 98, 256, 0, stream>>>(p);
    k_wsum<<<WSUM_BLOCKS, 256, 0, stream>>>(p);
    k_final<<<1, 64, 0, stream>>>(p);
}

// Round 10
// 533.478 us; speedup vs baseline: 2.5436x; 1.0958x over previous
//
#include <hip/hip_runtime.h>
#include <stdint.h>

#define NN 50000
#define EE 800000
#define FIN 256
#define HD 128
#define DD 32
#define KK 25000
#define SLOPEF 0.4f
#define NEGF (-1e9f)
#define ATT_OFF 34
#define STR_OFF (34 + EE * 4)
#define CW 128             // LDS-cached edges per node (deg ~Poisson(16); recompute fallback)

// counting-sort CSR build (layer 0 only; layer 1 reuses it via slot-filtering)
#define BCH 32             // edge chunks
#define EPC (EE / BCH)     // 25000 edges per chunk
#define NRQ 12500          // node-range quarter for count blocks (4 x 12500 = NN)

// ---------- helpers ----------
__device__ __forceinline__ unsigned fkey(float x) {
    unsigned u = __float_as_uint(x);
    return (u & 0x80000000u) ? ~u : (u | 0x80000000u);   // monotone float->uint
}
__device__ __forceinline__ float unfkey(unsigned k) {
    unsigned u = (k & 0x80000000u) ? (k ^ 0x80000000u) : ~k;
    return __uint_as_float(u);
}
__device__ __forceinline__ float lrelu(float v) { return v > 0.f ? v : SLOPEF * v; }

// ---------- pointer bundle ----------
struct P {
    // inputs
    const float *feature, *strength, *W0, *b0, *al0, *ar0, *Wc0, *bc0;
    const float *W1, *b1, *al1, *ar1, *gW, *gb, *cW, *cb;
    const int *src, *dst;
    // zeroed scratch
    double *Zacc, *racc;
    int *cnt;
    unsigned *gmaxk;
    unsigned *rs;                 // [0]=pivot,[1]=need,[2]=hi bin,[3]=hi remaining
    unsigned *binsHi, *binsLo;    // 65536 u32 bins each
    // other scratch
    unsigned *keys;
    unsigned char *degc_i, *degc_o;   // per-(chunk,node) u8 counts [BCH][NN]
    unsigned *cb0;                // per-(chunk,node) CSR base cursors
    int *dsum;                    // out-degree totals
    int *csr_src, *rank, *off0, *slot, *list, *bsum, *boff;
    float *z0, *el0, *er0, *q4, *m0f, *s0f, *b0wc, *hc, *xk, *z1;
    float *el1, *er1, *m1f, *s1f, *res, *g, *tscale;
    float *out;                   // d_out (float32)
};

// ---------- fp32 tiled GEMM body: C[M,128] = A[M,Kd] @ B[Kd,128] ----------
// R7 single-buffered version. R8/R9 lesson: source-level double-buffering
// spills on this body (compiler-defeated, cf. learn_hip m99/m100) — keep
// the simple 2-barrier loop; 80 us / 116 VGPR / no scratch is its floor.
#define BM 128
#define BN 64
#define BK 16
__device__ void gemm_body(
    const float* __restrict__ A, const float* __restrict__ B, float* __restrict__ C,
    int M, int Kd,
    const float* __restrict__ al, const float* __restrict__ ar,
    float* __restrict__ el, float* __restrict__ er,
    const float* __restrict__ Wc, float* __restrict__ q4,
    int bx, int by) {
    __shared__ float As[BK][BM + 4];
    __shared__ float Bs[BK][BN];
    int bm = by * BM, bn = bx * BN;
    int tid = threadIdx.x;
    int tr = tid >> 4, tc = tid & 15;
    int lrow = tid >> 1;
    int arow = (bm + lrow < M) ? (bm + lrow) : -1;
    float acc[8][4] = {};
    for (int k0 = 0; k0 < Kd; k0 += BK) {
        {
            int col = (tid & 1) << 3;
            float4 v0 = {0.f,0.f,0.f,0.f}, v1 = {0.f,0.f,0.f,0.f};
            if (arow >= 0) {
                const float* ap = A + (size_t)arow * Kd + k0 + col;
                v0 = *(const float4*)ap; v1 = *(const float4*)(ap + 4);
            }
            As[col + 0][lrow] = v0.x; As[col + 1][lrow] = v0.y;
            As[col + 2][lrow] = v0.z; As[col + 3][lrow] = v0.w;
            As[col + 4][lrow] = v1.x; As[col + 5][lrow] = v1.y;
            As[col + 6][lrow] = v1.z; As[col + 7][lrow] = v1.w;
        }
        {
            int kr = tid >> 4, col = (tid & 15) << 2;
            float4 v = *(const float4*)(B + (size_t)(k0 + kr) * HD + bn + col);
            *(float4*)&Bs[kr][col] = v;
        }
        __syncthreads();
#pragma unroll
        for (int kk = 0; kk < BK; kk++) {
            float a[8], b[4];
#pragma unroll
            for (int i = 0; i < 8; i++) a[i] = As[kk][tr * 8 + i];
#pragma unroll
            for (int j = 0; j < 4; j++) b[j] = Bs[kk][tc * 4 + j];
#pragma unroll
            for (int i = 0; i < 8; i++)
#pragma unroll
                for (int j = 0; j < 4; j++) acc[i][j] = fmaf(a[i], b[j], acc[i][j]);
        }
        __syncthreads();
    }
#pragma unroll
    for (int i = 0; i < 8; i++) {
        int gr = bm + tr * 8 + i;
        if (gr < M) {
            float4 v = {acc[i][0], acc[i][1], acc[i][2], acc[i][3]};
            *(float4*)(C + (size_t)gr * HD + bn + tc * 4) = v;
        }
    }
    int head = bx * 2 + (tc >> 3);
    int dbase = (tc & 7) * 4;
    const float* alh = al + head * 32 + dbase;
    const float* arh = ar + head * 32 + dbase;
    float a0 = alh[0], a1 = alh[1], a2 = alh[2], a3 = alh[3];
    float r0 = arh[0], r1 = arh[1], r2 = arh[2], r3 = arh[3];
    float w0 = 0.f, w1 = 0.f, w2 = 0.f, w3 = 0.f;
    if (Wc) {
        const float* wch = Wc + head * 32 + dbase;
        w0 = wch[0]; w1 = wch[1]; w2 = wch[2]; w3 = wch[3];
    }
#pragma unroll
    for (int i = 0; i < 8; i++) {
        int gr = bm + tr * 8 + i;
        float pe = acc[i][0]*a0 + acc[i][1]*a1 + acc[i][2]*a2 + acc[i][3]*a3;
        float pr = acc[i][0]*r0 + acc[i][1]*r1 + acc[i][2]*r2 + acc[i][3]*r3;
        float pq = acc[i][0]*w0 + acc[i][1]*w1 + acc[i][2]*w2 + acc[i][3]*w3;
#pragma unroll
        for (int o = 1; o < 8; o <<= 1) {
            pe += __shfl_xor(pe, o); pr += __shfl_xor(pr, o); pq += __shfl_xor(pq, o);
        }
        if ((tc & 7) == 0 && gr < M) {
            el[gr * 4 + head] = pe; er[gr * 4 + head] = pr;
            if (Wc) q4[gr * 4 + head] = pq;
        }
    }
}

// ---------- layer-0 count: (chunk x node-quarter) u8 LDS histogram, int4 loads ----------
__global__ __launch_bounds__(256) void k_count0(P p) {
    __shared__ unsigned hist[NRQ / 4];        // 12500 u8 counters
    int blk = blockIdx.x;
    int isD = blk < 128;
    int c = blk & 31, rq = (blk >> 5) & 3;
    int nbase = rq * NRQ;
    for (int w = threadIdx.x; w < NRQ / 4; w += 256) hist[w] = 0u;
    __syncthreads();
    int j0 = c * (EPC / 4), j1 = j0 + (EPC / 4);
    if (isD) {
        const int4* d4 = (const int4*)p.dst;
        for (int j = j0 + (int)threadIdx.x; j < j1; j += 256) {
            int4 dv = d4[j];
            int e = j * 4;
            int d, t;
            d = dv.x - nbase;
            if ((unsigned)d < (unsigned)NRQ) {
                unsigned sh = (unsigned)(d & 3) * 8u;
                t = (int)((atomicAdd(&hist[d >> 2], 1u << sh) >> sh) & 0xffu);
                p.rank[e + 0] = t;
            }
            d = dv.y - nbase;
            if ((unsigned)d < (unsigned)NRQ) {
                unsigned sh = (unsigned)(d & 3) * 8u;
                t = (int)((atomicAdd(&hist[d >> 2], 1u << sh) >> sh) & 0xffu);
                p.rank[e + 1] = t;
            }
            d = dv.z - nbase;
            if ((unsigned)d < (unsigned)NRQ) {
                unsigned sh = (unsigned)(d & 3) * 8u;
                t = (int)((atomicAdd(&hist[d >> 2], 1u << sh) >> sh) & 0xffu);
                p.rank[e + 2] = t;
            }
            d = dv.w - nbase;
            if ((unsigned)d < (unsigned)NRQ) {
                unsigned sh = (unsigned)(d & 3) * 8u;
                t = (int)((atomicAdd(&hist[d >> 2], 1u << sh) >> sh) & 0xffu);
                p.rank[e + 3] = t;
            }
        }
    } else {
        const int4* s4 = (const int4*)p.src;
        for (int j = j0 + (int)threadIdx.x; j < j1; j += 256) {
            int4 sv = s4[j];
            int s;
            s = sv.x - nbase;
            if ((unsigned)s < (unsigned)NRQ) atomicAdd(&hist[s >> 2], 1u << ((unsigned)(s & 3) * 8u));
            s = sv.y - nbase;
            if ((unsigned)s < (unsigned)NRQ) atomicAdd(&hist[s >> 2], 1u << ((unsigned)(s & 3) * 8u));
            s = sv.z - nbase;
            if ((unsigned)s < (unsigned)NRQ) atomicAdd(&hist[s >> 2], 1u << ((unsigned)(s & 3) * 8u));
            s = sv.w - nbase;
            if ((unsigned)s < (unsigned)NRQ) atomicAdd(&hist[s >> 2], 1u << ((unsigned)(s & 3) * 8u));
        }
    }
    __syncthreads();
    unsigned* o32 = (unsigned*)((isD ? p.degc_i : p.degc_o) + (size_t)c * NN + nbase);
    for (int w = threadIdx.x; w < NRQ / 4; w += 256) o32[w] = hist[w];
}

// ---------- two-level exclusive scan over node totals (stream-ordered) ----------
__global__ __launch_bounds__(256) void k_bsum(const unsigned char* __restrict__ deg,
                                              int* __restrict__ bsum, int n, int nn) {
    int i = blockIdx.x * 256 + threadIdx.x;
    int v = 0;
    if (i < n) {
#pragma unroll
        for (int c = 0; c < BCH; c++) v += deg[(size_t)c * nn + i];
    }
    int lane = threadIdx.x & 63, w = threadIdx.x >> 6;
    __shared__ int ws[4];
#pragma unroll
    for (int o = 1; o < 64; o <<= 1) v += __shfl_xor(v, o);
    if (lane == 0) ws[w] = v;
    __syncthreads();
    if (threadIdx.x == 0) bsum[blockIdx.x] = ws[0] + ws[1] + ws[2] + ws[3];
}
__global__ __launch_bounds__(256) void k_bscan(const int* __restrict__ bsum, int nb,
                                               int* __restrict__ boff,
                                               int* __restrict__ off, int n) {
    __shared__ int ws[4];
    __shared__ int wo[5];
    int t = threadIdx.x;
    int v = (t < nb) ? bsum[t] : 0;
    int lane = t & 63, w = t >> 6;
    int incl = v;
    for (int o = 1; o < 64; o <<= 1) { int u = __shfl_up(incl, o); if (lane >= o) incl += u; }
    if (lane == 63) ws[w] = incl;
    __syncthreads();
    if (t == 0) { int a = 0; for (int i = 0; i < 4; i++) { wo[i] = a; a += ws[i]; } wo[4] = a; }
    __syncthreads();
    if (t < nb) boff[t] = wo[w] + incl - v;
    if (t == 0) off[n] = wo[4];
}
// final scan: off0 + per-chunk bases cb0 + out-degree totals dsum
__global__ __launch_bounds__(256) void k_fscan0(P p) {
    __shared__ int ws[4];
    __shared__ int wo[4];
    int i = blockIdx.x * 256 + threadIdx.x;
    int v = 0;
    if (i < NN) {
#pragma unroll
        for (int c = 0; c < BCH; c++) v += p.degc_i[(size_t)c * NN + i];
    }
    int lane = threadIdx.x & 63, w = threadIdx.x >> 6;
    int incl = v;
    for (int o = 1; o < 64; o <<= 1) { int u = __shfl_up(incl, o); if (lane >= o) incl += u; }
    if (lane == 63) ws[w] = incl;
    __syncthreads();
    if (threadIdx.x == 0) { int a = 0; for (int k = 0; k < 4; k++) { wo[k] = a; a += ws[k]; } }
    __syncthreads();
    if (i < NN) {
        int base = p.boff[blockIdx.x] + wo[w] + incl - v;
        p.off0[i] = base;
        unsigned run = (unsigned)base;
        int s = 0;
#pragma unroll
        for (int c = 0; c < BCH; c++) {
            p.cb0[(size_t)c * NN + i] = run;
            run += p.degc_i[(size_t)c * NN + i];
            s += p.degc_o[(size_t)c * NN + i];
        }
        p.dsum[i] = s;
    }
}

// ---------- CSR scatter0: int4 (4 edges/thread; chunk uniform per int4) ----------
#define GB_E 3125
#define GB_E4 782
__global__ __launch_bounds__(256) void k_scat0(P p) {
    int j = blockIdx.x * 256 + threadIdx.x;
    if (j >= EE / 4) return;
    int c = j / (EPC / 4);
    int4 dv = ((const int4*)p.dst)[j];
    int4 sv = ((const int4*)p.src)[j];
    int4 rv = ((const int4*)p.rank)[j];
    const unsigned* cb = p.cb0 + (size_t)c * NN;
    p.csr_src[cb[dv.x] + (unsigned)rv.x] = sv.x;
    p.csr_src[cb[dv.y] + (unsigned)rv.y] = sv.y;
    p.csr_src[cb[dv.z] + (unsigned)rv.z] = sv.z;
    p.csr_src[cb[dv.w] + (unsigned)rv.w] = sv.w;
}

// ---------- gemm0 (+ b0wc prep micro-block) ----------
#define G0B 782            // 2 x 391 gemm blocks
__global__ __launch_bounds__(256) void k_gemm0(P p) {
    int blk = blockIdx.x;
    if (blk < G0B) {
        gemm_body(p.feature, p.W0, p.z0, NN, FIN, p.al0, p.ar0, p.el0, p.er0,
                  p.Wc0, p.q4, blk & 1, blk >> 1);
    } else {
        int l = threadIdx.x;
        if (l < 64) {
            float t = p.b0[l] * p.Wc0[l] + p.b0[l + 64] * p.Wc0[l + 64];
#pragma unroll
            for (int o = 1; o < 64; o <<= 1) t += __shfl_xor(t, o);
            if (l == 0) p.b0wc[0] = t;
        }
    }
}

// ---------- layer-0 softmax + SCALAR q-gather (all nodes) ----------
__global__ __launch_bounds__(256) void k_fgatlite(
    const int* __restrict__ off, const int* __restrict__ csrs,
    const float* __restrict__ el, const float* __restrict__ er,
    const float* __restrict__ q4, const int* __restrict__ dsum,
    const float* __restrict__ b0wc,
    float* __restrict__ hc, float* __restrict__ m0f, float* __restrict__ s0f) {
    int wv = threadIdx.x >> 6, lane = threadIdx.x & 63;
    int v = blockIdx.x * 4 + wv;
    int b = off[v], e = off[v + 1], deg = e - b;
    int h = lane >> 4, sub = lane & 15;
    float erh = er[(size_t)v * 4 + h];
    float m = NEGF;
    for (int li = sub; li < deg; li += 16) {
        int s = csrs[b + li];
        m = fmaxf(m, lrelu(el[(size_t)s * 4 + h] + erh));
    }
#pragma unroll
    for (int o = 1; o < 16; o <<= 1) m = fmaxf(m, __shfl_xor(m, o));
    float ssum = 0.f, hq = 0.f;
    for (int li = sub; li < deg; li += 16) {
        int s = csrs[b + li];
        float ex = expf(lrelu(el[(size_t)s * 4 + h] + erh) - m);
        ssum += ex;
        hq = fmaf(ex, q4[(size_t)s * 4 + h], hq);
    }
#pragma unroll
    for (int o = 1; o < 16; o <<= 1) { ssum += __shfl_xor(ssum, o); hq += __shfl_xor(hq, o); }
    if (sub == 0) { m0f[v * 4 + h] = m; s0f[v * 4 + h] = ssum; }
    float t = hq / fmaxf(ssum, 1e-16f);
    t += __shfl_xor(t, 16);
    t += __shfl_xor(t, 32);
    if (lane == 0)
        hc[v] = (t + b0wc[0]) / sqrtf(fmaxf((float)dsum[v], 1.f));
}

// ---------- SAGPool score -> keys ----------
__global__ __launch_bounds__(256) void k_score(P p) {
    int v = blockIdx.x * blockDim.x + threadIdx.x;
    if (v >= NN) return;
    int b = p.off0[v], en = p.off0[v + 1];
    float acc = 0.f;
    for (int i = b; i < en; i++) acc += p.hc[p.csr_src[i]];
    float dg = fmaxf((float)(en - b), 1.f);
    float sc = acc / sqrtf(dg) + p.bc0[0];
    p.keys[v] = fkey(sc);
}

// ---------- hi-16 histogram: per-block u16-packed LDS (two 64KB half-passes) ----------
#define HB 49              // ceil(NN/1024)
__global__ __launch_bounds__(1024) void k_h0(P p) {
    __shared__ unsigned hist[16384];     // 64 KB: 32768 bins u16-packed per half
    int i = blockIdx.x * 1024 + (int)threadIdx.x;
    unsigned key = (i < NN) ? p.keys[i] : 0xFFFFFFFFu;  // sentinel: never counted
    unsigned b16 = key >> 16;
#pragma unroll
    for (int half = 0; half < 2; half++) {
        for (int w = threadIdx.x; w < 16384; w += 1024) hist[w] = 0u;
        __syncthreads();
        if (i < NN && (int)(b16 >> 15) == half) {
            unsigned bb = b16 & 0x7FFFu;
            atomicAdd(&hist[bb >> 1], 1u << (16u * (bb & 1u)));
        }
        __syncthreads();
        for (int w = threadIdx.x; w < 16384; w += 1024) {
            unsigned hv = hist[w];
            unsigned lo = hv & 0xFFFFu, hi = hv >> 16;
            if (lo) atomicAdd(&p.binsHi[half * 32768 + 2 * w], lo);
            if (hi) atomicAdd(&p.binsHi[half * 32768 + 2 * w + 1], hi);
        }
        __syncthreads();
    }
}

// ---------- lo-16 histogram among hi-bin candidates ----------
__global__ __launch_bounds__(1024) void k_h1(P p) {
    __shared__ unsigned hist[16384];
    int i = blockIdx.x * 1024 + (int)threadIdx.x;
    unsigned hib = p.rs[2];
    unsigned key = (i < NN) ? p.keys[i] : 0u;
    int cand = (i < NN) && ((key >> 16) == hib);
    unsigned b16 = key & 0xFFFFu;
#pragma unroll
    for (int half = 0; half < 2; half++) {
        for (int w = threadIdx.x; w < 16384; w += 1024) hist[w] = 0u;
        __syncthreads();
        if (cand && (int)(b16 >> 15) == half) {
            unsigned bb = b16 & 0x7FFFu;
            atomicAdd(&hist[bb >> 1], 1u << (16u * (bb & 1u)));
        }
        __syncthreads();
        for (int w = threadIdx.x; w < 16384; w += 1024) {
            unsigned hv = hist[w];
            unsigned lo = hv & 0xFFFFu, hi = hv >> 16;
            if (lo) atomicAdd(&p.binsLo[half * 32768 + 2 * w], lo);
            if (hi) atomicAdd(&p.binsLo[half * 32768 + 2 * w + 1], hi);
        }
        __syncthreads();
    }
}

// ---------- radix pick: 1 block scans 65536 bins ----------
__global__ __launch_bounds__(1024) void k_rsel2(P p, int level) {
    const unsigned* bins = level ? p.binsLo : p.binsHi;
    int K = level ? (int)p.rs[3] : KK;
    __shared__ unsigned wsm[16];
    __shared__ unsigned wpre[17];
    int t = threadIdx.x;
    unsigned base = (unsigned)t * 64;
    const uint4* b4 = (const uint4*)(bins + base);
    unsigned S = 0;
#pragma unroll
    for (int i = 0; i < 16; i++) {
        uint4 u = b4[i];
        S += u.x + u.y + u.z + u.w;
    }
    int lane = t & 63, w = t >> 6;
    unsigned val = S;
    for (int o = 1; o < 64; o <<= 1) { unsigned u = __shfl_up(val, o); if (lane >= o) val += u; }
    if (lane == 63) wsm[w] = val;
    __syncthreads();
    if (t == 0) { unsigned a = 0; for (int i = 0; i < 16; i++) { wpre[i] = a; a += wsm[i]; } wpre[16] = a; }
    __syncthreads();
    unsigned incl = wpre[w] + val;
    unsigned running = wpre[16] - incl;    // keys in strictly higher bins
    for (int i = 63; i >= 0; i--) {
        unsigned c = bins[base + i];
        unsigned above = running;
        running += c;
        if ((int)above < K && (int)running >= K) {
            if (level == 0) { p.rs[2] = base + (unsigned)i; p.rs[3] = (unsigned)(K - (int)above); }
            else { p.rs[0] = (p.rs[2] << 16) | (base + (unsigned)i); p.rs[1] = (unsigned)(K - (int)above); }
        }
    }
}

// ---------- parallel tie counting ----------
__global__ __launch_bounds__(256) void k_tcnt(P p) {
    __shared__ int ws[4];
    int v = blockIdx.x * 256 + (int)threadIdx.x;
    int flag = (v < NN && p.keys[v] == p.rs[0]) ? 1 : 0;
    unsigned long long m = __ballot(flag);
    int lane = threadIdx.x & 63, w = threadIdx.x >> 6;
    if (lane == 0) ws[w] = __popcll(m);
    __syncthreads();
    if (threadIdx.x == 0) p.bsum[blockIdx.x] = ws[0] + ws[1] + ws[2] + ws[3];
}

// ---------- list build: select + lowest-index tie ranks inline ----------
__global__ __launch_bounds__(256) void k_list(P p) {
    __shared__ int pre0;
    __shared__ int ws[4];
    int blk = blockIdx.x, tid = threadIdx.x;
    unsigned pivot = p.rs[0];
    int need = (int)p.rs[1];
    int v = blk * 256 + tid;
    unsigned k = (v < NN) ? p.keys[v] : 0u;
    int flag = (v < NN && k == pivot) ? 1 : 0;
    unsigned long long mask = __ballot(flag);
    int lane = tid & 63, w = tid >> 6;
    if (lane == 0) ws[w] = __popcll(mask);
    if (tid == 0) {
        int s = 0;
        for (int b2 = 0; b2 < blk; b2++) s += p.bsum[b2];
        pre0 = s;
    }
    __syncthreads();
    int woff = 0;
    for (int i = 0; i < w; i++) woff += ws[i];
    int rank = pre0 + woff + __popcll(mask & ((1ull << lane) - 1ull));
    if (v < NN) {
        int selv = (k > pivot) || (flag && rank < need);
        if (selv) {
            int idx = atomicAdd(p.cnt, 1);
            p.list[idx] = v;
            p.slot[v] = idx;
            p.tscale[idx] = tanhf(unfkey(k));
        } else {
            p.slot[v] = -1;
        }
    }
}

// ---------- full x for SELECTED nodes only ----------
__global__ __launch_bounds__(256) void k_fgatx(
    const int* __restrict__ list, const float* __restrict__ tscale,
    const int* __restrict__ off, const int* __restrict__ csrs,
    const float* __restrict__ el, const float* __restrict__ er,
    const float* __restrict__ m0f, const float* __restrict__ s0f,
    const float* __restrict__ z, const float* __restrict__ b0,
    float* __restrict__ xk) {
    __shared__ int ssrc[4][CW];
    __shared__ float sexp[4][CW][4];
    int wv = threadIdx.x >> 6, lane = threadIdx.x & 63;
    int i = blockIdx.x * 4 + wv;
    int v = list[i];
    int b = off[v], e = off[v + 1], deg = e - b;
    int h = lane >> 4, sub = lane & 15;
    float erh = er[(size_t)v * 4 + h];
    float mh = m0f[v * 4 + h];
    for (int li = sub; li < deg; li += 16) {
        int s = csrs[b + li];
        if (h == 0 && li < CW) ssrc[wv][li] = s;
        if (li < CW) sexp[wv][li][h] = expf(lrelu(el[(size_t)s * 4 + h] + erh) - mh);
    }
    __syncthreads();
    int h0 = lane >> 5, h1 = h0 + 2;
    float s0 = s0f[v * 4 + h0], s1 = s0f[v * 4 + h1];
    float m0 = m0f[v * 4 + h0], m1 = m0f[v * 4 + h1];
    float er0v = er[(size_t)v * 4 + h0], er1v = er[(size_t)v * 4 + h1];
    int c0 = lane, c1 = lane + 64;
    float acc0 = 0.f, acc1 = 0.f;
    for (int li = 0; li < deg; li++) {
        int s; float w0, w1;
        if (li < CW) {
            s = ssrc[wv][li];
            w0 = sexp[wv][li][h0]; w1 = sexp[wv][li][h1];
        } else {
            s = csrs[b + li];
            w0 = expf(lrelu(el[(size_t)s * 4 + h0] + er0v) - m0);
            w1 = expf(lrelu(el[(size_t)s * 4 + h1] + er1v) - m1);
        }
        int su = __builtin_amdgcn_readfirstlane(s);
        const float* zr = z + (size_t)su * HD;
        acc0 = fmaf(w0, zr[c0], acc0);
        acc1 = fmaf(w1, zr[c1], acc1);
    }
    float ts = tscale[i];
    float* xr = xk + (size_t)i * HD;
    xr[c0] = (acc0 / fmaxf(s0, 1e-16f) + b0[c0]) * ts;
    xr[c1] = (acc1 / fmaxf(s1, 1e-16f) + b0[c1]) * ts;
}

// ---------- pure gemm1 ----------
#define G1B 392
__global__ __launch_bounds__(256) void k_gemm1(P p) {
    gemm_body(p.xk, p.W1, p.z1, KK, HD, p.al1, p.ar1, p.el1, p.er1,
              nullptr, nullptr, blockIdx.x & 1, blockIdx.x >> 1);
}

// ---------- layer-1 fused GAT: reuses LAYER-0 CSR, filters by slot ----------
__global__ __launch_bounds__(256) void k_fgat2(P p) {
    __shared__ int ssrc[4][CW];
    __shared__ float sexp[4][CW][4];
    int wv = threadIdx.x >> 6, lane = threadIdx.x & 63;
    int i = blockIdx.x * 4 + wv;          // slot index
    int v = p.list[i];                    // original node id
    int b = p.off0[v], e = p.off0[v + 1], deg = e - b;
    int h = lane >> 4, sub = lane & 15;
    float4 er4 = *(const float4*)(p.er1 + (size_t)i * 4);
    float erh = ((const float*)&er4)[h];
    float m = NEGF;
    for (int li = sub; li < deg; li += 16) {
        int so = p.csr_src[b + li];
        int ss = p.slot[so];
        if (h == 0 && li < CW) ssrc[wv][li] = ss;
        if (ss >= 0) m = fmaxf(m, lrelu(p.el1[(size_t)ss * 4 + h] + erh));
    }
#pragma unroll
    for (int o = 1; o < 16; o <<= 1) m = fmaxf(m, __shfl_xor(m, o));
    float ssum = 0.f;
    for (int li = sub; li < deg; li += 16) {
        int so = p.csr_src[b + li];
        int ss = p.slot[so];
        float x = (ss >= 0) ? expf(lrelu(p.el1[(size_t)ss * 4 + h] + erh) - m) : 0.f;
        if (li < CW) sexp[wv][li][h] = x;
        ssum += x;
    }
#pragma unroll
    for (int o = 1; o < 16; o <<= 1) ssum += __shfl_xor(ssum, o);
    if (sub == 0) { p.m1f[i * 4 + h] = m; p.s1f[i * 4 + h] = ssum; }
    __syncthreads();
    int h0 = lane >> 5, h1 = h0 + 2;
    float m0 = __shfl(m, h0 << 4), m1 = __shfl(m, h1 << 4);
    float s0 = __shfl(ssum, h0 << 4), s1 = __shfl(ssum, h1 << 4);
    int c0 = lane, c1 = lane + 64;
    float acc0 = 0.f, acc1 = 0.f;
    for (int li = 0; li < deg; li++) {
        int s; float w0, w1;
        if (li < CW) {
            s = ssrc[wv][li];
            if (s < 0) continue;
            w0 = sexp[wv][li][h0]; w1 = sexp[wv][li][h1];
        } else {
            int so = p.csr_src[b + li];
            s = p.slot[so];
            if (s < 0) continue;
            w0 = expf(lrelu(p.el1[(size_t)s * 4 + h0] + ((const float*)&er4)[h0]) - m0);
            w1 = expf(lrelu(p.el1[(size_t)s * 4 + h1] + ((const float*)&er4)[h1]) - m1);
        }
        int su = __builtin_amdgcn_readfirstlane(s);
        const float* zr = p.z1 + (size_t)su * HD;
        acc0 = fmaf(w0, zr[c0], acc0);
        acc1 = fmaf(w1, zr[c1], acc1);
    }
    float xc0 = acc0 / fmaxf(s0, 1e-16f) + p.b1[c0];
    float xc1 = acc1 / fmaxf(s1, 1e-16f) + p.b1[c1];
    float t = xc0 + xc1;
    t += __shfl_xor(t, 32);
    float pg = 0.f;
    if (lane < 32) {
        float r = 0.25f * t;
        p.res[(size_t)i * 32 + lane] = r;
        pg = r * p.gW[lane];
    }
#pragma unroll
    for (int o = 1; o < 32; o <<= 1) pg += __shfl_xor(pg, o);
    if (lane == 0) p.g[i] = pg + p.gb[0];
}

// ---------- MERGED: per-edge alpha outputs || gmax ----------
__global__ __launch_bounds__(256) void k_eg(P p) {
    int blk = blockIdx.x;
    if (blk < GB_E) {
        int e = blk * 256 + (int)threadIdx.x;
        if (e >= EE) return;
        int ds = p.slot[p.src[e]], dd = p.slot[p.dst[e]];
        float a[4] = {0.f, 0.f, 0.f, 0.f};
        float st = 0.f;
        if (ds >= 0 && dd >= 0) {
            float4 es = *(const float4*)(p.el1 + ds * 4);
            float4 ed = *(const float4*)(p.er1 + dd * 4);
            float l[4] = {lrelu(es.x + ed.x), lrelu(es.y + ed.y), lrelu(es.z + ed.z), lrelu(es.w + ed.w)};
#pragma unroll
            for (int h = 0; h < 4; h++) {
                float m = p.m1f[dd * 4 + h];
                float ex = expf(l[h] - m);
                a[h] = ex / fmaxf(p.s1f[dd * 4 + h], 1e-16f);
            }
            st = p.strength[e];
        }
        float* o = p.out + ATT_OFF + (size_t)e * 4;
        *(float2*)(o) = make_float2(a[0], a[1]);
        *(float2*)(o + 2) = make_float2(a[2], a[3]);
        p.out[STR_OFF + e] = st;
    } else {
        __shared__ float red[256];
        int t = threadIdx.x;
        float m = -3.4e38f;
        for (int i = (blk - GB_E) * 256 + t; i < KK; i += 98 * 256) m = fmaxf(m, p.g[i]);
        red[t] = m;
        __syncthreads();
        for (int o = 128; o > 0; o >>= 1) { if (t < o) red[t] = fmaxf(red[t], red[t + o]); __syncthreads(); }
        if (t == 0) atomicMax(p.gmaxk, fkey(red[0]));   // memset-0 identity ok
    }
}

#define WSUM_BLOCKS 104
__global__ __launch_bounds__(256) void k_wsum(P p) {
    __shared__ double vred[256];
    __shared__ double zred[8];
    int t = threadIdx.x, il = t >> 5, d = t & 31;
    float gm = unfkey(*p.gmaxk);
    double accv = 0.0, accw = 0.0;
    for (int i = blockIdx.x * 8 + il; i < KK; i += WSUM_BLOCKS * 8) {
        float w = expf(p.g[i] - gm);
        accv += (double)(w * p.res[(size_t)i * 32 + d]);
        if (d == 0) accw += (double)w;
    }
    vred[t] = accv;
    if (d == 0) zred[il] = accw;
    __syncthreads();
    if (il == 0) {
        double s = 0;
#pragma unroll
        for (int k2 = 0; k2 < 8; k2++) s += vred[k2 * 32 + d];
        atomicAdd(&p.racc[d], s);
    }
    if (t == 32) {
        double z2 = 0;
#pragma unroll
        for (int k2 = 0; k2 < 8; k2++) z2 += zred[k2];
        atomicAdd(p.Zacc, z2);
    }
}
__global__ void k_final(P p) {
    __shared__ float rb[32];
    int t = threadIdx.x;
    double Z = *p.Zacc;
    if (t < 32) {
        float r = (float)(p.racc[t] / Z);
        p.out[t] = r;
        rb[t] = r;
    }
    __syncthreads();
    if (t < 2) {
        float s = 0.f;
        for (int d = 0; d < 32; d++) s += rb[d] * p.cW[d * 2 + t];
        p.out[32 + t] = s + p.cb[t];
    }
}

// ---------- host ----------
extern "C" void kernel_launch(void* const* d_in, const int* in_sizes, int n_in,
                              void* d_out, int out_size, void* d_ws, size_t ws_size,
                              hipStream_t stream) {
    (void)in_sizes; (void)n_in; (void)out_size; (void)ws_size;
    P p;
    p.feature  = (const float*)d_in[0];
    p.strength = (const float*)d_in[1];
    p.W0  = (const float*)d_in[2];  p.b0  = (const float*)d_in[3];
    p.al0 = (const float*)d_in[4];  p.ar0 = (const float*)d_in[5];
    p.Wc0 = (const float*)d_in[6];  p.bc0 = (const float*)d_in[7];
    p.W1  = (const float*)d_in[8];  p.b1  = (const float*)d_in[9];
    p.al1 = (const float*)d_in[10]; p.ar1 = (const float*)d_in[11];
    p.gW  = (const float*)d_in[12]; p.gb  = (const float*)d_in[13];
    p.cW  = (const float*)d_in[14]; p.cb  = (const float*)d_in[15];
    p.src = (const int*)d_in[16];   p.dst = (const int*)d_in[17];
    p.out = (float*)d_out;

    char* ws = (char*)d_ws;
    size_t off = 0;
    auto alloc = [&](size_t bytes) -> void* {
        void* r = ws + off;
        off = (off + bytes + 255) & ~(size_t)255;
        return r;
    };
    // ---- zeroed region (must stay first/contiguous) ----
    p.Zacc  = (double*)alloc(8);
    p.racc  = (double*)alloc(32 * 8);
    p.cnt   = (int*)alloc(4);
    p.gmaxk = (unsigned*)alloc(4);
    p.rs    = (unsigned*)alloc(16);
    p.binsHi = (unsigned*)alloc(65536 * 4);
    p.binsLo = (unsigned*)alloc(65536 * 4);
    size_t zbytes = off;
    // ---- big buffers (fully overwritten each run) ----
    p.degc_i = (unsigned char*)alloc((size_t)BCH * NN);
    p.degc_o = (unsigned char*)alloc((size_t)BCH * NN);
    p.cb0 = (unsigned*)alloc((size_t)BCH * NN * 4);
    p.dsum = (int*)alloc((size_t)NN * 4);
    p.z0 = (float*)alloc((size_t)NN * HD * 4);
    p.xk = (float*)alloc((size_t)KK * HD * 4);
    p.z1 = (float*)alloc((size_t)KK * HD * 4);
    p.csr_src = (int*)alloc((size_t)EE * 4);
    p.rank    = (int*)alloc((size_t)EE * 4);
    p.el0 = (float*)alloc((size_t)NN * 4 * 4);
    p.er0 = (float*)alloc((size_t)NN * 4 * 4);
    p.q4  = (float*)alloc((size_t)NN * 4 * 4);
    p.m0f = (float*)alloc((size_t)NN * 4 * 4);
    p.s0f = (float*)alloc((size_t)NN * 4 * 4);
    p.b0wc = (float*)alloc(4);
    p.off0 = (int*)alloc((size_t)(NN + 1) * 4);
    p.bsum = (int*)alloc(256 * 4);
    p.boff = (int*)alloc(256 * 4);
    p.hc    = (float*)alloc((size_t)NN * 4);
    p.keys  = (unsigned*)alloc((size_t)NN * 4);
    p.slot  = (int*)alloc((size_t)NN * 4);
    p.list  = (int*)alloc((size_t)KK * 4);
    p.tscale = (float*)alloc((size_t)KK * 4);
    p.el1 = (float*)alloc((size_t)KK * 4 * 4);
    p.er1 = (float*)alloc((size_t)KK * 4 * 4);
    p.m1f = (float*)alloc((size_t)KK * 4 * 4);
    p.s1f = (float*)alloc((size_t)KK * 4 * 4);
    p.res = (float*)alloc((size_t)KK * DD * 4);
    p.g   = (float*)alloc((size_t)KK * 4);

    const int GB_N = (NN + 255) / 256;        // 196

    hipMemsetAsync(d_ws, 0, zbytes, stream);

    // ---- GAT layer 0: count -> scan -> scatter0 -> gemm0 -> fgatlite ----
    k_count0<<<256, 256, 0, stream>>>(p);
    k_bsum<<<GB_N, 256, 0, stream>>>(p.degc_i, p.bsum, NN, NN);
    k_bscan<<<1, 256, 0, stream>>>(p.bsum, GB_N, p.boff, p.off0, NN);
    k_fscan0<<<GB_N, 256, 0, stream>>>(p);
    k_scat0<<<GB_E4, 256, 0, stream>>>(p);
    k_gemm0<<<G0B + 1, 256, 0, stream>>>(p);
    k_fgatlite<<<NN / 4, 256, 0, stream>>>(p.off0, p.csr_src, p.el0, p.er0, p.q4,
                                           p.dsum, p.b0wc, p.hc, p.m0f, p.s0f);

    // ---- SAGPool: stream-ordered select ----
    k_score<<<GB_N, 256, 0, stream>>>(p);
    k_h0<<<HB, 1024, 0, stream>>>(p);
    k_rsel2<<<1, 1024, 0, stream>>>(p, 0);
    k_h1<<<HB, 1024, 0, stream>>>(p);
    k_rsel2<<<1, 1024, 0, stream>>>(p, 1);
    k_tcnt<<<GB_N, 256, 0, stream>>>(p);
    k_list<<<GB_N, 256, 0, stream>>>(p);

    // ---- GAT layer 1: fgatx -> gemm1 -> fgat2 (layer-0 CSR reused) ----
    k_fgatx<<<KK / 4, 256, 0, stream>>>(p.list, p.tscale, p.off0, p.csr_src,
                                        p.el0, p.er0, p.m0f, p.s0f, p.z0, p.b0, p.xk);
    k_gemm1<<<G1B, 256, 0, stream>>>(p);
    k_fgat2<<<KK / 4, 256, 0, stream>>>(p);

    // ---- edge outputs || gmax, then readout ----
    k_eg<<<GB_E + 98, 256, 0, stream>>>(p);
    k_wsum<<<WSUM_BLOCKS, 256, 0, stream>>>(p);
    k_final<<<1, 64, 0, stream>>>(p);
}

// Round 11
// 516.161 us; speedup vs baseline: 2.6290x; 1.0335x over previous
//
#include <hip/hip_runtime.h>
#include <stdint.h>

#define NN 50000
#define EE 800000
#define FIN 256
#define HD 128
#define DD 32
#define KK 25000
#define SLOPEF 0.4f
#define NEGF (-1e9f)
#define ATT_OFF 34
#define STR_OFF (34 + EE * 4)
#define CW 128             // LDS-cached edges per node (deg ~Poisson(16); recompute fallback)

// counting-sort CSR build (layer 0 only; layer 1 reuses it via slot-filtering)
#define BCH 32             // edge chunks
#define EPC (EE / BCH)     // 25000 edges per chunk
#define NRQ 12500          // node-range quarter for count blocks (4 x 12500 = NN)

// ---------- helpers ----------
__device__ __forceinline__ unsigned fkey(float x) {
    unsigned u = __float_as_uint(x);
    return (u & 0x80000000u) ? ~u : (u | 0x80000000u);   // monotone float->uint
}
__device__ __forceinline__ float unfkey(unsigned k) {
    unsigned u = (k & 0x80000000u) ? (k ^ 0x80000000u) : ~k;
    return __uint_as_float(u);
}
__device__ __forceinline__ float lrelu(float v) { return v > 0.f ? v : SLOPEF * v; }

// ---------- pointer bundle ----------
struct P {
    // inputs
    const float *feature, *strength, *W0, *b0, *al0, *ar0, *Wc0, *bc0;
    const float *W1, *b1, *al1, *ar1, *gW, *gb, *cW, *cb;
    const int *src, *dst;
    // zeroed scratch
    double *Zacc, *racc;
    int *cnt;
    unsigned *gmaxk;
    unsigned *rs;                 // [0]=pivot,[1]=need,[2]=hi bin,[3]=hi remaining
    unsigned *binsHi, *binsLo;    // 65536 u32 bins each
    // other scratch
    unsigned *keys;
    unsigned char *degc_i, *degc_o;   // per-(chunk,node) u8 counts [BCH][NN]
    unsigned *cb0;                // per-(chunk,node) CSR base cursors
    int *dsum;                    // out-degree totals
    int *csr_src, *rank, *off0, *slot, *list, *bsum, *boff;
    float *z0, *el0, *er0, *q4, *m0f, *s0f, *b0wc, *hc, *xk, *z1;
    float *el1, *er1, *m1f, *s1f, *res, *g, *tscale;
    float *out;                   // d_out (float32)
};

// ---------- fp32 tiled GEMM body: C[M,128] = A[M,Kd] @ B[Kd,128] ----------
// R11: 64x64 tile (was 128x64). R7-R10 showed the loop is latency-bound at
// ~12 waves/CU; halving per-thread state (acc 32->16, VGPR ~80) and doubling
// the grid (~6 blocks/CU) raises TLP ~2x. ILP (dbuf) is compiler-defeated
// (R8/R9 spills); TLP is the remaining latency-hiding axis.
#define BM 64
#define BN 64
#define BK 16
__device__ void gemm_body(
    const float* __restrict__ A, const float* __restrict__ B, float* __restrict__ C,
    int M, int Kd,
    const float* __restrict__ al, const float* __restrict__ ar,
    float* __restrict__ el, float* __restrict__ er,
    const float* __restrict__ Wc, float* __restrict__ q4,
    int bx, int by) {
    __shared__ float As[BK][BM + 4];
    __shared__ float Bs[BK][BN];
    int bm = by * BM, bn = bx * BN;
    int tid = threadIdx.x;
    int tr = tid >> 4, tc = tid & 15;
    int lrow = tid >> 2;                 // 0..63 A-tile row
    int acol = (tid & 3) << 2;           // 0,4,8,12
    int arow = (bm + lrow < M) ? (bm + lrow) : -1;
    float acc[4][4] = {};
    for (int k0 = 0; k0 < Kd; k0 += BK) {
        {
            float4 v = {0.f, 0.f, 0.f, 0.f};
            if (arow >= 0) v = *(const float4*)(A + (size_t)arow * Kd + k0 + acol);
            As[acol + 0][lrow] = v.x; As[acol + 1][lrow] = v.y;
            As[acol + 2][lrow] = v.z; As[acol + 3][lrow] = v.w;
        }
        {
            int kr = tid >> 4, col = (tid & 15) << 2;
            float4 v = *(const float4*)(B + (size_t)(k0 + kr) * HD + bn + col);
            *(float4*)&Bs[kr][col] = v;
        }
        __syncthreads();
#pragma unroll
        for (int kk = 0; kk < BK; kk++) {
            float a[4], b[4];
#pragma unroll
            for (int i = 0; i < 4; i++) a[i] = As[kk][tr * 4 + i];
#pragma unroll
            for (int j = 0; j < 4; j++) b[j] = Bs[kk][tc * 4 + j];
#pragma unroll
            for (int i = 0; i < 4; i++)
#pragma unroll
                for (int j = 0; j < 4; j++) acc[i][j] = fmaf(a[i], b[j], acc[i][j]);
        }
        __syncthreads();
    }
#pragma unroll
    for (int i = 0; i < 4; i++) {
        int gr = bm + tr * 4 + i;
        if (gr < M) {
            float4 v = {acc[i][0], acc[i][1], acc[i][2], acc[i][3]};
            *(float4*)(C + (size_t)gr * HD + bn + tc * 4) = v;
        }
    }
    // epilogue: heads 2*bx, 2*bx+1; 8-lane tree reduce per (row, head)
    int head = bx * 2 + (tc >> 3);
    int dbase = (tc & 7) * 4;
    const float* alh = al + head * 32 + dbase;
    const float* arh = ar + head * 32 + dbase;
    float a0 = alh[0], a1 = alh[1], a2 = alh[2], a3 = alh[3];
    float r0 = arh[0], r1 = arh[1], r2 = arh[2], r3 = arh[3];
    float w0 = 0.f, w1 = 0.f, w2 = 0.f, w3 = 0.f;
    if (Wc) {
        const float* wch = Wc + head * 32 + dbase;
        w0 = wch[0]; w1 = wch[1]; w2 = wch[2]; w3 = wch[3];
    }
#pragma unroll
    for (int i = 0; i < 4; i++) {
        int gr = bm + tr * 4 + i;
        float pe = acc[i][0]*a0 + acc[i][1]*a1 + acc[i][2]*a2 + acc[i][3]*a3;
        float pr = acc[i][0]*r0 + acc[i][1]*r1 + acc[i][2]*r2 + acc[i][3]*r3;
        float pq = acc[i][0]*w0 + acc[i][1]*w1 + acc[i][2]*w2 + acc[i][3]*w3;
#pragma unroll
        for (int o = 1; o < 8; o <<= 1) {
            pe += __shfl_xor(pe, o); pr += __shfl_xor(pr, o); pq += __shfl_xor(pq, o);
        }
        if ((tc & 7) == 0 && gr < M) {
            el[gr * 4 + head] = pe; er[gr * 4 + head] = pr;
            if (Wc) q4[gr * 4 + head] = pq;
        }
    }
}

// ---------- layer-0 count: (chunk x node-quarter) u8 LDS histogram, int4 loads ----------
__global__ __launch_bounds__(256) void k_count0(P p) {
    __shared__ unsigned hist[NRQ / 4];        // 12500 u8 counters
    int blk = blockIdx.x;
    int isD = blk < 128;
    int c = blk & 31, rq = (blk >> 5) & 3;
    int nbase = rq * NRQ;
    for (int w = threadIdx.x; w < NRQ / 4; w += 256) hist[w] = 0u;
    __syncthreads();
    int j0 = c * (EPC / 4), j1 = j0 + (EPC / 4);
    if (isD) {
        const int4* d4 = (const int4*)p.dst;
        for (int j = j0 + (int)threadIdx.x; j < j1; j += 256) {
            int4 dv = d4[j];
            int e = j * 4;
            int d, t;
            d = dv.x - nbase;
            if ((unsigned)d < (unsigned)NRQ) {
                unsigned sh = (unsigned)(d & 3) * 8u;
                t = (int)((atomicAdd(&hist[d >> 2], 1u << sh) >> sh) & 0xffu);
                p.rank[e + 0] = t;
            }
            d = dv.y - nbase;
            if ((unsigned)d < (unsigned)NRQ) {
                unsigned sh = (unsigned)(d & 3) * 8u;
                t = (int)((atomicAdd(&hist[d >> 2], 1u << sh) >> sh) & 0xffu);
                p.rank[e + 1] = t;
            }
            d = dv.z - nbase;
            if ((unsigned)d < (unsigned)NRQ) {
                unsigned sh = (unsigned)(d & 3) * 8u;
                t = (int)((atomicAdd(&hist[d >> 2], 1u << sh) >> sh) & 0xffu);
                p.rank[e + 2] = t;
            }
            d = dv.w - nbase;
            if ((unsigned)d < (unsigned)NRQ) {
                unsigned sh = (unsigned)(d & 3) * 8u;
                t = (int)((atomicAdd(&hist[d >> 2], 1u << sh) >> sh) & 0xffu);
                p.rank[e + 3] = t;
            }
        }
    } else {
        const int4* s4 = (const int4*)p.src;
        for (int j = j0 + (int)threadIdx.x; j < j1; j += 256) {
            int4 sv = s4[j];
            int s;
            s = sv.x - nbase;
            if ((unsigned)s < (unsigned)NRQ) atomicAdd(&hist[s >> 2], 1u << ((unsigned)(s & 3) * 8u));
            s = sv.y - nbase;
            if ((unsigned)s < (unsigned)NRQ) atomicAdd(&hist[s >> 2], 1u << ((unsigned)(s & 3) * 8u));
            s = sv.z - nbase;
            if ((unsigned)s < (unsigned)NRQ) atomicAdd(&hist[s >> 2], 1u << ((unsigned)(s & 3) * 8u));
            s = sv.w - nbase;
            if ((unsigned)s < (unsigned)NRQ) atomicAdd(&hist[s >> 2], 1u << ((unsigned)(s & 3) * 8u));
        }
    }
    __syncthreads();
    unsigned* o32 = (unsigned*)((isD ? p.degc_i : p.degc_o) + (size_t)c * NN + nbase);
    for (int w = threadIdx.x; w < NRQ / 4; w += 256) o32[w] = hist[w];
}

// ---------- two-level exclusive scan over node totals (stream-ordered) ----------
__global__ __launch_bounds__(256) void k_bsum(const unsigned char* __restrict__ deg,
                                              int* __restrict__ bsum, int n, int nn) {
    int i = blockIdx.x * 256 + threadIdx.x;
    int v = 0;
    if (i < n) {
#pragma unroll
        for (int c = 0; c < BCH; c++) v += deg[(size_t)c * nn + i];
    }
    int lane = threadIdx.x & 63, w = threadIdx.x >> 6;
    __shared__ int ws[4];
#pragma unroll
    for (int o = 1; o < 64; o <<= 1) v += __shfl_xor(v, o);
    if (lane == 0) ws[w] = v;
    __syncthreads();
    if (threadIdx.x == 0) bsum[blockIdx.x] = ws[0] + ws[1] + ws[2] + ws[3];
}
__global__ __launch_bounds__(256) void k_bscan(const int* __restrict__ bsum, int nb,
                                               int* __restrict__ boff,
                                               int* __restrict__ off, int n) {
    __shared__ int ws[4];
    __shared__ int wo[5];
    int t = threadIdx.x;
    int v = (t < nb) ? bsum[t] : 0;
    int lane = t & 63, w = t >> 6;
    int incl = v;
    for (int o = 1; o < 64; o <<= 1) { int u = __shfl_up(incl, o); if (lane >= o) incl += u; }
    if (lane == 63) ws[w] = incl;
    __syncthreads();
    if (t == 0) { int a = 0; for (int i = 0; i < 4; i++) { wo[i] = a; a += ws[i]; } wo[4] = a; }
    __syncthreads();
    if (t < nb) boff[t] = wo[w] + incl - v;
    if (t == 0) off[n] = wo[4];
}
// final scan: off0 + per-chunk bases cb0 + out-degree totals dsum
__global__ __launch_bounds__(256) void k_fscan0(P p) {
    __shared__ int ws[4];
    __shared__ int wo[4];
    int i = blockIdx.x * 256 + threadIdx.x;
    int v = 0;
    if (i < NN) {
#pragma unroll
        for (int c = 0; c < BCH; c++) v += p.degc_i[(size_t)c * NN + i];
    }
    int lane = threadIdx.x & 63, w = threadIdx.x >> 6;
    int incl = v;
    for (int o = 1; o < 64; o <<= 1) { int u = __shfl_up(incl, o); if (lane >= o) incl += u; }
    if (lane == 63) ws[w] = incl;
    __syncthreads();
    if (threadIdx.x == 0) { int a = 0; for (int k = 0; k < 4; k++) { wo[k] = a; a += ws[k]; } }
    __syncthreads();
    if (i < NN) {
        int base = p.boff[blockIdx.x] + wo[w] + incl - v;
        p.off0[i] = base;
        unsigned run = (unsigned)base;
        int s = 0;
#pragma unroll
        for (int c = 0; c < BCH; c++) {
            p.cb0[(size_t)c * NN + i] = run;
            run += p.degc_i[(size_t)c * NN + i];
            s += p.degc_o[(size_t)c * NN + i];
        }
        p.dsum[i] = s;
    }
}

// ---------- CSR scatter0: int4 (4 edges/thread; chunk uniform per int4) ----------
#define GB_E 3125
#define GB_E4 782
__global__ __launch_bounds__(256) void k_scat0(P p) {
    int j = blockIdx.x * 256 + threadIdx.x;
    if (j >= EE / 4) return;
    int c = j / (EPC / 4);
    int4 dv = ((const int4*)p.dst)[j];
    int4 sv = ((const int4*)p.src)[j];
    int4 rv = ((const int4*)p.rank)[j];
    const unsigned* cb = p.cb0 + (size_t)c * NN;
    p.csr_src[cb[dv.x] + (unsigned)rv.x] = sv.x;
    p.csr_src[cb[dv.y] + (unsigned)rv.y] = sv.y;
    p.csr_src[cb[dv.z] + (unsigned)rv.z] = sv.z;
    p.csr_src[cb[dv.w] + (unsigned)rv.w] = sv.w;
}

// ---------- gemm0 (+ b0wc prep micro-block) ----------
#define G0B 1564           // 2 x 782 gemm blocks (64-row tiles)
__global__ __launch_bounds__(256) void k_gemm0(P p) {
    int blk = blockIdx.x;
    if (blk < G0B) {
        gemm_body(p.feature, p.W0, p.z0, NN, FIN, p.al0, p.ar0, p.el0, p.er0,
                  p.Wc0, p.q4, blk & 1, blk >> 1);
    } else {
        int l = threadIdx.x;
        if (l < 64) {
            float t = p.b0[l] * p.Wc0[l] + p.b0[l + 64] * p.Wc0[l + 64];
#pragma unroll
            for (int o = 1; o < 64; o <<= 1) t += __shfl_xor(t, o);
            if (l == 0) p.b0wc[0] = t;
        }
    }
}

// ---------- layer-0 softmax + SCALAR q-gather (all nodes) ----------
__global__ __launch_bounds__(256) void k_fgatlite(
    const int* __restrict__ off, const int* __restrict__ csrs,
    const float* __restrict__ el, const float* __restrict__ er,
    const float* __restrict__ q4, const int* __restrict__ dsum,
    const float* __restrict__ b0wc,
    float* __restrict__ hc, float* __restrict__ m0f, float* __restrict__ s0f) {
    int wv = threadIdx.x >> 6, lane = threadIdx.x & 63;
    int v = blockIdx.x * 4 + wv;
    int b = off[v], e = off[v + 1], deg = e - b;
    int h = lane >> 4, sub = lane & 15;
    float erh = er[(size_t)v * 4 + h];
    float m = NEGF;
    for (int li = sub; li < deg; li += 16) {
        int s = csrs[b + li];
        m = fmaxf(m, lrelu(el[(size_t)s * 4 + h] + erh));
    }
#pragma unroll
    for (int o = 1; o < 16; o <<= 1) m = fmaxf(m, __shfl_xor(m, o));
    float ssum = 0.f, hq = 0.f;
    for (int li = sub; li < deg; li += 16) {
        int s = csrs[b + li];
        float ex = expf(lrelu(el[(size_t)s * 4 + h] + erh) - m);
        ssum += ex;
        hq = fmaf(ex, q4[(size_t)s * 4 + h], hq);
    }
#pragma unroll
    for (int o = 1; o < 16; o <<= 1) { ssum += __shfl_xor(ssum, o); hq += __shfl_xor(hq, o); }
    if (sub == 0) { m0f[v * 4 + h] = m; s0f[v * 4 + h] = ssum; }
    float t = hq / fmaxf(ssum, 1e-16f);
    t += __shfl_xor(t, 16);
    t += __shfl_xor(t, 32);
    if (lane == 0)
        hc[v] = (t + b0wc[0]) / sqrtf(fmaxf((float)dsum[v], 1.f));
}

// ---------- SAGPool score -> keys ----------
__global__ __launch_bounds__(256) void k_score(P p) {
    int v = blockIdx.x * blockDim.x + threadIdx.x;
    if (v >= NN) return;
    int b = p.off0[v], en = p.off0[v + 1];
    float acc = 0.f;
    for (int i = b; i < en; i++) acc += p.hc[p.csr_src[i]];
    float dg = fmaxf((float)(en - b), 1.f);
    float sc = acc / sqrtf(dg) + p.bc0[0];
    p.keys[v] = fkey(sc);
}

// ---------- hi-16 histogram: per-block u16-packed LDS (two 64KB half-passes) ----------
#define HB 49              // ceil(NN/1024)
__global__ __launch_bounds__(1024) void k_h0(P p) {
    __shared__ unsigned hist[16384];     // 64 KB: 32768 bins u16-packed per half
    int i = blockIdx.x * 1024 + (int)threadIdx.x;
    unsigned key = (i < NN) ? p.keys[i] : 0xFFFFFFFFu;  // sentinel: never counted
    unsigned b16 = key >> 16;
#pragma unroll
    for (int half = 0; half < 2; half++) {
        for (int w = threadIdx.x; w < 16384; w += 1024) hist[w] = 0u;
        __syncthreads();
        if (i < NN && (int)(b16 >> 15) == half) {
            unsigned bb = b16 & 0x7FFFu;
            atomicAdd(&hist[bb >> 1], 1u << (16u * (bb & 1u)));
        }
        __syncthreads();
        for (int w = threadIdx.x; w < 16384; w += 1024) {
            unsigned hv = hist[w];
            unsigned lo = hv & 0xFFFFu, hi = hv >> 16;
            if (lo) atomicAdd(&p.binsHi[half * 32768 + 2 * w], lo);
            if (hi) atomicAdd(&p.binsHi[half * 32768 + 2 * w + 1], hi);
        }
        __syncthreads();
    }
}

// ---------- lo-16 histogram among hi-bin candidates ----------
__global__ __launch_bounds__(1024) void k_h1(P p) {
    __shared__ unsigned hist[16384];
    int i = blockIdx.x * 1024 + (int)threadIdx.x;
    unsigned hib = p.rs[2];
    unsigned key = (i < NN) ? p.keys[i] : 0u;
    int cand = (i < NN) && ((key >> 16) == hib);
    unsigned b16 = key & 0xFFFFu;
#pragma unroll
    for (int half = 0; half < 2; half++) {
        for (int w = threadIdx.x; w < 16384; w += 1024) hist[w] = 0u;
        __syncthreads();
        if (cand && (int)(b16 >> 15) == half) {
            unsigned bb = b16 & 0x7FFFu;
            atomicAdd(&hist[bb >> 1], 1u << (16u * (bb & 1u)));
        }
        __syncthreads();
        for (int w = threadIdx.x; w < 16384; w += 1024) {
            unsigned hv = hist[w];
            unsigned lo = hv & 0xFFFFu, hi = hv >> 16;
            if (lo) atomicAdd(&p.binsLo[half * 32768 + 2 * w], lo);
            if (hi) atomicAdd(&p.binsLo[half * 32768 + 2 * w + 1], hi);
        }
        __syncthreads();
    }
}

// ---------- radix pick: 1 block scans 65536 bins ----------
__global__ __launch_bounds__(1024) void k_rsel2(P p, int level) {
    const unsigned* bins = level ? p.binsLo : p.binsHi;
    int K = level ? (int)p.rs[3] : KK;
    __shared__ unsigned wsm[16];
    __shared__ unsigned wpre[17];
    int t = threadIdx.x;
    unsigned base = (unsigned)t * 64;
    const uint4* b4 = (const uint4*)(bins + base);
    unsigned S = 0;
#pragma unroll
    for (int i = 0; i < 16; i++) {
        uint4 u = b4[i];
        S += u.x + u.y + u.z + u.w;
    }
    int lane = t & 63, w = t >> 6;
    unsigned val = S;
    for (int o = 1; o < 64; o <<= 1) { unsigned u = __shfl_up(val, o); if (lane >= o) val += u; }
    if (lane == 63) wsm[w] = val;
    __syncthreads();
    if (t == 0) { unsigned a = 0; for (int i = 0; i < 16; i++) { wpre[i] = a; a += wsm[i]; } wpre[16] = a; }
    __syncthreads();
    unsigned incl = wpre[w] + val;
    unsigned running = wpre[16] - incl;    // keys in strictly higher bins
    for (int i = 63; i >= 0; i--) {
        unsigned c = bins[base + i];
        unsigned above = running;
        running += c;
        if ((int)above < K && (int)running >= K) {
            if (level == 0) { p.rs[2] = base + (unsigned)i; p.rs[3] = (unsigned)(K - (int)above); }
            else { p.rs[0] = (p.rs[2] << 16) | (base + (unsigned)i); p.rs[1] = (unsigned)(K - (int)above); }
        }
    }
}

// ---------- parallel tie counting ----------
__global__ __launch_bounds__(256) void k_tcnt(P p) {
    __shared__ int ws[4];
    int v = blockIdx.x * 256 + (int)threadIdx.x;
    int flag = (v < NN && p.keys[v] == p.rs[0]) ? 1 : 0;
    unsigned long long m = __ballot(flag);
    int lane = threadIdx.x & 63, w = threadIdx.x >> 6;
    if (lane == 0) ws[w] = __popcll(m);
    __syncthreads();
    if (threadIdx.x == 0) p.bsum[blockIdx.x] = ws[0] + ws[1] + ws[2] + ws[3];
}

// ---------- list build: select + lowest-index tie ranks inline ----------
__global__ __launch_bounds__(256) void k_list(P p) {
    __shared__ int pre0;
    __shared__ int ws[4];
    int blk = blockIdx.x, tid = threadIdx.x;
    unsigned pivot = p.rs[0];
    int need = (int)p.rs[1];
    int v = blk * 256 + tid;
    unsigned k = (v < NN) ? p.keys[v] : 0u;
    int flag = (v < NN && k == pivot) ? 1 : 0;
    unsigned long long mask = __ballot(flag);
    int lane = tid & 63, w = tid >> 6;
    if (lane == 0) ws[w] = __popcll(mask);
    if (tid == 0) {
        int s = 0;
        for (int b2 = 0; b2 < blk; b2++) s += p.bsum[b2];
        pre0 = s;
    }
    __syncthreads();
    int woff = 0;
    for (int i = 0; i < w; i++) woff += ws[i];
    int rank = pre0 + woff + __popcll(mask & ((1ull << lane) - 1ull));
    if (v < NN) {
        int selv = (k > pivot) || (flag && rank < need);
        if (selv) {
            int idx = atomicAdd(p.cnt, 1);
            p.list[idx] = v;
            p.slot[v] = idx;
            p.tscale[idx] = tanhf(unfkey(k));
        } else {
            p.slot[v] = -1;
        }
    }
}

// ---------- full x for SELECTED nodes only ----------
__global__ __launch_bounds__(256) void k_fgatx(
    const int* __restrict__ list, const float* __restrict__ tscale,
    const int* __restrict__ off, const int* __restrict__ csrs,
    const float* __restrict__ el, const float* __restrict__ er,
    const float* __restrict__ m0f, const float* __restrict__ s0f,
    const float* __restrict__ z, const float* __restrict__ b0,
    float* __restrict__ xk) {
    __shared__ int ssrc[4][CW];
    __shared__ float sexp[4][CW][4];
    int wv = threadIdx.x >> 6, lane = threadIdx.x & 63;
    int i = blockIdx.x * 4 + wv;
    int v = list[i];
    int b = off[v], e = off[v + 1], deg = e - b;
    int h = lane >> 4, sub = lane & 15;
    float erh = er[(size_t)v * 4 + h];
    float mh = m0f[v * 4 + h];
    for (int li = sub; li < deg; li += 16) {
        int s = csrs[b + li];
        if (h == 0 && li < CW) ssrc[wv][li] = s;
        if (li < CW) sexp[wv][li][h] = expf(lrelu(el[(size_t)s * 4 + h] + erh) - mh);
    }
    __syncthreads();
    int h0 = lane >> 5, h1 = h0 + 2;
    float s0 = s0f[v * 4 + h0], s1 = s0f[v * 4 + h1];
    float m0 = m0f[v * 4 + h0], m1 = m0f[v * 4 + h1];
    float er0v = er[(size_t)v * 4 + h0], er1v = er[(size_t)v * 4 + h1];
    int c0 = lane, c1 = lane + 64;
    float acc0 = 0.f, acc1 = 0.f;
    for (int li = 0; li < deg; li++) {
        int s; float w0, w1;
        if (li < CW) {
            s = ssrc[wv][li];
            w0 = sexp[wv][li][h0]; w1 = sexp[wv][li][h1];
        } else {
            s = csrs[b + li];
            w0 = expf(lrelu(el[(size_t)s * 4 + h0] + er0v) - m0);
            w1 = expf(lrelu(el[(size_t)s * 4 + h1] + er1v) - m1);
        }
        int su = __builtin_amdgcn_readfirstlane(s);
        const float* zr = z + (size_t)su * HD;
        acc0 = fmaf(w0, zr[c0], acc0);
        acc1 = fmaf(w1, zr[c1], acc1);
    }
    float ts = tscale[i];
    float* xr = xk + (size_t)i * HD;
    xr[c0] = (acc0 / fmaxf(s0, 1e-16f) + b0[c0]) * ts;
    xr[c1] = (acc1 / fmaxf(s1, 1e-16f) + b0[c1]) * ts;
}

// ---------- pure gemm1 ----------
#define G1B 782
__global__ __launch_bounds__(256) void k_gemm1(P p) {
    gemm_body(p.xk, p.W1, p.z1, KK, HD, p.al1, p.ar1, p.el1, p.er1,
              nullptr, nullptr, blockIdx.x & 1, blockIdx.x >> 1);
}

// ---------- layer-1 fused GAT: reuses LAYER-0 CSR, filters by slot ----------
__global__ __launch_bounds__(256) void k_fgat2(P p) {
    __shared__ int ssrc[4][CW];
    __shared__ float sexp[4][CW][4];
    int wv = threadIdx.x >> 6, lane = threadIdx.x & 63;
    int i = blockIdx.x * 4 + wv;          // slot index
    int v = p.list[i];                    // original node id
    int b = p.off0[v], e = p.off0[v + 1], deg = e - b;
    int h = lane >> 4, sub = lane & 15;
    float4 er4 = *(const float4*)(p.er1 + (size_t)i * 4);
    float erh = ((const float*)&er4)[h];
    float m = NEGF;
    for (int li = sub; li < deg; li += 16) {
        int so = p.csr_src[b + li];
        int ss = p.slot[so];
        if (h == 0 && li < CW) ssrc[wv][li] = ss;
        if (ss >= 0) m = fmaxf(m, lrelu(p.el1[(size_t)ss * 4 + h] + erh));
    }
#pragma unroll
    for (int o = 1; o < 16; o <<= 1) m = fmaxf(m, __shfl_xor(m, o));
    float ssum = 0.f;
    for (int li = sub; li < deg; li += 16) {
        int so = p.csr_src[b + li];
        int ss = p.slot[so];
        float x = (ss >= 0) ? expf(lrelu(p.el1[(size_t)ss * 4 + h] + erh) - m) : 0.f;
        if (li < CW) sexp[wv][li][h] = x;
        ssum += x;
    }
#pragma unroll
    for (int o = 1; o < 16; o <<= 1) ssum += __shfl_xor(ssum, o);
    if (sub == 0) { p.m1f[i * 4 + h] = m; p.s1f[i * 4 + h] = ssum; }
    __syncthreads();
    int h0 = lane >> 5, h1 = h0 + 2;
    float m0 = __shfl(m, h0 << 4), m1 = __shfl(m, h1 << 4);
    float s0 = __shfl(ssum, h0 << 4), s1 = __shfl(ssum, h1 << 4);
    int c0 = lane, c1 = lane + 64;
    float acc0 = 0.f, acc1 = 0.f;
    for (int li = 0; li < deg; li++) {
        int s; float w0, w1;
        if (li < CW) {
            s = ssrc[wv][li];
            if (s < 0) continue;
            w0 = sexp[wv][li][h0]; w1 = sexp[wv][li][h1];
        } else {
            int so = p.csr_src[b + li];
            s = p.slot[so];
            if (s < 0) continue;
            w0 = expf(lrelu(p.el1[(size_t)s * 4 + h0] + ((const float*)&er4)[h0]) - m0);
            w1 = expf(lrelu(p.el1[(size_t)s * 4 + h1] + ((const float*)&er4)[h1]) - m1);
        }
        int su = __builtin_amdgcn_readfirstlane(s);
        const float* zr = p.z1 + (size_t)su * HD;
        acc0 = fmaf(w0, zr[c0], acc0);
        acc1 = fmaf(w1, zr[c1], acc1);
    }
    float xc0 = acc0 / fmaxf(s0, 1e-16f) + p.b1[c0];
    float xc1 = acc1 / fmaxf(s1, 1e-16f) + p.b1[c1];
    float t = xc0 + xc1;
    t += __shfl_xor(t, 32);
    float pg = 0.f;
    if (lane < 32) {
        float r = 0.25f * t;
        p.res[(size_t)i * 32 + lane] = r;
        pg = r * p.gW[lane];
    }
#pragma unroll
    for (int o = 1; o < 32; o <<= 1) pg += __shfl_xor(pg, o);
    if (lane == 0) p.g[i] = pg + p.gb[0];
}

// ---------- MERGED: per-edge alpha outputs || gmax ----------
__global__ __launch_bounds__(256) void k_eg(P p) {
    int blk = blockIdx.x;
    if (blk < GB_E) {
        int e = blk * 256 + (int)threadIdx.x;
        if (e >= EE) return;
        int ds = p.slot[p.src[e]], dd = p.slot[p.dst[e]];
        float a[4] = {0.f, 0.f, 0.f, 0.f};
        float st = 0.f;
        if (ds >= 0 && dd >= 0) {
            float4 es = *(const float4*)(p.el1 + ds * 4);
            float4 ed = *(const float4*)(p.er1 + dd * 4);
            float l[4] = {lrelu(es.x + ed.x), lrelu(es.y + ed.y), lrelu(es.z + ed.z), lrelu(es.w + ed.w)};
#pragma unroll
            for (int h = 0; h < 4; h++) {
                float m = p.m1f[dd * 4 + h];
                float ex = expf(l[h] - m);
                a[h] = ex / fmaxf(p.s1f[dd * 4 + h], 1e-16f);
            }
            st = p.strength[e];
        }
        float* o = p.out + ATT_OFF + (size_t)e * 4;
        *(float2*)(o) = make_float2(a[0], a[1]);
        *(float2*)(o + 2) = make_float2(a[2], a[3]);
        p.out[STR_OFF + e] = st;
    } else {
        __shared__ float red[256];
        int t = threadIdx.x;
        float m = -3.4e38f;
        for (int i = (blk - GB_E) * 256 + t; i < KK; i += 98 * 256) m = fmaxf(m, p.g[i]);
        red[t] = m;
        __syncthreads();
        for (int o = 128; o > 0; o >>= 1) { if (t < o) red[t] = fmaxf(red[t], red[t + o]); __syncthreads(); }
        if (t == 0) atomicMax(p.gmaxk, fkey(red[0]));   // memset-0 identity ok
    }
}

#define WSUM_BLOCKS 104
__global__ __launch_bounds__(256) void k_wsum(P p) {
    __shared__ double vred[256];
    __shared__ double zred[8];
    int t = threadIdx.x, il = t >> 5, d = t & 31;
    float gm = unfkey(*p.gmaxk);
    double accv = 0.0, accw = 0.0;
    for (int i = blockIdx.x * 8 + il; i < KK; i += WSUM_BLOCKS * 8) {
        float w = expf(p.g[i] - gm);
        accv += (double)(w * p.res[(size_t)i * 32 + d]);
        if (d == 0) accw += (double)w;
    }
    vred[t] = accv;
    if (d == 0) zred[il] = accw;
    __syncthreads();
    if (il == 0) {
        double s = 0;
#pragma unroll
        for (int k2 = 0; k2 < 8; k2++) s += vred[k2 * 32 + d];
        atomicAdd(&p.racc[d], s);
    }
    if (t == 32) {
        double z2 = 0;
#pragma unroll
        for (int k2 = 0; k2 < 8; k2++) z2 += zred[k2];
        atomicAdd(p.Zacc, z2);
    }
}
__global__ void k_final(P p) {
    __shared__ float rb[32];
    int t = threadIdx.x;
    double Z = *p.Zacc;
    if (t < 32) {
        float r = (float)(p.racc[t] / Z);
        p.out[t] = r;
        rb[t] = r;
    }
    __syncthreads();
    if (t < 2) {
        float s = 0.f;
        for (int d = 0; d < 32; d++) s += rb[d] * p.cW[d * 2 + t];
        p.out[32 + t] = s + p.cb[t];
    }
}

// ---------- host ----------
extern "C" void kernel_launch(void* const* d_in, const int* in_sizes, int n_in,
                              void* d_out, int out_size, void* d_ws, size_t ws_size,
                              hipStream_t stream) {
    (void)in_sizes; (void)n_in; (void)out_size; (void)ws_size;
    P p;
    p.feature  = (const float*)d_in[0];
    p.strength = (const float*)d_in[1];
    p.W0  = (const float*)d_in[2];  p.b0  = (const float*)d_in[3];
    p.al0 = (const float*)d_in[4];  p.ar0 = (const float*)d_in[5];
    p.Wc0 = (const float*)d_in[6];  p.bc0 = (const float*)d_in[7];
    p.W1  = (const float*)d_in[8];  p.b1  = (const float*)d_in[9];
    p.al1 = (const float*)d_in[10]; p.ar1 = (const float*)d_in[11];
    p.gW  = (const float*)d_in[12]; p.gb  = (const float*)d_in[13];
    p.cW  = (const float*)d_in[14]; p.cb  = (const float*)d_in[15];
    p.src = (const int*)d_in[16];   p.dst = (const int*)d_in[17];
    p.out = (float*)d_out;

    char* ws = (char*)d_ws;
    size_t off = 0;
    auto alloc = [&](size_t bytes) -> void* {
        void* r = ws + off;
        off = (off + bytes + 255) & ~(size_t)255;
        return r;
    };
    // ---- zeroed region (must stay first/contiguous) ----
    p.Zacc  = (double*)alloc(8);
    p.racc  = (double*)alloc(32 * 8);
    p.cnt   = (int*)alloc(4);
    p.gmaxk = (unsigned*)alloc(4);
    p.rs    = (unsigned*)alloc(16);
    p.binsHi = (unsigned*)alloc(65536 * 4);
    p.binsLo = (unsigned*)alloc(65536 * 4);
    size_t zbytes = off;
    // ---- big buffers (fully overwritten each run) ----
    p.degc_i = (unsigned char*)alloc((size_t)BCH * NN);
    p.degc_o = (unsigned char*)alloc((size_t)BCH * NN);
    p.cb0 = (unsigned*)alloc((size_t)BCH * NN * 4);
    p.dsum = (int*)alloc((size_t)NN * 4);
    p.z0 = (float*)alloc((size_t)NN * HD * 4);
    p.xk = (float*)alloc((size_t)KK * HD * 4);
    p.z1 = (float*)alloc((size_t)KK * HD * 4);
    p.csr_src = (int*)alloc((size_t)EE * 4);
    p.rank    = (int*)alloc((size_t)EE * 4);
    p.el0 = (float*)alloc((size_t)NN * 4 * 4);
    p.er0 = (float*)alloc((size_t)NN * 4 * 4);
    p.q4  = (float*)alloc((size_t)NN * 4 * 4);
    p.m0f = (float*)alloc((size_t)NN * 4 * 4);
    p.s0f = (float*)alloc((size_t)NN * 4 * 4);
    p.b0wc = (float*)alloc(4);
    p.off0 = (int*)alloc((size_t)(NN + 1) * 4);
    p.bsum = (int*)alloc(256 * 4);
    p.boff = (int*)alloc(256 * 4);
    p.hc    = (float*)alloc((size_t)NN * 4);
    p.keys  = (unsigned*)alloc((size_t)NN * 4);
    p.slot  = (int*)alloc((size_t)NN * 4);
    p.list  = (int*)alloc((size_t)KK * 4);
    p.tscale = (float*)alloc((size_t)KK * 4);
    p.el1 = (float*)alloc((size_t)KK * 4 * 4);
    p.er1 = (float*)alloc((size_t)KK * 4 * 4);
    p.m1f = (float*)alloc((size_t)KK * 4 * 4);
    p.s1f = (float*)alloc((size_t)KK * 4 * 4);
    p.res = (float*)alloc((size_t)KK * DD * 4);
    p.g   = (float*)alloc((size_t)KK * 4);

    const int GB_N = (NN + 255) / 256;        // 196

    hipMemsetAsync(d_ws, 0, zbytes, stream);

    // ---- GAT layer 0: count -> scan -> scatter0 -> gemm0 -> fgatlite ----
    k_count0<<<256, 256, 0, stream>>>(p);
    k_bsum<<<GB_N, 256, 0, stream>>>(p.degc_i, p.bsum, NN, NN);
    k_bscan<<<1, 256, 0, stream>>>(p.bsum, GB_N, p.boff, p.off0, NN);
    k_fscan0<<<GB_N, 256, 0, stream>>>(p);
    k_scat0<<<GB_E4, 256, 0, stream>>>(p);
    k_gemm0<<<G0B + 1, 256, 0, stream>>>(p);
    k_fgatlite<<<NN / 4, 256, 0, stream>>>(p.off0, p.csr_src, p.el0, p.er0, p.q4,
                                           p.dsum, p.b0wc, p.hc, p.m0f, p.s0f);

    // ---- SAGPool: stream-ordered select ----
    k_score<<<GB_N, 256, 0, stream>>>(p);
    k_h0<<<HB, 1024, 0, stream>>>(p);
    k_rsel2<<<1, 1024, 0, stream>>>(p, 0);
    k_h1<<<HB, 1024, 0, stream>>>(p);
    k_rsel2<<<1, 1024, 0, stream>>>(p, 1);
    k_tcnt<<<GB_N, 256, 0, stream>>>(p);
    k_list<<<GB_N, 256, 0, stream>>>(p);

    // ---- GAT layer 1: fgatx -> gemm1 -> fgat2 (layer-0 CSR reused) ----
    k_fgatx<<<KK / 4, 256, 0, stream>>>(p.list, p.tscale, p.off0, p.csr_src,
                                        p.el0, p.er0, p.m0f, p.s0f, p.z0, p.b0, p.xk);
    k_gemm1<<<G1B, 256, 0, stream>>>(p);
    k_fgat2<<<KK / 4, 256, 0, stream>>>(p);

    // ---- edge outputs || gmax, then readout ----
    k_eg<<<GB_E + 98, 256, 0, stream>>>(p);
    k_wsum<<<WSUM_BLOCKS, 256, 0, stream>>>(p);
    k_final<<<1, 64, 0, stream>>>(p);
}

// Round 12
// 512.270 us; speedup vs baseline: 2.6489x; 1.0076x over previous
//
#include <hip/hip_runtime.h>
#include <stdint.h>

#define NN 50000
#define EE 800000
#define FIN 256
#define HD 128
#define DD 32
#define KK 25000
#define SLOPEF 0.4f
#define NEGF (-1e9f)
#define ATT_OFF 34
#define STR_OFF (34 + EE * 4)
#define CW 128             // LDS-cached edges per node (deg ~Poisson(16); recompute fallback)

// counting-sort CSR build (layer 0 only; layer 1 reuses it via slot-filtering)
#define BCH 32             // edge chunks
#define EPC (EE / BCH)     // 25000 edges per chunk
#define NRQ 12500          // node-range quarter for count blocks (4 x 12500 = NN)

// ---------- helpers ----------
__device__ __forceinline__ unsigned fkey(float x) {
    unsigned u = __float_as_uint(x);
    return (u & 0x80000000u) ? ~u : (u | 0x80000000u);   // monotone float->uint
}
__device__ __forceinline__ float unfkey(unsigned k) {
    unsigned u = (k & 0x80000000u) ? (k ^ 0x80000000u) : ~k;
    return __uint_as_float(u);
}
__device__ __forceinline__ float lrelu(float v) { return v > 0.f ? v : SLOPEF * v; }

// ---------- pointer bundle ----------
struct P {
    // inputs
    const float *feature, *strength, *W0, *b0, *al0, *ar0, *Wc0, *bc0;
    const float *W1, *b1, *al1, *ar1, *gW, *gb, *cW, *cb;
    const int *src, *dst;
    // zeroed scratch
    double *Zacc, *racc;
    int *cnt;
    unsigned *gmaxk;
    unsigned *rs;                 // [0]=pivot,[1]=need,[2]=hi bin,[3]=hi remaining
    unsigned *binsHi, *binsLo;    // 65536 u32 bins each
    // other scratch
    unsigned *keys;
    unsigned char *degc_i, *degc_o;   // per-(chunk,node) u8 counts [BCH][NN]
    unsigned *cb0;                // per-(chunk,node) CSR base cursors
    int *dsum;                    // out-degree totals
    int *csr_src, *rank, *off0, *slot, *list, *bsum, *boff;
    float *z0, *el0, *er0, *q4, *m0f, *s0f, *b0wc, *hc, *xk, *z1;
    float *el1, *er1, *m1f, *s1f, *res, *g, *tscale;
    float *out;                   // d_out (float32)
};

// ---------- fp32 tiled GEMM body: C[M,128] = A[M,Kd] @ B[Kd,128] ----------
// 64x64 tile (R11: TLP win, 88->77). R12: BK=32 — half the barriers, 2x loads
// in flight per round. LDS 16.9 KB, acc 16 regs. Kd must be /32 (256,128 ok).
#define BM 64
#define BN 64
#define BK 32
__device__ void gemm_body(
    const float* __restrict__ A, const float* __restrict__ B, float* __restrict__ C,
    int M, int Kd,
    const float* __restrict__ al, const float* __restrict__ ar,
    float* __restrict__ el, float* __restrict__ er,
    const float* __restrict__ Wc, float* __restrict__ q4,
    int bx, int by) {
    __shared__ float As[BK][BM + 4];
    __shared__ float Bs[BK][BN];
    int bm = by * BM, bn = bx * BN;
    int tid = threadIdx.x;
    int tr = tid >> 4, tc = tid & 15;
    int lrow = tid >> 2;                 // 0..63 A-tile row
    int acol = (tid & 3) << 3;           // 0,8,16,24
    int arow = (bm + lrow < M) ? (bm + lrow) : -1;
    int bkr = tid >> 3;                  // 0..31 B-tile row
    int bcol = (tid & 7) << 3;           // 0,8,..,56
    float acc[4][4] = {};
    for (int k0 = 0; k0 < Kd; k0 += BK) {
        {
            float4 v0 = {0.f,0.f,0.f,0.f}, v1 = {0.f,0.f,0.f,0.f};
            if (arow >= 0) {
                const float* ap = A + (size_t)arow * Kd + k0 + acol;
                v0 = *(const float4*)ap; v1 = *(const float4*)(ap + 4);
            }
            As[acol + 0][lrow] = v0.x; As[acol + 1][lrow] = v0.y;
            As[acol + 2][lrow] = v0.z; As[acol + 3][lrow] = v0.w;
            As[acol + 4][lrow] = v1.x; As[acol + 5][lrow] = v1.y;
            As[acol + 6][lrow] = v1.z; As[acol + 7][lrow] = v1.w;
        }
        {
            const float* bp = B + (size_t)(k0 + bkr) * HD + bn + bcol;
            float4 v0 = *(const float4*)bp;
            float4 v1 = *(const float4*)(bp + 4);
            *(float4*)&Bs[bkr][bcol] = v0;
            *(float4*)&Bs[bkr][bcol + 4] = v1;
        }
        __syncthreads();
#pragma unroll
        for (int kk = 0; kk < BK; kk++) {
            float a[4], b[4];
#pragma unroll
            for (int i = 0; i < 4; i++) a[i] = As[kk][tr * 4 + i];
#pragma unroll
            for (int j = 0; j < 4; j++) b[j] = Bs[kk][tc * 4 + j];
#pragma unroll
            for (int i = 0; i < 4; i++)
#pragma unroll
                for (int j = 0; j < 4; j++) acc[i][j] = fmaf(a[i], b[j], acc[i][j]);
        }
        __syncthreads();
    }
#pragma unroll
    for (int i = 0; i < 4; i++) {
        int gr = bm + tr * 4 + i;
        if (gr < M) {
            float4 v = {acc[i][0], acc[i][1], acc[i][2], acc[i][3]};
            *(float4*)(C + (size_t)gr * HD + bn + tc * 4) = v;
        }
    }
    // epilogue: heads 2*bx, 2*bx+1; 8-lane tree reduce per (row, head)
    int head = bx * 2 + (tc >> 3);
    int dbase = (tc & 7) * 4;
    const float* alh = al + head * 32 + dbase;
    const float* arh = ar + head * 32 + dbase;
    float a0 = alh[0], a1 = alh[1], a2 = alh[2], a3 = alh[3];
    float r0 = arh[0], r1 = arh[1], r2 = arh[2], r3 = arh[3];
    float w0 = 0.f, w1 = 0.f, w2 = 0.f, w3 = 0.f;
    if (Wc) {
        const float* wch = Wc + head * 32 + dbase;
        w0 = wch[0]; w1 = wch[1]; w2 = wch[2]; w3 = wch[3];
    }
#pragma unroll
    for (int i = 0; i < 4; i++) {
        int gr = bm + tr * 4 + i;
        float pe = acc[i][0]*a0 + acc[i][1]*a1 + acc[i][2]*a2 + acc[i][3]*a3;
        float pr = acc[i][0]*r0 + acc[i][1]*r1 + acc[i][2]*r2 + acc[i][3]*r3;
        float pq = acc[i][0]*w0 + acc[i][1]*w1 + acc[i][2]*w2 + acc[i][3]*w3;
#pragma unroll
        for (int o = 1; o < 8; o <<= 1) {
            pe += __shfl_xor(pe, o); pr += __shfl_xor(pr, o); pq += __shfl_xor(pq, o);
        }
        if ((tc & 7) == 0 && gr < M) {
            el[gr * 4 + head] = pe; er[gr * 4 + head] = pr;
            if (Wc) q4[gr * 4 + head] = pq;
        }
    }
}

// ---------- layer-0 count: (chunk x node-quarter) u8 LDS histogram, int4 loads ----------
__global__ __launch_bounds__(256) void k_count0(P p) {
    __shared__ unsigned hist[NRQ / 4];        // 12500 u8 counters
    int blk = blockIdx.x;
    int isD = blk < 128;
    int c = blk & 31, rq = (blk >> 5) & 3;
    int nbase = rq * NRQ;
    for (int w = threadIdx.x; w < NRQ / 4; w += 256) hist[w] = 0u;
    __syncthreads();
    int j0 = c * (EPC / 4), j1 = j0 + (EPC / 4);
    if (isD) {
        const int4* d4 = (const int4*)p.dst;
        for (int j = j0 + (int)threadIdx.x; j < j1; j += 256) {
            int4 dv = d4[j];
            int e = j * 4;
            int d, t;
            d = dv.x - nbase;
            if ((unsigned)d < (unsigned)NRQ) {
                unsigned sh = (unsigned)(d & 3) * 8u;
                t = (int)((atomicAdd(&hist[d >> 2], 1u << sh) >> sh) & 0xffu);
                p.rank[e + 0] = t;
            }
            d = dv.y - nbase;
            if ((unsigned)d < (unsigned)NRQ) {
                unsigned sh = (unsigned)(d & 3) * 8u;
                t = (int)((atomicAdd(&hist[d >> 2], 1u << sh) >> sh) & 0xffu);
                p.rank[e + 1] = t;
            }
            d = dv.z - nbase;
            if ((unsigned)d < (unsigned)NRQ) {
                unsigned sh = (unsigned)(d & 3) * 8u;
                t = (int)((atomicAdd(&hist[d >> 2], 1u << sh) >> sh) & 0xffu);
                p.rank[e + 2] = t;
            }
            d = dv.w - nbase;
            if ((unsigned)d < (unsigned)NRQ) {
                unsigned sh = (unsigned)(d & 3) * 8u;
                t = (int)((atomicAdd(&hist[d >> 2], 1u << sh) >> sh) & 0xffu);
                p.rank[e + 3] = t;
            }
        }
    } else {
        const int4* s4 = (const int4*)p.src;
        for (int j = j0 + (int)threadIdx.x; j < j1; j += 256) {
            int4 sv = s4[j];
            int s;
            s = sv.x - nbase;
            if ((unsigned)s < (unsigned)NRQ) atomicAdd(&hist[s >> 2], 1u << ((unsigned)(s & 3) * 8u));
            s = sv.y - nbase;
            if ((unsigned)s < (unsigned)NRQ) atomicAdd(&hist[s >> 2], 1u << ((unsigned)(s & 3) * 8u));
            s = sv.z - nbase;
            if ((unsigned)s < (unsigned)NRQ) atomicAdd(&hist[s >> 2], 1u << ((unsigned)(s & 3) * 8u));
            s = sv.w - nbase;
            if ((unsigned)s < (unsigned)NRQ) atomicAdd(&hist[s >> 2], 1u << ((unsigned)(s & 3) * 8u));
        }
    }
    __syncthreads();
    unsigned* o32 = (unsigned*)((isD ? p.degc_i : p.degc_o) + (size_t)c * NN + nbase);
    for (int w = threadIdx.x; w < NRQ / 4; w += 256) o32[w] = hist[w];
}

// ---------- two-level exclusive scan over node totals (stream-ordered) ----------
__global__ __launch_bounds__(256) void k_bsum(const unsigned char* __restrict__ deg,
                                              int* __restrict__ bsum, int n, int nn) {
    int i = blockIdx.x * 256 + threadIdx.x;
    int v = 0;
    if (i < n) {
#pragma unroll
        for (int c = 0; c < BCH; c++) v += deg[(size_t)c * nn + i];
    }
    int lane = threadIdx.x & 63, w = threadIdx.x >> 6;
    __shared__ int ws[4];
#pragma unroll
    for (int o = 1; o < 64; o <<= 1) v += __shfl_xor(v, o);
    if (lane == 0) ws[w] = v;
    __syncthreads();
    if (threadIdx.x == 0) bsum[blockIdx.x] = ws[0] + ws[1] + ws[2] + ws[3];
}
__global__ __launch_bounds__(256) void k_bscan(const int* __restrict__ bsum, int nb,
                                               int* __restrict__ boff,
                                               int* __restrict__ off, int n) {
    __shared__ int ws[4];
    __shared__ int wo[5];
    int t = threadIdx.x;
    int v = (t < nb) ? bsum[t] : 0;
    int lane = t & 63, w = t >> 6;
    int incl = v;
    for (int o = 1; o < 64; o <<= 1) { int u = __shfl_up(incl, o); if (lane >= o) incl += u; }
    if (lane == 63) ws[w] = incl;
    __syncthreads();
    if (t == 0) { int a = 0; for (int i = 0; i < 4; i++) { wo[i] = a; a += ws[i]; } wo[4] = a; }
    __syncthreads();
    if (t < nb) boff[t] = wo[w] + incl - v;
    if (t == 0) off[n] = wo[4];
}
// final scan: off0 + per-chunk bases cb0 + out-degree totals dsum
__global__ __launch_bounds__(256) void k_fscan0(P p) {
    __shared__ int ws[4];
    __shared__ int wo[4];
    int i = blockIdx.x * 256 + threadIdx.x;
    int v = 0;
    if (i < NN) {
#pragma unroll
        for (int c = 0; c < BCH; c++) v += p.degc_i[(size_t)c * NN + i];
    }
    int lane = threadIdx.x & 63, w = threadIdx.x >> 6;
    int incl = v;
    for (int o = 1; o < 64; o <<= 1) { int u = __shfl_up(incl, o); if (lane >= o) incl += u; }
    if (lane == 63) ws[w] = incl;
    __syncthreads();
    if (threadIdx.x == 0) { int a = 0; for (int k = 0; k < 4; k++) { wo[k] = a; a += ws[k]; } }
    __syncthreads();
    if (i < NN) {
        int base = p.boff[blockIdx.x] + wo[w] + incl - v;
        p.off0[i] = base;
        unsigned run = (unsigned)base;
        int s = 0;
#pragma unroll
        for (int c = 0; c < BCH; c++) {
            p.cb0[(size_t)c * NN + i] = run;
            run += p.degc_i[(size_t)c * NN + i];
            s += p.degc_o[(size_t)c * NN + i];
        }
        p.dsum[i] = s;
    }
}

// ---------- MERGED: gemm0 || CSR scatter0 || b0wc (all post-fscan0-independent) ----------
// R12: scat0 (gather-latency, ~0 VALU) co-scheduled with gemm0 (VALU/LDS) —
// complementary pipes overlap (m114); at 84-96 VGPR the R7 split penalty is gone.
#define G0B 1564           // 2 x 782 gemm blocks (64-row tiles)
#define GB_E4 782          // scat blocks (4 edges/thread)
__global__ __launch_bounds__(256) void k_gemm0(P p) {
    int blk = blockIdx.x;
    if (blk < G0B) {
        gemm_body(p.feature, p.W0, p.z0, NN, FIN, p.al0, p.ar0, p.el0, p.er0,
                  p.Wc0, p.q4, blk & 1, blk >> 1);
    } else if (blk < G0B + GB_E4) {
        int j = (blk - G0B) * 256 + threadIdx.x;
        if (j < EE / 4) {
            int c = j / (EPC / 4);
            int4 dv = ((const int4*)p.dst)[j];
            int4 sv = ((const int4*)p.src)[j];
            int4 rv = ((const int4*)p.rank)[j];
            const unsigned* cb = p.cb0 + (size_t)c * NN;
            p.csr_src[cb[dv.x] + (unsigned)rv.x] = sv.x;
            p.csr_src[cb[dv.y] + (unsigned)rv.y] = sv.y;
            p.csr_src[cb[dv.z] + (unsigned)rv.z] = sv.z;
            p.csr_src[cb[dv.w] + (unsigned)rv.w] = sv.w;
        }
    } else {
        int l = threadIdx.x;
        if (l < 64) {
            float t = p.b0[l] * p.Wc0[l] + p.b0[l + 64] * p.Wc0[l + 64];
#pragma unroll
            for (int o = 1; o < 64; o <<= 1) t += __shfl_xor(t, o);
            if (l == 0) p.b0wc[0] = t;
        }
    }
}

// ---------- layer-0 softmax + SCALAR q-gather (all nodes) ----------
__global__ __launch_bounds__(256) void k_fgatlite(
    const int* __restrict__ off, const int* __restrict__ csrs,
    const float* __restrict__ el, const float* __restrict__ er,
    const float* __restrict__ q4, const int* __restrict__ dsum,
    const float* __restrict__ b0wc,
    float* __restrict__ hc, float* __restrict__ m0f, float* __restrict__ s0f) {
    int wv = threadIdx.x >> 6, lane = threadIdx.x & 63;
    int v = blockIdx.x * 4 + wv;
    int b = off[v], e = off[v + 1], deg = e - b;
    int h = lane >> 4, sub = lane & 15;
    float erh = er[(size_t)v * 4 + h];
    float m = NEGF;
    for (int li = sub; li < deg; li += 16) {
        int s = csrs[b + li];
        m = fmaxf(m, lrelu(el[(size_t)s * 4 + h] + erh));
    }
#pragma unroll
    for (int o = 1; o < 16; o <<= 1) m = fmaxf(m, __shfl_xor(m, o));
    float ssum = 0.f, hq = 0.f;
    for (int li = sub; li < deg; li += 16) {
        int s = csrs[b + li];
        float ex = expf(lrelu(el[(size_t)s * 4 + h] + erh) - m);
        ssum += ex;
        hq = fmaf(ex, q4[(size_t)s * 4 + h], hq);
    }
#pragma unroll
    for (int o = 1; o < 16; o <<= 1) { ssum += __shfl_xor(ssum, o); hq += __shfl_xor(hq, o); }
    if (sub == 0) { m0f[v * 4 + h] = m; s0f[v * 4 + h] = ssum; }
    float t = hq / fmaxf(ssum, 1e-16f);
    t += __shfl_xor(t, 16);
    t += __shfl_xor(t, 32);
    if (lane == 0)
        hc[v] = (t + b0wc[0]) / sqrtf(fmaxf((float)dsum[v], 1.f));
}

// ---------- SAGPool score -> keys ----------
__global__ __launch_bounds__(256) void k_score(P p) {
    int v = blockIdx.x * blockDim.x + threadIdx.x;
    if (v >= NN) return;
    int b = p.off0[v], en = p.off0[v + 1];
    float acc = 0.f;
    for (int i = b; i < en; i++) acc += p.hc[p.csr_src[i]];
    float dg = fmaxf((float)(en - b), 1.f);
    float sc = acc / sqrtf(dg) + p.bc0[0];
    p.keys[v] = fkey(sc);
}

// ---------- hi-16 histogram: per-block u16-packed LDS (two 64KB half-passes) ----------
#define HB 49              // ceil(NN/1024)
__global__ __launch_bounds__(1024) void k_h0(P p) {
    __shared__ unsigned hist[16384];     // 64 KB: 32768 bins u16-packed per half
    int i = blockIdx.x * 1024 + (int)threadIdx.x;
    unsigned key = (i < NN) ? p.keys[i] : 0xFFFFFFFFu;  // sentinel: never counted
    unsigned b16 = key >> 16;
#pragma unroll
    for (int half = 0; half < 2; half++) {
        for (int w = threadIdx.x; w < 16384; w += 1024) hist[w] = 0u;
        __syncthreads();
        if (i < NN && (int)(b16 >> 15) == half) {
            unsigned bb = b16 & 0x7FFFu;
            atomicAdd(&hist[bb >> 1], 1u << (16u * (bb & 1u)));
        }
        __syncthreads();
        for (int w = threadIdx.x; w < 16384; w += 1024) {
            unsigned hv = hist[w];
            unsigned lo = hv & 0xFFFFu, hi = hv >> 16;
            if (lo) atomicAdd(&p.binsHi[half * 32768 + 2 * w], lo);
            if (hi) atomicAdd(&p.binsHi[half * 32768 + 2 * w + 1], hi);
        }
        __syncthreads();
    }
}

// ---------- lo-16 histogram among hi-bin candidates ----------
__global__ __launch_bounds__(1024) void k_h1(P p) {
    __shared__ unsigned hist[16384];
    int i = blockIdx.x * 1024 + (int)threadIdx.x;
    unsigned hib = p.rs[2];
    unsigned key = (i < NN) ? p.keys[i] : 0u;
    int cand = (i < NN) && ((key >> 16) == hib);
    unsigned b16 = key & 0xFFFFu;
#pragma unroll
    for (int half = 0; half < 2; half++) {
        for (int w = threadIdx.x; w < 16384; w += 1024) hist[w] = 0u;
        __syncthreads();
        if (cand && (int)(b16 >> 15) == half) {
            unsigned bb = b16 & 0x7FFFu;
            atomicAdd(&hist[bb >> 1], 1u << (16u * (bb & 1u)));
        }
        __syncthreads();
        for (int w = threadIdx.x; w < 16384; w += 1024) {
            unsigned hv = hist[w];
            unsigned lo = hv & 0xFFFFu, hi = hv >> 16;
            if (lo) atomicAdd(&p.binsLo[half * 32768 + 2 * w], lo);
            if (hi) atomicAdd(&p.binsLo[half * 32768 + 2 * w + 1], hi);
        }
        __syncthreads();
    }
}

// ---------- radix pick: 1 block scans 65536 bins ----------
__global__ __launch_bounds__(1024) void k_rsel2(P p, int level) {
    const unsigned* bins = level ? p.binsLo : p.binsHi;
    int K = level ? (int)p.rs[3] : KK;
    __shared__ unsigned wsm[16];
    __shared__ unsigned wpre[17];
    int t = threadIdx.x;
    unsigned base = (unsigned)t * 64;
    const uint4* b4 = (const uint4*)(bins + base);
    unsigned S = 0;
#pragma unroll
    for (int i = 0; i < 16; i++) {
        uint4 u = b4[i];
        S += u.x + u.y + u.z + u.w;
    }
    int lane = t & 63, w = t >> 6;
    unsigned val = S;
    for (int o = 1; o < 64; o <<= 1) { unsigned u = __shfl_up(val, o); if (lane >= o) val += u; }
    if (lane == 63) wsm[w] = val;
    __syncthreads();
    if (t == 0) { unsigned a = 0; for (int i = 0; i < 16; i++) { wpre[i] = a; a += wsm[i]; } wpre[16] = a; }
    __syncthreads();
    unsigned incl = wpre[w] + val;
    unsigned running = wpre[16] - incl;    // keys in strictly higher bins
    for (int i = 63; i >= 0; i--) {
        unsigned c = bins[base + i];
        unsigned above = running;
        running += c;
        if ((int)above < K && (int)running >= K) {
            if (level == 0) { p.rs[2] = base + (unsigned)i; p.rs[3] = (unsigned)(K - (int)above); }
            else { p.rs[0] = (p.rs[2] << 16) | (base + (unsigned)i); p.rs[1] = (unsigned)(K - (int)above); }
        }
    }
}

// ---------- parallel tie counting ----------
__global__ __launch_bounds__(256) void k_tcnt(P p) {
    __shared__ int ws[4];
    int v = blockIdx.x * 256 + (int)threadIdx.x;
    int flag = (v < NN && p.keys[v] == p.rs[0]) ? 1 : 0;
    unsigned long long m = __ballot(flag);
    int lane = threadIdx.x & 63, w = threadIdx.x >> 6;
    if (lane == 0) ws[w] = __popcll(m);
    __syncthreads();
    if (threadIdx.x == 0) p.bsum[blockIdx.x] = ws[0] + ws[1] + ws[2] + ws[3];
}

// ---------- list build: select + lowest-index tie ranks inline ----------
__global__ __launch_bounds__(256) void k_list(P p) {
    __shared__ int pre0;
    __shared__ int ws[4];
    int blk = blockIdx.x, tid = threadIdx.x;
    unsigned pivot = p.rs[0];
    int need = (int)p.rs[1];
    int v = blk * 256 + tid;
    unsigned k = (v < NN) ? p.keys[v] : 0u;
    int flag = (v < NN && k == pivot) ? 1 : 0;
    unsigned long long mask = __ballot(flag);
    int lane = tid & 63, w = tid >> 6;
    if (lane == 0) ws[w] = __popcll(mask);
    if (tid == 0) {
        int s = 0;
        for (int b2 = 0; b2 < blk; b2++) s += p.bsum[b2];
        pre0 = s;
    }
    __syncthreads();
    int woff = 0;
    for (int i = 0; i < w; i++) woff += ws[i];
    int rank = pre0 + woff + __popcll(mask & ((1ull << lane) - 1ull));
    if (v < NN) {
        int selv = (k > pivot) || (flag && rank < need);
        if (selv) {
            int idx = atomicAdd(p.cnt, 1);
            p.list[idx] = v;
            p.slot[v] = idx;
            p.tscale[idx] = tanhf(unfkey(k));
        } else {
            p.slot[v] = -1;
        }
    }
}

// ---------- full x for SELECTED nodes only ----------
__global__ __launch_bounds__(256) void k_fgatx(
    const int* __restrict__ list, const float* __restrict__ tscale,
    const int* __restrict__ off, const int* __restrict__ csrs,
    const float* __restrict__ el, const float* __restrict__ er,
    const float* __restrict__ m0f, const float* __restrict__ s0f,
    const float* __restrict__ z, const float* __restrict__ b0,
    float* __restrict__ xk) {
    __shared__ int ssrc[4][CW];
    __shared__ float sexp[4][CW][4];
    int wv = threadIdx.x >> 6, lane = threadIdx.x & 63;
    int i = blockIdx.x * 4 + wv;
    int v = list[i];
    int b = off[v], e = off[v + 1], deg = e - b;
    int h = lane >> 4, sub = lane & 15;
    float erh = er[(size_t)v * 4 + h];
    float mh = m0f[v * 4 + h];
    for (int li = sub; li < deg; li += 16) {
        int s = csrs[b + li];
        if (h == 0 && li < CW) ssrc[wv][li] = s;
        if (li < CW) sexp[wv][li][h] = expf(lrelu(el[(size_t)s * 4 + h] + erh) - mh);
    }
    __syncthreads();
    int h0 = lane >> 5, h1 = h0 + 2;
    float s0 = s0f[v * 4 + h0], s1 = s0f[v * 4 + h1];
    float m0 = m0f[v * 4 + h0], m1 = m0f[v * 4 + h1];
    float er0v = er[(size_t)v * 4 + h0], er1v = er[(size_t)v * 4 + h1];
    int c0 = lane, c1 = lane + 64;
    float acc0 = 0.f, acc1 = 0.f;
    for (int li = 0; li < deg; li++) {
        int s; float w0, w1;
        if (li < CW) {
            s = ssrc[wv][li];
            w0 = sexp[wv][li][h0]; w1 = sexp[wv][li][h1];
        } else {
            s = csrs[b + li];
            w0 = expf(lrelu(el[(size_t)s * 4 + h0] + er0v) - m0);
            w1 = expf(lrelu(el[(size_t)s * 4 + h1] + er1v) - m1);
        }
        int su = __builtin_amdgcn_readfirstlane(s);
        const float* zr = z + (size_t)su * HD;
        acc0 = fmaf(w0, zr[c0], acc0);
        acc1 = fmaf(w1, zr[c1], acc1);
    }
    float ts = tscale[i];
    float* xr = xk + (size_t)i * HD;
    xr[c0] = (acc0 / fmaxf(s0, 1e-16f) + b0[c0]) * ts;
    xr[c1] = (acc1 / fmaxf(s1, 1e-16f) + b0[c1]) * ts;
}

// ---------- pure gemm1 ----------
#define G1B 782
__global__ __launch_bounds__(256) void k_gemm1(P p) {
    gemm_body(p.xk, p.W1, p.z1, KK, HD, p.al1, p.ar1, p.el1, p.er1,
              nullptr, nullptr, blockIdx.x & 1, blockIdx.x >> 1);
}

// ---------- layer-1 fused GAT: reuses LAYER-0 CSR, filters by slot ----------
__global__ __launch_bounds__(256) void k_fgat2(P p) {
    __shared__ int ssrc[4][CW];
    __shared__ float sexp[4][CW][4];
    int wv = threadIdx.x >> 6, lane = threadIdx.x & 63;
    int i = blockIdx.x * 4 + wv;          // slot index
    int v = p.list[i];                    // original node id
    int b = p.off0[v], e = p.off0[v + 1], deg = e - b;
    int h = lane >> 4, sub = lane & 15;
    float4 er4 = *(const float4*)(p.er1 + (size_t)i * 4);
    float erh = ((const float*)&er4)[h];
    float m = NEGF;
    for (int li = sub; li < deg; li += 16) {
        int so = p.csr_src[b + li];
        int ss = p.slot[so];
        if (h == 0 && li < CW) ssrc[wv][li] = ss;
        if (ss >= 0) m = fmaxf(m, lrelu(p.el1[(size_t)ss * 4 + h] + erh));
    }
#pragma unroll
    for (int o = 1; o < 16; o <<= 1) m = fmaxf(m, __shfl_xor(m, o));
    float ssum = 0.f;
    for (int li = sub; li < deg; li += 16) {
        int so = p.csr_src[b + li];
        int ss = p.slot[so];
        float x = (ss >= 0) ? expf(lrelu(p.el1[(size_t)ss * 4 + h] + erh) - m) : 0.f;
        if (li < CW) sexp[wv][li][h] = x;
        ssum += x;
    }
#pragma unroll
    for (int o = 1; o < 16; o <<= 1) ssum += __shfl_xor(ssum, o);
    if (sub == 0) { p.m1f[i * 4 + h] = m; p.s1f[i * 4 + h] = ssum; }
    __syncthreads();
    int h0 = lane >> 5, h1 = h0 + 2;
    float m0 = __shfl(m, h0 << 4), m1 = __shfl(m, h1 << 4);
    float s0 = __shfl(ssum, h0 << 4), s1 = __shfl(ssum, h1 << 4);
    int c0 = lane, c1 = lane + 64;
    float acc0 = 0.f, acc1 = 0.f;
    for (int li = 0; li < deg; li++) {
        int s; float w0, w1;
        if (li < CW) {
            s = ssrc[wv][li];
            if (s < 0) continue;
            w0 = sexp[wv][li][h0]; w1 = sexp[wv][li][h1];
        } else {
            int so = p.csr_src[b + li];
            s = p.slot[so];
            if (s < 0) continue;
            w0 = expf(lrelu(p.el1[(size_t)s * 4 + h0] + ((const float*)&er4)[h0]) - m0);
            w1 = expf(lrelu(p.el1[(size_t)s * 4 + h1] + ((const float*)&er4)[h1]) - m1);
        }
        int su = __builtin_amdgcn_readfirstlane(s);
        const float* zr = p.z1 + (size_t)su * HD;
        acc0 = fmaf(w0, zr[c0], acc0);
        acc1 = fmaf(w1, zr[c1], acc1);
    }
    float xc0 = acc0 / fmaxf(s0, 1e-16f) + p.b1[c0];
    float xc1 = acc1 / fmaxf(s1, 1e-16f) + p.b1[c1];
    float t = xc0 + xc1;
    t += __shfl_xor(t, 32);
    float pg = 0.f;
    if (lane < 32) {
        float r = 0.25f * t;
        p.res[(size_t)i * 32 + lane] = r;
        pg = r * p.gW[lane];
    }
#pragma unroll
    for (int o = 1; o < 32; o <<= 1) pg += __shfl_xor(pg, o);
    if (lane == 0) p.g[i] = pg + p.gb[0];
}

// ---------- MERGED: per-edge alpha outputs || gmax ----------
#define GB_E 3125
__global__ __launch_bounds__(256) void k_eg(P p) {
    int blk = blockIdx.x;
    if (blk < GB_E) {
        int e = blk * 256 + (int)threadIdx.x;
        if (e >= EE) return;
        int ds = p.slot[p.src[e]], dd = p.slot[p.dst[e]];
        float a[4] = {0.f, 0.f, 0.f, 0.f};
        float st = 0.f;
        if (ds >= 0 && dd >= 0) {
            float4 es = *(const float4*)(p.el1 + ds * 4);
            float4 ed = *(const float4*)(p.er1 + dd * 4);
            float l[4] = {lrelu(es.x + ed.x), lrelu(es.y + ed.y), lrelu(es.z + ed.z), lrelu(es.w + ed.w)};
#pragma unroll
            for (int h = 0; h < 4; h++) {
                float m = p.m1f[dd * 4 + h];
                float ex = expf(l[h] - m);
                a[h] = ex / fmaxf(p.s1f[dd * 4 + h], 1e-16f);
            }
            st = p.strength[e];
        }
        float* o = p.out + ATT_OFF + (size_t)e * 4;
        *(float2*)(o) = make_float2(a[0], a[1]);
        *(float2*)(o + 2) = make_float2(a[2], a[3]);
        p.out[STR_OFF + e] = st;
    } else {
        __shared__ float red[256];
        int t = threadIdx.x;
        float m = -3.4e38f;
        for (int i = (blk - GB_E) * 256 + t; i < KK; i += 98 * 256) m = fmaxf(m, p.g[i]);
        red[t] = m;
        __syncthreads();
        for (int o = 128; o > 0; o >>= 1) { if (t < o) red[t] = fmaxf(red[t], red[t + o]); __syncthreads(); }
        if (t == 0) atomicMax(p.gmaxk, fkey(red[0]));   // memset-0 identity ok
    }
}

#define WSUM_BLOCKS 104
__global__ __launch_bounds__(256) void k_wsum(P p) {
    __shared__ double vred[256];
    __shared__ double zred[8];
    int t = threadIdx.x, il = t >> 5, d = t & 31;
    float gm = unfkey(*p.gmaxk);
    double accv = 0.0, accw = 0.0;
    for (int i = blockIdx.x * 8 + il; i < KK; i += WSUM_BLOCKS * 8) {
        float w = expf(p.g[i] - gm);
        accv += (double)(w * p.res[(size_t)i * 32 + d]);
        if (d == 0) accw += (double)w;
    }
    vred[t] = accv;
    if (d == 0) zred[il] = accw;
    __syncthreads();
    if (il == 0) {
        double s = 0;
#pragma unroll
        for (int k2 = 0; k2 < 8; k2++) s += vred[k2 * 32 + d];
        atomicAdd(&p.racc[d], s);
    }
    if (t == 32) {
        double z2 = 0;
#pragma unroll
        for (int k2 = 0; k2 < 8; k2++) z2 += zred[k2];
        atomicAdd(p.Zacc, z2);
    }
}
__global__ void k_final(P p) {
    __shared__ float rb[32];
    int t = threadIdx.x;
    double Z = *p.Zacc;
    if (t < 32) {
        float r = (float)(p.racc[t] / Z);
        p.out[t] = r;
        rb[t] = r;
    }
    __syncthreads();
    if (t < 2) {
        float s = 0.f;
        for (int d = 0; d < 32; d++) s += rb[d] * p.cW[d * 2 + t];
        p.out[32 + t] = s + p.cb[t];
    }
}

// ---------- host ----------
extern "C" void kernel_launch(void* const* d_in, const int* in_sizes, int n_in,
                              void* d_out, int out_size, void* d_ws, size_t ws_size,
                              hipStream_t stream) {
    (void)in_sizes; (void)n_in; (void)out_size; (void)ws_size;
    P p;
    p.feature  = (const float*)d_in[0];
    p.strength = (const float*)d_in[1];
    p.W0  = (const float*)d_in[2];  p.b0  = (const float*)d_in[3];
    p.al0 = (const float*)d_in[4];  p.ar0 = (const float*)d_in[5];
    p.Wc0 = (const float*)d_in[6];  p.bc0 = (const float*)d_in[7];
    p.W1  = (const float*)d_in[8];  p.b1  = (const float*)d_in[9];
    p.al1 = (const float*)d_in[10]; p.ar1 = (const float*)d_in[11];
    p.gW  = (const float*)d_in[12]; p.gb  = (const float*)d_in[13];
    p.cW  = (const float*)d_in[14]; p.cb  = (const float*)d_in[15];
    p.src = (const int*)d_in[16];   p.dst = (const int*)d_in[17];
    p.out = (float*)d_out;

    char* ws = (char*)d_ws;
    size_t off = 0;
    auto alloc = [&](size_t bytes) -> void* {
        void* r = ws + off;
        off = (off + bytes + 255) & ~(size_t)255;
        return r;
    };
    // ---- zeroed region (must stay first/contiguous) ----
    p.Zacc  = (double*)alloc(8);
    p.racc  = (double*)alloc(32 * 8);
    p.cnt   = (int*)alloc(4);
    p.gmaxk = (unsigned*)alloc(4);
    p.rs    = (unsigned*)alloc(16);
    p.binsHi = (unsigned*)alloc(65536 * 4);
    p.binsLo = (unsigned*)alloc(65536 * 4);
    size_t zbytes = off;
    // ---- big buffers (fully overwritten each run) ----
    p.degc_i = (unsigned char*)alloc((size_t)BCH * NN);
    p.degc_o = (unsigned char*)alloc((size_t)BCH * NN);
    p.cb0 = (unsigned*)alloc((size_t)BCH * NN * 4);
    p.dsum = (int*)alloc((size_t)NN * 4);
    p.z0 = (float*)alloc((size_t)NN * HD * 4);
    p.xk = (float*)alloc((size_t)KK * HD * 4);
    p.z1 = (float*)alloc((size_t)KK * HD * 4);
    p.csr_src = (int*)alloc((size_t)EE * 4);
    p.rank    = (int*)alloc((size_t)EE * 4);
    p.el0 = (float*)alloc((size_t)NN * 4 * 4);
    p.er0 = (float*)alloc((size_t)NN * 4 * 4);
    p.q4  = (float*)alloc((size_t)NN * 4 * 4);
    p.m0f = (float*)alloc((size_t)NN * 4 * 4);
    p.s0f = (float*)alloc((size_t)NN * 4 * 4);
    p.b0wc = (float*)alloc(4);
    p.off0 = (int*)alloc((size_t)(NN + 1) * 4);
    p.bsum = (int*)alloc(256 * 4);
    p.boff = (int*)alloc(256 * 4);
    p.hc    = (float*)alloc((size_t)NN * 4);
    p.keys  = (unsigned*)alloc((size_t)NN * 4);
    p.slot  = (int*)alloc((size_t)NN * 4);
    p.list  = (int*)alloc((size_t)KK * 4);
    p.tscale = (float*)alloc((size_t)KK * 4);
    p.el1 = (float*)alloc((size_t)KK * 4 * 4);
    p.er1 = (float*)alloc((size_t)KK * 4 * 4);
    p.m1f = (float*)alloc((size_t)KK * 4 * 4);
    p.s1f = (float*)alloc((size_t)KK * 4 * 4);
    p.res = (float*)alloc((size_t)KK * DD * 4);
    p.g   = (float*)alloc((size_t)KK * 4);

    const int GB_N = (NN + 255) / 256;        // 196

    hipMemsetAsync(d_ws, 0, zbytes, stream);

    // ---- GAT layer 0: count -> scan -> (gemm0 || scatter0) -> fgatlite ----
    k_count0<<<256, 256, 0, stream>>>(p);
    k_bsum<<<GB_N, 256, 0, stream>>>(p.degc_i, p.bsum, NN, NN);
    k_bscan<<<1, 256, 0, stream>>>(p.bsum, GB_N, p.boff, p.off0, NN);
    k_fscan0<<<GB_N, 256, 0, stream>>>(p);
    k_gemm0<<<G0B + GB_E4 + 1, 256, 0, stream>>>(p);
    k_fgatlite<<<NN / 4, 256, 0, stream>>>(p.off0, p.csr_src, p.el0, p.er0, p.q4,
                                           p.dsum, p.b0wc, p.hc, p.m0f, p.s0f);

    // ---- SAGPool: stream-ordered select ----
    k_score<<<GB_N, 256, 0, stream>>>(p);
    k_h0<<<HB, 1024, 0, stream>>>(p);
    k_rsel2<<<1, 1024, 0, stream>>>(p, 0);
    k_h1<<<HB, 1024, 0, stream>>>(p);
    k_rsel2<<<1, 1024, 0, stream>>>(p, 1);
    k_tcnt<<<GB_N, 256, 0, stream>>>(p);
    k_list<<<GB_N, 256, 0, stream>>>(p);

    // ---- GAT layer 1: fgatx -> gemm1 -> fgat2 (layer-0 CSR reused) ----
    k_fgatx<<<KK / 4, 256, 0, stream>>>(p.list, p.tscale, p.off0, p.csr_src,
                                        p.el0, p.er0, p.m0f, p.s0f, p.z0, p.b0, p.xk);
    k_gemm1<<<G1B, 256, 0, stream>>>(p);
    k_fgat2<<<KK / 4, 256, 0, stream>>>(p);

    // ---- edge outputs || gmax, then readout ----
    k_eg<<<GB_E + 98, 256, 0, stream>>>(p);
    k_wsum<<<WSUM_BLOCKS, 256, 0, stream>>>(p);
    k_final<<<1, 64, 0, stream>>>(p);
}

// Round 13
// 505.232 us; speedup vs baseline: 2.6859x; 1.0139x over previous
//
#include <hip/hip_runtime.h>
#include <stdint.h>

#define NN 50000
#define EE 800000
#define FIN 256
#define HD 128
#define DD 32
#define KK 25000
#define SLOPEF 0.4f
#define NEGF (-1e9f)
#define ATT_OFF 34
#define STR_OFF (34 + EE * 4)
#define CW 128             // LDS-cached edges per node (deg ~Poisson(16); recompute fallback)

// counting-sort CSR build (layer 0 only; layer 1 reuses it via slot-filtering)
#define BCH 32             // edge chunks
#define EPC (EE / BCH)     // 25000 edges per chunk
#define NRQ 12500          // node-range quarter for count blocks (4 x 12500 = NN)

// ---------- helpers ----------
__device__ __forceinline__ unsigned fkey(float x) {
    unsigned u = __float_as_uint(x);
    return (u & 0x80000000u) ? ~u : (u | 0x80000000u);   // monotone float->uint
}
__device__ __forceinline__ float unfkey(unsigned k) {
    unsigned u = (k & 0x80000000u) ? (k ^ 0x80000000u) : ~k;
    return __uint_as_float(u);
}
__device__ __forceinline__ float lrelu(float v) { return v > 0.f ? v : SLOPEF * v; }

// ---------- pointer bundle ----------
struct P {
    // inputs
    const float *feature, *strength, *W0, *b0, *al0, *ar0, *Wc0, *bc0;
    const float *W1, *b1, *al1, *ar1, *gW, *gb, *cW, *cb;
    const int *src, *dst;
    // zeroed scratch
    double *Zacc, *racc;
    int *cnt;
    unsigned *gmaxk;
    unsigned *rs;                 // [0]=pivot,[1]=need,[2]=hi bin,[3]=hi remaining
    unsigned *binsHi, *binsLo;    // 65536 u32 bins each
    // other scratch
    unsigned *keys;
    unsigned char *degc_i, *degc_o;   // per-(chunk,node) u8 counts [BCH][NN]
    unsigned *cb0;                // per-(chunk,node) CSR base cursors
    int *dsum;                    // out-degree totals
    int *csr_src, *rank, *off0, *slot, *list, *bsum, *boff;
    float *z0, *el0, *er0, *q4, *m0f, *s0f, *b0wc, *hc, *xk, *z1;
    float *el1, *er1, *m1f, *s1f, *res, *g, *tscale;
    float *out;                   // d_out (float32)
};

// ---------- fp32 tiled GEMM body: C[M,128] = A[M,Kd] @ B[Kd,128] ----------
// 64x64 tile, BK=32. R13: As stride 68->65 — with acol=(tid&3)*8 the 8*68=544
// inter-lane offset is 0 mod 32 (4-way write conflict, R12's 4x SQ_LDS_BANK_
// CONFLICT); 8*65=520 = 8 mod 32 -> 2-way (free per m136).
#define BM 64
#define BN 64
#define BK 32
__device__ void gemm_body(
    const float* __restrict__ A, const float* __restrict__ B, float* __restrict__ C,
    int M, int Kd,
    const float* __restrict__ al, const float* __restrict__ ar,
    float* __restrict__ el, float* __restrict__ er,
    const float* __restrict__ Wc, float* __restrict__ q4,
    int bx, int by) {
    __shared__ float As[BK][BM + 1];
    __shared__ float Bs[BK][BN];
    int bm = by * BM, bn = bx * BN;
    int tid = threadIdx.x;
    int tr = tid >> 4, tc = tid & 15;
    int lrow = tid >> 2;                 // 0..63 A-tile row
    int acol = (tid & 3) << 3;           // 0,8,16,24
    int arow = (bm + lrow < M) ? (bm + lrow) : -1;
    int bkr = tid >> 3;                  // 0..31 B-tile row
    int bcol = (tid & 7) << 3;           // 0,8,..,56
    float acc[4][4] = {};
    for (int k0 = 0; k0 < Kd; k0 += BK) {
        {
            float4 v0 = {0.f,0.f,0.f,0.f}, v1 = {0.f,0.f,0.f,0.f};
            if (arow >= 0) {
                const float* ap = A + (size_t)arow * Kd + k0 + acol;
                v0 = *(const float4*)ap; v1 = *(const float4*)(ap + 4);
            }
            As[acol + 0][lrow] = v0.x; As[acol + 1][lrow] = v0.y;
            As[acol + 2][lrow] = v0.z; As[acol + 3][lrow] = v0.w;
            As[acol + 4][lrow] = v1.x; As[acol + 5][lrow] = v1.y;
            As[acol + 6][lrow] = v1.z; As[acol + 7][lrow] = v1.w;
        }
        {
            const float* bp = B + (size_t)(k0 + bkr) * HD + bn + bcol;
            float4 v0 = *(const float4*)bp;
            float4 v1 = *(const float4*)(bp + 4);
            *(float4*)&Bs[bkr][bcol] = v0;
            *(float4*)&Bs[bkr][bcol + 4] = v1;
        }
        __syncthreads();
#pragma unroll
        for (int kk = 0; kk < BK; kk++) {
            float a[4], b[4];
#pragma unroll
            for (int i = 0; i < 4; i++) a[i] = As[kk][tr * 4 + i];
#pragma unroll
            for (int j = 0; j < 4; j++) b[j] = Bs[kk][tc * 4 + j];
#pragma unroll
            for (int i = 0; i < 4; i++)
#pragma unroll
                for (int j = 0; j < 4; j++) acc[i][j] = fmaf(a[i], b[j], acc[i][j]);
        }
        __syncthreads();
    }
#pragma unroll
    for (int i = 0; i < 4; i++) {
        int gr = bm + tr * 4 + i;
        if (gr < M) {
            float4 v = {acc[i][0], acc[i][1], acc[i][2], acc[i][3]};
            *(float4*)(C + (size_t)gr * HD + bn + tc * 4) = v;
        }
    }
    // epilogue: heads 2*bx, 2*bx+1; 8-lane tree reduce per (row, head)
    int head = bx * 2 + (tc >> 3);
    int dbase = (tc & 7) * 4;
    const float* alh = al + head * 32 + dbase;
    const float* arh = ar + head * 32 + dbase;
    float a0 = alh[0], a1 = alh[1], a2 = alh[2], a3 = alh[3];
    float r0 = arh[0], r1 = arh[1], r2 = arh[2], r3 = arh[3];
    float w0 = 0.f, w1 = 0.f, w2 = 0.f, w3 = 0.f;
    if (Wc) {
        const float* wch = Wc + head * 32 + dbase;
        w0 = wch[0]; w1 = wch[1]; w2 = wch[2]; w3 = wch[3];
    }
#pragma unroll
    for (int i = 0; i < 4; i++) {
        int gr = bm + tr * 4 + i;
        float pe = acc[i][0]*a0 + acc[i][1]*a1 + acc[i][2]*a2 + acc[i][3]*a3;
        float pr = acc[i][0]*r0 + acc[i][1]*r1 + acc[i][2]*r2 + acc[i][3]*r3;
        float pq = acc[i][0]*w0 + acc[i][1]*w1 + acc[i][2]*w2 + acc[i][3]*w3;
#pragma unroll
        for (int o = 1; o < 8; o <<= 1) {
            pe += __shfl_xor(pe, o); pr += __shfl_xor(pr, o); pq += __shfl_xor(pq, o);
        }
        if ((tc & 7) == 0 && gr < M) {
            el[gr * 4 + head] = pe; er[gr * 4 + head] = pr;
            if (Wc) q4[gr * 4 + head] = pq;
        }
    }
}

// ---------- layer-0 count: (chunk x node-quarter) u8 LDS histogram, int4 loads ----------
__global__ __launch_bounds__(256) void k_count0(P p) {
    __shared__ unsigned hist[NRQ / 4];        // 12500 u8 counters
    int blk = blockIdx.x;
    int isD = blk < 128;
    int c = blk & 31, rq = (blk >> 5) & 3;
    int nbase = rq * NRQ;
    for (int w = threadIdx.x; w < NRQ / 4; w += 256) hist[w] = 0u;
    __syncthreads();
    int j0 = c * (EPC / 4), j1 = j0 + (EPC / 4);
    if (isD) {
        const int4* d4 = (const int4*)p.dst;
        for (int j = j0 + (int)threadIdx.x; j < j1; j += 256) {
            int4 dv = d4[j];
            int e = j * 4;
            int d, t;
            d = dv.x - nbase;
            if ((unsigned)d < (unsigned)NRQ) {
                unsigned sh = (unsigned)(d & 3) * 8u;
                t = (int)((atomicAdd(&hist[d >> 2], 1u << sh) >> sh) & 0xffu);
                p.rank[e + 0] = t;
            }
            d = dv.y - nbase;
            if ((unsigned)d < (unsigned)NRQ) {
                unsigned sh = (unsigned)(d & 3) * 8u;
                t = (int)((atomicAdd(&hist[d >> 2], 1u << sh) >> sh) & 0xffu);
                p.rank[e + 1] = t;
            }
            d = dv.z - nbase;
            if ((unsigned)d < (unsigned)NRQ) {
                unsigned sh = (unsigned)(d & 3) * 8u;
                t = (int)((atomicAdd(&hist[d >> 2], 1u << sh) >> sh) & 0xffu);
                p.rank[e + 2] = t;
            }
            d = dv.w - nbase;
            if ((unsigned)d < (unsigned)NRQ) {
                unsigned sh = (unsigned)(d & 3) * 8u;
                t = (int)((atomicAdd(&hist[d >> 2], 1u << sh) >> sh) & 0xffu);
                p.rank[e + 3] = t;
            }
        }
    } else {
        const int4* s4 = (const int4*)p.src;
        for (int j = j0 + (int)threadIdx.x; j < j1; j += 256) {
            int4 sv = s4[j];
            int s;
            s = sv.x - nbase;
            if ((unsigned)s < (unsigned)NRQ) atomicAdd(&hist[s >> 2], 1u << ((unsigned)(s & 3) * 8u));
            s = sv.y - nbase;
            if ((unsigned)s < (unsigned)NRQ) atomicAdd(&hist[s >> 2], 1u << ((unsigned)(s & 3) * 8u));
            s = sv.z - nbase;
            if ((unsigned)s < (unsigned)NRQ) atomicAdd(&hist[s >> 2], 1u << ((unsigned)(s & 3) * 8u));
            s = sv.w - nbase;
            if ((unsigned)s < (unsigned)NRQ) atomicAdd(&hist[s >> 2], 1u << ((unsigned)(s & 3) * 8u));
        }
    }
    __syncthreads();
    unsigned* o32 = (unsigned*)((isD ? p.degc_i : p.degc_o) + (size_t)c * NN + nbase);
    for (int w = threadIdx.x; w < NRQ / 4; w += 256) o32[w] = hist[w];
}

// ---------- two-level exclusive scan over node totals (stream-ordered) ----------
__global__ __launch_bounds__(256) void k_bsum(const unsigned char* __restrict__ deg,
                                              int* __restrict__ bsum, int n, int nn) {
    int i = blockIdx.x * 256 + threadIdx.x;
    int v = 0;
    if (i < n) {
#pragma unroll
        for (int c = 0; c < BCH; c++) v += deg[(size_t)c * nn + i];
    }
    int lane = threadIdx.x & 63, w = threadIdx.x >> 6;
    __shared__ int ws[4];
#pragma unroll
    for (int o = 1; o < 64; o <<= 1) v += __shfl_xor(v, o);
    if (lane == 0) ws[w] = v;
    __syncthreads();
    if (threadIdx.x == 0) bsum[blockIdx.x] = ws[0] + ws[1] + ws[2] + ws[3];
}
__global__ __launch_bounds__(256) void k_bscan(const int* __restrict__ bsum, int nb,
                                               int* __restrict__ boff,
                                               int* __restrict__ off, int n) {
    __shared__ int ws[4];
    __shared__ int wo[5];
    int t = threadIdx.x;
    int v = (t < nb) ? bsum[t] : 0;
    int lane = t & 63, w = t >> 6;
    int incl = v;
    for (int o = 1; o < 64; o <<= 1) { int u = __shfl_up(incl, o); if (lane >= o) incl += u; }
    if (lane == 63) ws[w] = incl;
    __syncthreads();
    if (t == 0) { int a = 0; for (int i = 0; i < 4; i++) { wo[i] = a; a += ws[i]; } wo[4] = a; }
    __syncthreads();
    if (t < nb) boff[t] = wo[w] + incl - v;
    if (t == 0) off[n] = wo[4];
}
// final scan: off0 + per-chunk bases cb0 + out-degree totals dsum
__global__ __launch_bounds__(256) void k_fscan0(P p) {
    __shared__ int ws[4];
    __shared__ int wo[4];
    int i = blockIdx.x * 256 + threadIdx.x;
    int v = 0;
    if (i < NN) {
#pragma unroll
        for (int c = 0; c < BCH; c++) v += p.degc_i[(size_t)c * NN + i];
    }
    int lane = threadIdx.x & 63, w = threadIdx.x >> 6;
    int incl = v;
    for (int o = 1; o < 64; o <<= 1) { int u = __shfl_up(incl, o); if (lane >= o) incl += u; }
    if (lane == 63) ws[w] = incl;
    __syncthreads();
    if (threadIdx.x == 0) { int a = 0; for (int k = 0; k < 4; k++) { wo[k] = a; a += ws[k]; } }
    __syncthreads();
    if (i < NN) {
        int base = p.boff[blockIdx.x] + wo[w] + incl - v;
        p.off0[i] = base;
        unsigned run = (unsigned)base;
        int s = 0;
#pragma unroll
        for (int c = 0; c < BCH; c++) {
            p.cb0[(size_t)c * NN + i] = run;
            run += p.degc_i[(size_t)c * NN + i];
            s += p.degc_o[(size_t)c * NN + i];
        }
        p.dsum[i] = s;
    }
}

// ---------- MERGED: gemm0 || CSR scatter0 || b0wc (all post-fscan0-independent) ----------
#define G0B 1564           // 2 x 782 gemm blocks (64-row tiles)
#define GB_E4 782          // scat blocks (4 edges/thread)
__global__ __launch_bounds__(256) void k_gemm0(P p) {
    int blk = blockIdx.x;
    if (blk < G0B) {
        gemm_body(p.feature, p.W0, p.z0, NN, FIN, p.al0, p.ar0, p.el0, p.er0,
                  p.Wc0, p.q4, blk & 1, blk >> 1);
    } else if (blk < G0B + GB_E4) {
        int j = (blk - G0B) * 256 + threadIdx.x;
        if (j < EE / 4) {
            int c = j / (EPC / 4);
            int4 dv = ((const int4*)p.dst)[j];
            int4 sv = ((const int4*)p.src)[j];
            int4 rv = ((const int4*)p.rank)[j];
            const unsigned* cb = p.cb0 + (size_t)c * NN;
            p.csr_src[cb[dv.x] + (unsigned)rv.x] = sv.x;
            p.csr_src[cb[dv.y] + (unsigned)rv.y] = sv.y;
            p.csr_src[cb[dv.z] + (unsigned)rv.z] = sv.z;
            p.csr_src[cb[dv.w] + (unsigned)rv.w] = sv.w;
        }
    } else {
        int l = threadIdx.x;
        if (l < 64) {
            float t = p.b0[l] * p.Wc0[l] + p.b0[l + 64] * p.Wc0[l + 64];
#pragma unroll
            for (int o = 1; o < 64; o <<= 1) t += __shfl_xor(t, o);
            if (l == 0) p.b0wc[0] = t;
        }
    }
}

// ---------- layer-0 softmax (NO max-pass: logits bounded ~6, exp safe) ----------
// alpha = exp(l)/sum(exp(l)) is algebraically identical to max-subtracted form;
// fp32 diff ~1e-7 vs 2e-3 absmax budget. One CSR walk instead of two.
__global__ __launch_bounds__(256) void k_fgatlite(
    const int* __restrict__ off, const int* __restrict__ csrs,
    const float* __restrict__ el, const float* __restrict__ er,
    const float* __restrict__ q4, const int* __restrict__ dsum,
    const float* __restrict__ b0wc,
    float* __restrict__ hc, float* __restrict__ m0f, float* __restrict__ s0f) {
    int wv = threadIdx.x >> 6, lane = threadIdx.x & 63;
    int v = blockIdx.x * 4 + wv;
    int b = off[v], e = off[v + 1], deg = e - b;
    int h = lane >> 4, sub = lane & 15;
    float erh = er[(size_t)v * 4 + h];
    float ssum = 0.f, hq = 0.f;
    for (int li = sub; li < deg; li += 16) {
        int s = csrs[b + li];
        float ex = expf(lrelu(el[(size_t)s * 4 + h] + erh));
        ssum += ex;
        hq = fmaf(ex, q4[(size_t)s * 4 + h], hq);
    }
#pragma unroll
    for (int o = 1; o < 16; o <<= 1) { ssum += __shfl_xor(ssum, o); hq += __shfl_xor(hq, o); }
    if (sub == 0) { m0f[v * 4 + h] = 0.f; s0f[v * 4 + h] = ssum; }
    float t = hq / fmaxf(ssum, 1e-16f);
    t += __shfl_xor(t, 16);
    t += __shfl_xor(t, 32);
    if (lane == 0)
        hc[v] = (t + b0wc[0]) / sqrtf(fmaxf((float)dsum[v], 1.f));
}

// ---------- SAGPool score -> keys ----------
__global__ __launch_bounds__(256) void k_score(P p) {
    int v = blockIdx.x * blockDim.x + threadIdx.x;
    if (v >= NN) return;
    int b = p.off0[v], en = p.off0[v + 1];
    float acc = 0.f;
    for (int i = b; i < en; i++) acc += p.hc[p.csr_src[i]];
    float dg = fmaxf((float)(en - b), 1.f);
    float sc = acc / sqrtf(dg) + p.bc0[0];
    p.keys[v] = fkey(sc);
}

// ---------- hi-16 histogram: per-block u16-packed LDS (two 64KB half-passes) ----------
#define HB 49              // ceil(NN/1024)
__global__ __launch_bounds__(1024) void k_h0(P p) {
    __shared__ unsigned hist[16384];     // 64 KB: 32768 bins u16-packed per half
    int i = blockIdx.x * 1024 + (int)threadIdx.x;
    unsigned key = (i < NN) ? p.keys[i] : 0xFFFFFFFFu;  // sentinel: never counted
    unsigned b16 = key >> 16;
#pragma unroll
    for (int half = 0; half < 2; half++) {
        for (int w = threadIdx.x; w < 16384; w += 1024) hist[w] = 0u;
        __syncthreads();
        if (i < NN && (int)(b16 >> 15) == half) {
            unsigned bb = b16 & 0x7FFFu;
            atomicAdd(&hist[bb >> 1], 1u << (16u * (bb & 1u)));
        }
        __syncthreads();
        for (int w = threadIdx.x; w < 16384; w += 1024) {
            unsigned hv = hist[w];
            unsigned lo = hv & 0xFFFFu, hi = hv >> 16;
            if (lo) atomicAdd(&p.binsHi[half * 32768 + 2 * w], lo);
            if (hi) atomicAdd(&p.binsHi[half * 32768 + 2 * w + 1], hi);
        }
        __syncthreads();
    }
}

// ---------- lo-16 histogram among hi-bin candidates ----------
__global__ __launch_bounds__(1024) void k_h1(P p) {
    __shared__ unsigned hist[16384];
    int i = blockIdx.x * 1024 + (int)threadIdx.x;
    unsigned hib = p.rs[2];
    unsigned key = (i < NN) ? p.keys[i] : 0u;
    int cand = (i < NN) && ((key >> 16) == hib);
    unsigned b16 = key & 0xFFFFu;
#pragma unroll
    for (int half = 0; half < 2; half++) {
        for (int w = threadIdx.x; w < 16384; w += 1024) hist[w] = 0u;
        __syncthreads();
        if (cand && (int)(b16 >> 15) == half) {
            unsigned bb = b16 & 0x7FFFu;
            atomicAdd(&hist[bb >> 1], 1u << (16u * (bb & 1u)));
        }
        __syncthreads();
        for (int w = threadIdx.x; w < 16384; w += 1024) {
            unsigned hv = hist[w];
            unsigned lo = hv & 0xFFFFu, hi = hv >> 16;
            if (lo) atomicAdd(&p.binsLo[half * 32768 + 2 * w], lo);
            if (hi) atomicAdd(&p.binsLo[half * 32768 + 2 * w + 1], hi);
        }
        __syncthreads();
    }
}

// ---------- radix pick: 1 block scans 65536 bins ----------
__global__ __launch_bounds__(1024) void k_rsel2(P p, int level) {
    const unsigned* bins = level ? p.binsLo : p.binsHi;
    int K = level ? (int)p.rs[3] : KK;
    __shared__ unsigned wsm[16];
    __shared__ unsigned wpre[17];
    int t = threadIdx.x;
    unsigned base = (unsigned)t * 64;
    const uint4* b4 = (const uint4*)(bins + base);
    unsigned S = 0;
#pragma unroll
    for (int i = 0; i < 16; i++) {
        uint4 u = b4[i];
        S += u.x + u.y + u.z + u.w;
    }
    int lane = t & 63, w = t >> 6;
    unsigned val = S;
    for (int o = 1; o < 64; o <<= 1) { unsigned u = __shfl_up(val, o); if (lane >= o) val += u; }
    if (lane == 63) wsm[w] = val;
    __syncthreads();
    if (t == 0) { unsigned a = 0; for (int i = 0; i < 16; i++) { wpre[i] = a; a += wsm[i]; } wpre[16] = a; }
    __syncthreads();
    unsigned incl = wpre[w] + val;
    unsigned running = wpre[16] - incl;    // keys in strictly higher bins
    for (int i = 63; i >= 0; i--) {
        unsigned c = bins[base + i];
        unsigned above = running;
        running += c;
        if ((int)above < K && (int)running >= K) {
            if (level == 0) { p.rs[2] = base + (unsigned)i; p.rs[3] = (unsigned)(K - (int)above); }
            else { p.rs[0] = (p.rs[2] << 16) | (base + (unsigned)i); p.rs[1] = (unsigned)(K - (int)above); }
        }
    }
}

// ---------- parallel tie counting ----------
__global__ __launch_bounds__(256) void k_tcnt(P p) {
    __shared__ int ws[4];
    int v = blockIdx.x * 256 + (int)threadIdx.x;
    int flag = (v < NN && p.keys[v] == p.rs[0]) ? 1 : 0;
    unsigned long long m = __ballot(flag);
    int lane = threadIdx.x & 63, w = threadIdx.x >> 6;
    if (lane == 0) ws[w] = __popcll(m);
    __syncthreads();
    if (threadIdx.x == 0) p.bsum[blockIdx.x] = ws[0] + ws[1] + ws[2] + ws[3];
}

// ---------- list build: select + lowest-index tie ranks inline ----------
__global__ __launch_bounds__(256) void k_list(P p) {
    __shared__ int pre0;
    __shared__ int ws[4];
    int blk = blockIdx.x, tid = threadIdx.x;
    unsigned pivot = p.rs[0];
    int need = (int)p.rs[1];
    int v = blk * 256 + tid;
    unsigned k = (v < NN) ? p.keys[v] : 0u;
    int flag = (v < NN && k == pivot) ? 1 : 0;
    unsigned long long mask = __ballot(flag);
    int lane = tid & 63, w = tid >> 6;
    if (lane == 0) ws[w] = __popcll(mask);
    if (tid == 0) {
        int s = 0;
        for (int b2 = 0; b2 < blk; b2++) s += p.bsum[b2];
        pre0 = s;
    }
    __syncthreads();
    int woff = 0;
    for (int i = 0; i < w; i++) woff += ws[i];
    int rank = pre0 + woff + __popcll(mask & ((1ull << lane) - 1ull));
    if (v < NN) {
        int selv = (k > pivot) || (flag && rank < need);
        if (selv) {
            int idx = atomicAdd(p.cnt, 1);
            p.list[idx] = v;
            p.slot[v] = idx;
            p.tscale[idx] = tanhf(unfkey(k));
        } else {
            p.slot[v] = -1;
        }
    }
}

// ---------- full x for SELECTED nodes only ----------
__global__ __launch_bounds__(256) void k_fgatx(
    const int* __restrict__ list, const float* __restrict__ tscale,
    const int* __restrict__ off, const int* __restrict__ csrs,
    const float* __restrict__ el, const float* __restrict__ er,
    const float* __restrict__ m0f, const float* __restrict__ s0f,
    const float* __restrict__ z, const float* __restrict__ b0,
    float* __restrict__ xk) {
    __shared__ int ssrc[4][CW];
    __shared__ float sexp[4][CW][4];
    int wv = threadIdx.x >> 6, lane = threadIdx.x & 63;
    int i = blockIdx.x * 4 + wv;
    int v = list[i];
    int b = off[v], e = off[v + 1], deg = e - b;
    int h = lane >> 4, sub = lane & 15;
    float erh = er[(size_t)v * 4 + h];
    float mh = m0f[v * 4 + h];
    for (int li = sub; li < deg; li += 16) {
        int s = csrs[b + li];
        if (h == 0 && li < CW) ssrc[wv][li] = s;
        if (li < CW) sexp[wv][li][h] = expf(lrelu(el[(size_t)s * 4 + h] + erh) - mh);
    }
    __syncthreads();
    int h0 = lane >> 5, h1 = h0 + 2;
    float s0 = s0f[v * 4 + h0], s1 = s0f[v * 4 + h1];
    float m0 = m0f[v * 4 + h0], m1 = m0f[v * 4 + h1];
    float er0v = er[(size_t)v * 4 + h0], er1v = er[(size_t)v * 4 + h1];
    int c0 = lane, c1 = lane + 64;
    float acc0 = 0.f, acc1 = 0.f;
    for (int li = 0; li < deg; li++) {
        int s; float w0, w1;
        if (li < CW) {
            s = ssrc[wv][li];
            w0 = sexp[wv][li][h0]; w1 = sexp[wv][li][h1];
        } else {
            s = csrs[b + li];
            w0 = expf(lrelu(el[(size_t)s * 4 + h0] + er0v) - m0);
            w1 = expf(lrelu(el[(size_t)s * 4 + h1] + er1v) - m1);
        }
        int su = __builtin_amdgcn_readfirstlane(s);
        const float* zr = z + (size_t)su * HD;
        acc0 = fmaf(w0, zr[c0], acc0);
        acc1 = fmaf(w1, zr[c1], acc1);
    }
    float ts = tscale[i];
    float* xr = xk + (size_t)i * HD;
    xr[c0] = (acc0 / fmaxf(s0, 1e-16f) + b0[c0]) * ts;
    xr[c1] = (acc1 / fmaxf(s1, 1e-16f) + b0[c1]) * ts;
}

// ---------- pure gemm1 ----------
#define G1B 782
__global__ __launch_bounds__(256) void k_gemm1(P p) {
    gemm_body(p.xk, p.W1, p.z1, KK, HD, p.al1, p.ar1, p.el1, p.er1,
              nullptr, nullptr, blockIdx.x & 1, blockIdx.x >> 1);
}

// ---------- layer-1 fused GAT (no max-pass): 2 CSR walks instead of 3 ----------
__global__ __launch_bounds__(256) void k_fgat2(P p) {
    __shared__ int ssrc[4][CW];
    __shared__ float sexp[4][CW][4];
    int wv = threadIdx.x >> 6, lane = threadIdx.x & 63;
    int i = blockIdx.x * 4 + wv;          // slot index
    int v = p.list[i];                    // original node id
    int b = p.off0[v], e = p.off0[v + 1], deg = e - b;
    int h = lane >> 4, sub = lane & 15;
    float4 er4 = *(const float4*)(p.er1 + (size_t)i * 4);
    float erh = ((const float*)&er4)[h];
    float ssum = 0.f;
    for (int li = sub; li < deg; li += 16) {
        int so = p.csr_src[b + li];
        int ss = p.slot[so];
        if (h == 0 && li < CW) ssrc[wv][li] = ss;
        float x = (ss >= 0) ? expf(lrelu(p.el1[(size_t)ss * 4 + h] + erh)) : 0.f;
        if (li < CW) sexp[wv][li][h] = x;
        ssum += x;
    }
#pragma unroll
    for (int o = 1; o < 16; o <<= 1) ssum += __shfl_xor(ssum, o);
    if (sub == 0) { p.m1f[i * 4 + h] = 0.f; p.s1f[i * 4 + h] = ssum; }
    __syncthreads();
    int h0 = lane >> 5, h1 = h0 + 2;
    float s0 = __shfl(ssum, h0 << 4), s1 = __shfl(ssum, h1 << 4);
    int c0 = lane, c1 = lane + 64;
    float acc0 = 0.f, acc1 = 0.f;
    for (int li = 0; li < deg; li++) {
        int s; float w0, w1;
        if (li < CW) {
            s = ssrc[wv][li];
            if (s < 0) continue;
            w0 = sexp[wv][li][h0]; w1 = sexp[wv][li][h1];
        } else {
            int so = p.csr_src[b + li];
            s = p.slot[so];
            if (s < 0) continue;
            w0 = expf(lrelu(p.el1[(size_t)s * 4 + h0] + ((const float*)&er4)[h0]));
            w1 = expf(lrelu(p.el1[(size_t)s * 4 + h1] + ((const float*)&er4)[h1]));
        }
        int su = __builtin_amdgcn_readfirstlane(s);
        const float* zr = p.z1 + (size_t)su * HD;
        acc0 = fmaf(w0, zr[c0], acc0);
        acc1 = fmaf(w1, zr[c1], acc1);
    }
    float xc0 = acc0 / fmaxf(s0, 1e-16f) + p.b1[c0];
    float xc1 = acc1 / fmaxf(s1, 1e-16f) + p.b1[c1];
    float t = xc0 + xc1;
    t += __shfl_xor(t, 32);
    float pg = 0.f;
    if (lane < 32) {
        float r = 0.25f * t;
        p.res[(size_t)i * 32 + lane] = r;
        pg = r * p.gW[lane];
    }
#pragma unroll
    for (int o = 1; o < 32; o <<= 1) pg += __shfl_xor(pg, o);
    if (lane == 0) p.g[i] = pg + p.gb[0];
}

// ---------- MERGED: per-edge alpha outputs || gmax ----------
#define GB_E 3125
__global__ __launch_bounds__(256) void k_eg(P p) {
    int blk = blockIdx.x;
    if (blk < GB_E) {
        int e = blk * 256 + (int)threadIdx.x;
        if (e >= EE) return;
        int ds = p.slot[p.src[e]], dd = p.slot[p.dst[e]];
        float a[4] = {0.f, 0.f, 0.f, 0.f};
        float st = 0.f;
        if (ds >= 0 && dd >= 0) {
            float4 es = *(const float4*)(p.el1 + ds * 4);
            float4 ed = *(const float4*)(p.er1 + dd * 4);
            float l[4] = {lrelu(es.x + ed.x), lrelu(es.y + ed.y), lrelu(es.z + ed.z), lrelu(es.w + ed.w)};
#pragma unroll
            for (int h = 0; h < 4; h++) {
                float m = p.m1f[dd * 4 + h];
                float ex = expf(l[h] - m);
                a[h] = ex / fmaxf(p.s1f[dd * 4 + h], 1e-16f);
            }
            st = p.strength[e];
        }
        float* o = p.out + ATT_OFF + (size_t)e * 4;
        *(float2*)(o) = make_float2(a[0], a[1]);
        *(float2*)(o + 2) = make_float2(a[2], a[3]);
        p.out[STR_OFF + e] = st;
    } else {
        __shared__ float red[256];
        int t = threadIdx.x;
        float m = -3.4e38f;
        for (int i = (blk - GB_E) * 256 + t; i < KK; i += 98 * 256) m = fmaxf(m, p.g[i]);
        red[t] = m;
        __syncthreads();
        for (int o = 128; o > 0; o >>= 1) { if (t < o) red[t] = fmaxf(red[t], red[t + o]); __syncthreads(); }
        if (t == 0) atomicMax(p.gmaxk, fkey(red[0]));   // memset-0 identity ok
    }
}

#define WSUM_BLOCKS 104
__global__ __launch_bounds__(256) void k_wsum(P p) {
    __shared__ double vred[256];
    __shared__ double zred[8];
    int t = threadIdx.x, il = t >> 5, d = t & 31;
    float gm = unfkey(*p.gmaxk);
    double accv = 0.0, accw = 0.0;
    for (int i = blockIdx.x * 8 + il; i < KK; i += WSUM_BLOCKS * 8) {
        float w = expf(p.g[i] - gm);
        accv += (double)(w * p.res[(size_t)i * 32 + d]);
        if (d == 0) accw += (double)w;
    }
    vred[t] = accv;
    if (d == 0) zred[il] = accw;
    __syncthreads();
    if (il == 0) {
        double s = 0;
#pragma unroll
        for (int k2 = 0; k2 < 8; k2++) s += vred[k2 * 32 + d];
        atomicAdd(&p.racc[d], s);
    }
    if (t == 32) {
        double z2 = 0;
#pragma unroll
        for (int k2 = 0; k2 < 8; k2++) z2 += zred[k2];
        atomicAdd(p.Zacc, z2);
    }
}
__global__ void k_final(P p) {
    __shared__ float rb[32];
    int t = threadIdx.x;
    double Z = *p.Zacc;
    if (t < 32) {
        float r = (float)(p.racc[t] / Z);
        p.out[t] = r;
        rb[t] = r;
    }
    __syncthreads();
    if (t < 2) {
        float s = 0.f;
        for (int d = 0; d < 32; d++) s += rb[d] * p.cW[d * 2 + t];
        p.out[32 + t] = s + p.cb[t];
    }
}

// ---------- host ----------
extern "C" void kernel_launch(void* const* d_in, const int* in_sizes, int n_in,
                              void* d_out, int out_size, void* d_ws, size_t ws_size,
                              hipStream_t stream) {
    (void)in_sizes; (void)n_in; (void)out_size; (void)ws_size;
    P p;
    p.feature  = (const float*)d_in[0];
    p.strength = (const float*)d_in[1];
    p.W0  = (const float*)d_in[2];  p.b0  = (const float*)d_in[3];
    p.al0 = (const float*)d_in[4];  p.ar0 = (const float*)d_in[5];
    p.Wc0 = (const float*)d_in[6];  p.bc0 = (const float*)d_in[7];
    p.W1  = (const float*)d_in[8];  p.b1  = (const float*)d_in[9];
    p.al1 = (const float*)d_in[10]; p.ar1 = (const float*)d_in[11];
    p.gW  = (const float*)d_in[12]; p.gb  = (const float*)d_in[13];
    p.cW  = (const float*)d_in[14]; p.cb  = (const float*)d_in[15];
    p.src = (const int*)d_in[16];   p.dst = (const int*)d_in[17];
    p.out = (float*)d_out;

    char* ws = (char*)d_ws;
    size_t off = 0;
    auto alloc = [&](size_t bytes) -> void* {
        void* r = ws + off;
        off = (off + bytes + 255) & ~(size_t)255;
        return r;
    };
    // ---- zeroed region (must stay first/contiguous) ----
    p.Zacc  = (double*)alloc(8);
    p.racc  = (double*)alloc(32 * 8);
    p.cnt   = (int*)alloc(4);
    p.gmaxk = (unsigned*)alloc(4);
    p.rs    = (unsigned*)alloc(16);
    p.binsHi = (unsigned*)alloc(65536 * 4);
    p.binsLo = (unsigned*)alloc(65536 * 4);
    size_t zbytes = off;
    // ---- big buffers (fully overwritten each run) ----
    p.degc_i = (unsigned char*)alloc((size_t)BCH * NN);
    p.degc_o = (unsigned char*)alloc((size_t)BCH * NN);
    p.cb0 = (unsigned*)alloc((size_t)BCH * NN * 4);
    p.dsum = (int*)alloc((size_t)NN * 4);
    p.z0 = (float*)alloc((size_t)NN * HD * 4);
    p.xk = (float*)alloc((size_t)KK * HD * 4);
    p.z1 = (float*)alloc((size_t)KK * HD * 4);
    p.csr_src = (int*)alloc((size_t)EE * 4);
    p.rank    = (int*)alloc((size_t)EE * 4);
    p.el0 = (float*)alloc((size_t)NN * 4 * 4);
    p.er0 = (float*)alloc((size_t)NN * 4 * 4);
    p.q4  = (float*)alloc((size_t)NN * 4 * 4);
    p.m0f = (float*)alloc((size_t)NN * 4 * 4);
    p.s0f = (float*)alloc((size_t)NN * 4 * 4);
    p.b0wc = (float*)alloc(4);
    p.off0 = (int*)alloc((size_t)(NN + 1) * 4);
    p.bsum = (int*)alloc(256 * 4);
    p.boff = (int*)alloc(256 * 4);
    p.hc    = (float*)alloc((size_t)NN * 4);
    p.keys  = (unsigned*)alloc((size_t)NN * 4);
    p.slot  = (int*)alloc((size_t)NN * 4);
    p.list  = (int*)alloc((size_t)KK * 4);
    p.tscale = (float*)alloc((size_t)KK * 4);
    p.el1 = (float*)alloc((size_t)KK * 4 * 4);
    p.er1 = (float*)alloc((size_t)KK * 4 * 4);
    p.m1f = (float*)alloc((size_t)KK * 4 * 4);
    p.s1f = (float*)alloc((size_t)KK * 4 * 4);
    p.res = (float*)alloc((size_t)KK * DD * 4);
    p.g   = (float*)alloc((size_t)KK * 4);

    const int GB_N = (NN + 255) / 256;        // 196

    hipMemsetAsync(d_ws, 0, zbytes, stream);

    // ---- GAT layer 0: count -> scan -> (gemm0 || scatter0) -> fgatlite ----
    k_count0<<<256, 256, 0, stream>>>(p);
    k_bsum<<<GB_N, 256, 0, stream>>>(p.degc_i, p.bsum, NN, NN);
    k_bscan<<<1, 256, 0, stream>>>(p.bsum, GB_N, p.boff, p.off0, NN);
    k_fscan0<<<GB_N, 256, 0, stream>>>(p);
    k_gemm0<<<G0B + GB_E4 + 1, 256, 0, stream>>>(p);
    k_fgatlite<<<NN / 4, 256, 0, stream>>>(p.off0, p.csr_src, p.el0, p.er0, p.q4,
                                           p.dsum, p.b0wc, p.hc, p.m0f, p.s0f);

    // ---- SAGPool: stream-ordered select ----
    k_score<<<GB_N, 256, 0, stream>>>(p);
    k_h0<<<HB, 1024, 0, stream>>>(p);
    k_rsel2<<<1, 1024, 0, stream>>>(p, 0);
    k_h1<<<HB, 1024, 0, stream>>>(p);
    k_rsel2<<<1, 1024, 0, stream>>>(p, 1);
    k_tcnt<<<GB_N, 256, 0, stream>>>(p);
    k_list<<<GB_N, 256, 0, stream>>>(p);

    // ---- GAT layer 1: fgatx -> gemm1 -> fgat2 (layer-0 CSR reused) ----
    k_fgatx<<<KK / 4, 256, 0, stream>>>(p.list, p.tscale, p.off0, p.csr_src,
                                        p.el0, p.er0, p.m0f, p.s0f, p.z0, p.b0, p.xk);
    k_gemm1<<<G1B, 256, 0, stream>>>(p);
    k_fgat2<<<KK / 4, 256, 0, stream>>>(p);

    // ---- edge outputs || gmax, then readout ----
    k_eg<<<GB_E + 98, 256, 0, stream>>>(p);
    k_wsum<<<WSUM_BLOCKS, 256, 0, stream>>>(p);
    k_final<<<1, 64, 0, stream>>>(p);
}